// Round 8
// baseline (270.848 us; speedup 1.0000x reference)
//
#include <hip/hip_runtime.h>
#include <math.h>

// Problem constants: B=8, spatial 64x64 (HW=4096), C_mid=256, C=128, N=9 taps.
typedef const float* fp;
typedef __attribute__((ext_vector_type(8))) short short8;   // 8 bf16 = 4 VGPRs (MFMA A/B frag)
typedef __attribute__((ext_vector_type(4))) float f32x4;    // MFMA C/D frag

__device__ __forceinline__ unsigned short f2bf(float f){    // RTNE float->bf16
    unsigned u = __float_as_uint(f);
    u += 0x7fff + ((u >> 16) & 1);
    return (unsigned short)(u >> 16);
}

// ---------------- K0: merged prep — Wbf[n][o][c] bf16, Wpm[n][32q][128c] bf16, Wpwt[c][128o] f32
__global__ __launch_bounds__(256) void k_prep(fp dcn_w, fp pw, fp mw, fp pww,
                                              unsigned short* Wbf, unsigned short* Wpm, float* Wpwt){
    int i = blockIdx.x*256 + threadIdx.x;       // 217088 = 848 blocks
    if(i < 147456){
        int c = i & 127, o = (i >> 7) & 127, n = i >> 14;
        Wbf[i] = f2bf(dcn_w[o*1152 + c*9 + n]);
    } else if(i < 184320){
        int j = i - 147456;
        int c = j & 127, q = (j >> 7) & 31, n = j >> 12;
        float v = 0.f;
        if(q < 18)      v = pw[q*1152 + c*9 + n];
        else if(q < 27) v = mw[(q-18)*1152 + c*9 + n];
        Wpm[j] = f2bf(v);
    } else {
        int j = i - 184320;                     // 32768
        int o = j & 127, c = j >> 7;
        Wpwt[c*128 + o] = pww[o*256 + c];
    }
}

// ---------------- K1: fused upsample+concat+depthwise256 -> Bo (8,256,64,64)
__global__ __launch_bounds__(256) void k_updw256(fp x1, fp x2, fp w, fp bias, float* Bo){
    __shared__ float sA[66*68 + 4];
    int bid = blockIdx.x;
    int c = bid & 255, b = bid >> 8;
    int tid = threadIdx.x;
    for(int j = tid; j < 264; j += 256){
        int idx;
        if(j < 66)       idx = j;
        else if(j < 132) idx = 65*68 + (j-66);
        else if(j < 196) idx = (j-132+1)*68;
        else if(j < 260) idx = (j-196+1)*68 + 65;
        else             idx = 66*68 + (j-260);
        sA[idx] = 0.f;
    }
    if(c < 128){
        const float* src = x2 + ((size_t)(b*128+c)<<12);
        for(int j = tid; j < 1024; j += 256){
            int yy = j >> 4, x4 = (j & 15) << 2;
            float4 v = *(const float4*)&src[(yy<<6) + x4];
            float* d = &sA[(yy+1)*68 + x4 + 1];
            d[0]=v.x; d[1]=v.y; d[2]=v.z; d[3]=v.w;
        }
    } else {
        int cc = c - 128;
        fp src = x1 + ((b*128+cc)<<10);
        const float s = 31.0f/63.0f;
        for(int j = tid; j < 4096; j += 256){
            int yy = j >> 6, xx = j & 63;
            float fy = yy*s, fx = xx*s;
            int iy = (int)fy; if (iy > 30) iy = 30;
            int ix = (int)fx; if (ix > 30) ix = 30;
            float ty = fy - (float)iy, tx = fx - (float)ix;
            float v00 = src[iy*32+ix],     v01 = src[iy*32+ix+1];
            float v10 = src[(iy+1)*32+ix], v11 = src[(iy+1)*32+ix+1];
            sA[(yy+1)*68 + xx + 1] =
                (v00*(1.f-ty)+v10*ty)*(1.f-tx) + (v01*(1.f-ty)+v11*ty)*tx;
        }
    }
    __syncthreads();
    float w0=w[c*9+0], w1=w[c*9+1], w2=w[c*9+2];
    float w3=w[c*9+3], w4=w[c*9+4], w5=w[c*9+5];
    float w6=w[c*9+6], w7=w[c*9+7], w8=w[c*9+8];
    float bv = bias[c];
    float* dst = Bo + ((size_t)(b*256+c)<<12);
    for(int j = tid; j < 1024; j += 256){
        int y = j >> 4, x0 = (j & 15) << 2;
        float a0=bv, a1=bv, a2=bv, a3=bv;
        #pragma unroll
        for(int ky=0; ky<3; ky++){
            const float* rr = &sA[(y+ky)*68 + x0];
            float4 u0 = *(const float4*)&rr[0];
            float2 u1 = *(const float2*)&rr[4];
            float wA = (ky==0)?w0:((ky==1)?w3:w6);
            float wB = (ky==0)?w1:((ky==1)?w4:w7);
            float wC = (ky==0)?w2:((ky==1)?w5:w8);
            a0 += wA*u0.x + wB*u0.y + wC*u0.z;
            a1 += wA*u0.y + wB*u0.z + wC*u0.w;
            a2 += wA*u0.z + wB*u0.w + wC*u1.x;
            a3 += wA*u0.w + wB*u1.x + wC*u1.y;
        }
        *(float4*)&dst[(y<<6)+x0] = make_float4(a0,a1,a2,a3);
    }
}

// ---------------- K3: pointwise 256->128 + bias -> Ccl (channel-last)
__global__ __launch_bounds__(256) void k_pw(const float* Bi, fp Wt, fp bias, float* Ccl){
    __shared__ float sIn[256*32];
    int bid = blockIdx.x;                       // 1024
    int b = bid >> 7;
    int pix0 = (bid & 127) << 5;
    int tid = threadIdx.x;
    for(int j = tid; j < 256*32; j += 256){
        int c = j >> 5, p = j & 31;
        sIn[j] = Bi[((b*256 + c)<<12) + pix0 + p];
    }
    __syncthreads();
    int og = tid >> 3, pg = tid & 7;
    int o0 = og*4, p0 = pg*4;
    float acc[4][4];
    #pragma unroll
    for(int i=0;i<4;i++){ float bv=bias[o0+i];
        #pragma unroll
        for(int j=0;j<4;j++) acc[i][j]=bv; }
    for(int c=0;c<256;c++){
        float4 xv = *(const float4*)&sIn[(c<<5)+p0];
        float4 w4 = *(const float4*)&Wt[(c<<7)+o0];
        acc[0][0]+=w4.x*xv.x; acc[0][1]+=w4.x*xv.y; acc[0][2]+=w4.x*xv.z; acc[0][3]+=w4.x*xv.w;
        acc[1][0]+=w4.y*xv.x; acc[1][1]+=w4.y*xv.y; acc[1][2]+=w4.y*xv.z; acc[1][3]+=w4.y*xv.w;
        acc[2][0]+=w4.z*xv.x; acc[2][1]+=w4.z*xv.y; acc[2][2]+=w4.z*xv.z; acc[2][3]+=w4.z*xv.w;
        acc[3][0]+=w4.w*xv.x; acc[3][1]+=w4.w*xv.y; acc[3][2]+=w4.w*xv.z; acc[3][3]+=w4.w*xv.w;
    }
    #pragma unroll
    for(int j=0;j<4;j++){
        int px = pix0 + p0 + j;
        *(float4*)&Ccl[((size_t)(b<<12) + px)*128 + o0] =
            make_float4(acc[0][j],acc[1][j],acc[2][j],acc[3][j]);
    }
}

// ---------------- K4: offset(18)+mask(9, sigmoid) 3x3 conv via bf16 MFMA -> OM (verified v1)
__global__ __launch_bounds__(256) void k_offmask(fp Ccl, const unsigned short* Wpm,
                                                 fp pb, fp mb, float* OM){
    __shared__ __align__(16) unsigned short sW[32*136];
    __shared__ __align__(16) unsigned short sX[64*136];
    int b = blockIdx.x & 7;
    int y = blockIdx.x >> 3;
    int pix0 = y << 6;
    int tid = threadIdx.x;
    int lane = tid & 63, wave = tid >> 6;
    int m16 = lane & 15, quad = lane >> 4;
    int wp = wave << 4;
    const float* cb = Ccl + (size_t)(b<<12)*128;

    short8 ap = {0,0,0,0,0,0,0,0}, bpr = {0,0,0,0,0,0,0,0};
    if(quad == 0){
        ap[0]  = (short)f2bf((float)m16);
        bpr[0] = (short)f2bf((float)(m16+100));
    }
    f32x4 dp = {0.f,0.f,0.f,0.f};
    dp = __builtin_amdgcn_mfma_f32_16x16x32_bf16(ap, bpr, dp, 0,0,0);
    bool p1 = true;
    #pragma unroll
    for(int r=0;r<4;r++){
        float expP1 = (float)(quad*4+r) * (float)(m16+100);
        p1 = p1 && (fabsf(dp[r]-expP1) < 0.5f);
    }
    bool swapD = (__ballot(p1) != 0xFFFFFFFFFFFFFFFFull);

    f32x4 acc[2];
    acc[0] = (f32x4){0.f,0.f,0.f,0.f};
    acc[1] = (f32x4){0.f,0.f,0.f,0.f};

    for(int n=0;n<9;n++){
        int ky = n/3, kx = n - ky*3;
        int yy = y + ky - 1;
        bool rowok = (yy>=0 && yy<64);
        const int4* wsrc = (const int4*)(Wpm + (n<<12));
        for(int j=tid; j<512; j+=256){
            int q = j >> 4, cg = j & 15;
            *(int4*)&sW[q*136 + (cg<<3)] = wsrc[j];
        }
        #pragma unroll
        for(int it=0; it<8; it++){
            int e = tid + (it<<8);
            int cg = (e & 31) << 2, px = e >> 5;
            int xx = px + kx - 1;
            float4 v = make_float4(0.f,0.f,0.f,0.f);
            if(rowok && xx>=0 && xx<64)
                v = *(const float4*)&cb[(size_t)((yy<<6)+xx)*128 + cg];
            unsigned long long pk = (unsigned long long)f2bf(v.x)
                | ((unsigned long long)f2bf(v.y)<<16)
                | ((unsigned long long)f2bf(v.z)<<32)
                | ((unsigned long long)f2bf(v.w)<<48);
            *(unsigned long long*)&sX[px*136 + cg] = pk;
        }
        __syncthreads();
        #pragma unroll
        for(int ks=0; ks<4; ks++){
            int k0 = ks << 5;
            short8 bfr = *(const short8*)&sX[(wp + m16)*136 + k0 + (quad<<3)];
            #pragma unroll
            for(int qt=0;qt<2;qt++){
                short8 afr = *(const short8*)&sW[((qt<<4) + m16)*136 + k0 + (quad<<3)];
                acc[qt] = __builtin_amdgcn_mfma_f32_16x16x32_bf16(afr, bfr, acc[qt], 0,0,0);
            }
        }
        __syncthreads();
    }
    if(!swapD){
        #pragma unroll
        for(int qt=0;qt<2;qt++){
            int px = pix0 + wp + m16;
            #pragma unroll
            for(int r=0;r<4;r++){
                int q = (qt<<4) + (quad<<2) + r;
                if(q < 27){
                    float v = acc[qt][r] + ((q<18) ? pb[q] : mb[q-18]);
                    if(q>=18) v = 1.f/(1.f+expf(-v));
                    OM[((b*27+q)<<12) + px] = v;
                }
            }
        }
    } else {
        #pragma unroll
        for(int qt=0;qt<2;qt++){
            int q = (qt<<4) + m16;
            if(q < 27){
                float bias = (q<18) ? pb[q] : mb[q-18];
                #pragma unroll
                for(int r=0;r<4;r++){
                    int px = pix0 + wp + (quad<<2) + r;
                    float v = acc[qt][r] + bias;
                    if(q>=18) v = 1.f/(1.f+expf(-v));
                    OM[((b*27+q)<<12) + px] = v;
                }
            }
        }
    }
}

// ---------------- K5 v8: deformable conv via LDS WINDOW staging.
// Model (r7): all prior variants moved ~96 KB/block/tap through VMEM -> per-CU
// delivery-bound at ~62 us. v8: 16x4-px 2D tiles (grid 512); stage the tile's
// full sampling footprint (8 rows x 20 cols x 128 ch, bf16) in LDS ONCE; build
// MFMA B-fragments in-lane from window (no sX, no gather barrier). Gather L2
// traffic per block: 589 KB -> 73 KB. Weights: reg-prefetch load-early/write-late
// into sW (v4-verified), bounds(256,2) so no VGPR squeeze. Fallback global load
// for |off|>=1 corners (never taken on this data; correctness-safe).
__device__ __forceinline__ uint4 corner_frag(unsigned ex, const unsigned short* sWin,
                                             const float* cb, int ch0){
    uint4 r;
    if(__builtin_expect((int)(ex >> 31), 0)){
        const float* src = cb + (((size_t)(ex & 0x7fffffffu)) << 7) + ch0;
        float4 a = *(const float4*)src;
        float4 d = *(const float4*)(src + 4);
        r.x = (unsigned)f2bf(a.x) | ((unsigned)f2bf(a.y)<<16);
        r.y = (unsigned)f2bf(a.z) | ((unsigned)f2bf(a.w)<<16);
        r.z = (unsigned)f2bf(d.x) | ((unsigned)f2bf(d.y)<<16);
        r.w = (unsigned)f2bf(d.z) | ((unsigned)f2bf(d.w)<<16);
    } else {
        const unsigned* p = (const unsigned*)&sWin[ex + ch0];
        r.x = p[0]; r.y = p[1]; r.z = p[2]; r.w = p[3];
    }
    return r;
}

#define ACC8(C, g) do{ \
    v0 += (g)*__uint_as_float((C).x<<16); v1 += (g)*__uint_as_float((C).x & 0xffff0000u); \
    v2 += (g)*__uint_as_float((C).y<<16); v3 += (g)*__uint_as_float((C).y & 0xffff0000u); \
    v4 += (g)*__uint_as_float((C).z<<16); v5 += (g)*__uint_as_float((C).z & 0xffff0000u); \
    v6 += (g)*__uint_as_float((C).w<<16); v7 += (g)*__uint_as_float((C).w & 0xffff0000u); }while(0)

#define K5_META(t, buf) do{ \
    int px_ = tid >> 2, k_ = tid & 3; \
    int yq_ = y0 + (px_ >> 4), xq_ = x0 + (px_ & 15); \
    int pix_ = (yq_<<6) + xq_; \
    int kyy_ = (t)/3, kxx_ = (t)-kyy_*3; \
    float oxv_ = omb[((t)<<12)+pix_]; \
    float oyv_ = omb[(((t)+9)<<12)+pix_]; \
    float mv_  = omb[(((t)+18)<<12)+pix_]; \
    float pxf_ = (float)(yq_ + kyy_) + oxv_; \
    float pyf_ = (float)(xq_ + kxx_) + oyv_; \
    float fx_ = floorf(pxf_), fy_ = floorf(pyf_); \
    float qx0_ = fminf(fmaxf(fx_,0.f),65.f),  qx1_ = fminf(fmaxf(fx_+1.f,0.f),65.f); \
    float qy0_ = fminf(fmaxf(fy_,0.f),65.f),  qy1_ = fminf(fmaxf(fy_+1.f,0.f),65.f); \
    float pxc_ = fminf(fmaxf(pxf_,0.f),65.f), pyc_ = fminf(fmaxf(pyf_,0.f),65.f); \
    float dx0_ = 1.f+(qx0_-pxc_), dx1_ = 1.f-(qx1_-pxc_); \
    float dy0_ = 1.f+(qy0_-pyc_), dy1_ = 1.f-(qy1_-pyc_); \
    int ax0_=(int)qx0_, ax1_=(int)qx1_, ay0_=(int)qy0_, ay1_=(int)qy1_; \
    bool vx0_ = (ax0_>=1)&&(ax0_<=64), vx1_ = (ax1_>=1)&&(ax1_<=64); \
    bool vy0_ = (ay0_>=1)&&(ay0_<=64), vy1_ = (ay1_>=1)&&(ay1_<=64); \
    int  axs_ = (k_&1) ? ax1_ : ax0_; \
    int  ays_ = (k_==1||k_==2) ? ay1_ : ay0_; \
    bool vxs_ = (k_&1) ? vx1_ : vx0_; \
    bool vys_ = (k_==1||k_==2) ? vy1_ : vy0_; \
    float dxs_ = (k_&1) ? dx1_ : dx0_; \
    float dys_ = (k_==1||k_==2) ? dy1_ : dy0_; \
    bool v_ = vxs_ && vys_; \
    float g_ = v_ ? dxs_*dys_*mv_ : 0.f; \
    unsigned enc_ = 0u; \
    if(v_){ \
        int wr_ = axs_ - 1 - (y0 - 2); \
        int wc_ = ays_ - 1 - (x0 - 2); \
        if(wr_>=0 && wr_<8 && wc_>=0 && wc_<20) enc_ = (unsigned)((wr_*20 + wc_)*132); \
        else enc_ = 0x80000000u | (unsigned)(((axs_-1)<<6)+(ays_-1)); \
    } \
    sM[buf][tid] = make_uint2(enc_, __float_as_uint(g_)); \
}while(0)

#define K5_LOADW(t) do{ \
    const int4* ws_ = (const int4*)(Wbf + ((t)<<14)); \
    _Pragma("unroll") \
    for(int k_=0;k_<8;k_++) wreg[k_] = ws_[tid + (k_<<8)]; }while(0)

#define K5_WRITEW() do{ \
    _Pragma("unroll") \
    for(int k_=0;k_<8;k_++){ int j_ = tid + (k_<<8); \
        *(int4*)&sW[(j_>>4)*136 + ((j_&15)<<3)] = wreg[k_]; } }while(0)

__global__ __launch_bounds__(256, 2) void k_deform(fp Ccl, fp OM, const unsigned short* Wbf,
                                                   float* D, float* stats){
    __shared__ __align__(16) unsigned short sWin[160*132];   // 42,240 B window (8x20 pos x 128 ch bf16)
    __shared__ __align__(16) unsigned short sW[128*136];     // 34,816 B weights [o][c]
    __shared__ __align__(8)  uint2 sM[2][256];               //  4,096 B meta dbuf (64 px x 4 corners)
    int b = blockIdx.x & 7;
    int tile = blockIdx.x >> 3;          // 64 tiles: 16 y-tiles x 4 x-tiles
    int y0 = (tile >> 2) << 2;           // tile = 4 rows
    int x0 = (tile & 3) << 4;            //        x 16 cols
    int tid = threadIdx.x;
    int lane = tid & 63, wave = tid >> 6;
    int m16 = lane & 15, quad = lane >> 4;
    const float* omb = OM + b*27*4096;
    const float* cb  = Ccl + ((size_t)(b)<<12)*128;

    // ---- probe
    short8 ap = {0,0,0,0,0,0,0,0}, bpr = {0,0,0,0,0,0,0,0};
    if(quad == 0){
        ap[0]  = (short)f2bf((float)m16);
        bpr[0] = (short)f2bf((float)(m16+100));
    }
    f32x4 dp = {0.f,0.f,0.f,0.f};
    dp = __builtin_amdgcn_mfma_f32_16x16x32_bf16(ap, bpr, dp, 0,0,0);
    bool p1 = true;
    #pragma unroll
    for(int r=0;r<4;r++){
        float expP1 = (float)(quad*4+r) * (float)(m16+100);
        p1 = p1 && (fabsf(dp[r]-expP1) < 0.5f);
    }
    bool swapD = (__ballot(p1) != 0xFFFFFFFFFFFFFFFFull);

    f32x4 acc[8];                        // 8 o-tiles x (wave's 16 px row)
    #pragma unroll
    for(int i=0;i<8;i++) acc[i] = (f32x4){0.f,0.f,0.f,0.f};
    int4 wreg[8];                        // weight staging regs (static indices)

    // ---- prologue: issue W(0) loads, stage window (covers latency), meta(0), write sW
    K5_LOADW(0);
    for(int i = tid; i < 5120; i += 256){        // 160 pos x 32 ch-groups
        int pos = i >> 5, cg = (i & 31) << 2;
        int wr = pos/20, wc = pos - wr*20;
        int gy = y0 - 2 + wr, gx = x0 - 2 + wc;
        float4 v = make_float4(0.f,0.f,0.f,0.f);
        if(gy>=0 && gy<64 && gx>=0 && gx<64)
            v = *(const float4*)&cb[((size_t)((gy<<6)+gx)<<7) + cg];
        unsigned long long pk = (unsigned long long)f2bf(v.x)
            | ((unsigned long long)f2bf(v.y)<<16)
            | ((unsigned long long)f2bf(v.z)<<32)
            | ((unsigned long long)f2bf(v.w)<<48);
        *(unsigned long long*)&sWin[pos*132 + cg] = pk;
    }
    K5_META(0, 0);
    K5_WRITEW();
    __syncthreads();                      // window, sM[0], sW(0) ready

    int px_local = (wave << 4) + m16;     // this lane's pixel (B-frag col = m16)
    for(int n=0;n<9;n++){
        if(n<8) K5_LOADW(n+1);            // issue next-tap W loads early
        // meta for this tap (4 corners, broadcast across quads)
        const uint2* mp = &sM[n&1][px_local<<2];
        uint2 e0 = mp[0], e1 = mp[1], e2 = mp[2], e3 = mp[3];
        float g0 = __uint_as_float(e0.y), g1 = __uint_as_float(e1.y);
        float g2 = __uint_as_float(e2.y), g3 = __uint_as_float(e3.y);
        #pragma unroll
        for(int ks=0; ks<4; ks++){
            int ch0 = (ks<<5) + (quad<<3);
            uint4 c0 = corner_frag(e0.x, sWin, cb, ch0);
            uint4 c1 = corner_frag(e1.x, sWin, cb, ch0);
            uint4 c2 = corner_frag(e2.x, sWin, cb, ch0);
            uint4 c3 = corner_frag(e3.x, sWin, cb, ch0);
            float v0=0.f,v1=0.f,v2=0.f,v3=0.f,v4=0.f,v5=0.f,v6=0.f,v7=0.f;
            ACC8(c0, g0); ACC8(c1, g1); ACC8(c2, g2); ACC8(c3, g3);
            union { uint4 u; short8 s; } bu;
            bu.u.x = (unsigned)f2bf(v0) | ((unsigned)f2bf(v1)<<16);
            bu.u.y = (unsigned)f2bf(v2) | ((unsigned)f2bf(v3)<<16);
            bu.u.z = (unsigned)f2bf(v4) | ((unsigned)f2bf(v5)<<16);
            bu.u.w = (unsigned)f2bf(v6) | ((unsigned)f2bf(v7)<<16);
            #pragma unroll
            for(int ot=0; ot<8; ot++){
                short8 afr = *(const short8*)&sW[((ot<<4)+m16)*136 + (ks<<5) + (quad<<3)];
                acc[ot] = __builtin_amdgcn_mfma_f32_16x16x32_bf16(afr, bu.s, acc[ot], 0,0,0);
            }
        }
        if(n<8) K5_META(n+1, (n+1)&1);    // writes other sM buffer (not read this phase)
        __syncthreads();                  // MFMA(n) done: sW free, sM[(n+1)&1] complete
        if(n<8){
            K5_WRITEW();                  // sW <- W(n+1) from regs (latency already covered)
            __syncthreads();              // sW(n+1) ready
        }
    }

    // epilogue: D writes + per-channel sum/sumsq (stats LDS overlaid on dead window)
    float* sdq = (float*)&sWin[0];        // [0..127]=sum, [128..255]=sumsq
    sdq[tid] = 0.f;
    __syncthreads();
    int ybase = ((y0 + wave) << 6) + x0;  // this wave's output row
    if(!swapD){
        #pragma unroll
        for(int ot=0;ot<8;ot++){
            #pragma unroll
            for(int r=0;r<4;r++){
                int o = (ot<<4) + (quad<<2) + r;
                D[((b*128+o)<<12) + ybase + m16] = acc[ot][r];
            }
        }
        #pragma unroll
        for(int ot=0;ot<8;ot++){
            #pragma unroll
            for(int r=0;r<4;r++){
                float s  = acc[ot][r];
                float s2 = s*s;
                #pragma unroll
                for(int msk=1; msk<16; msk<<=1){
                    s  += __shfl_xor(s, msk, 64);
                    s2 += __shfl_xor(s2, msk, 64);
                }
                if(m16 == 0){
                    int o = (ot<<4) + (quad<<2) + r;
                    atomicAdd(&sdq[o], s);
                    atomicAdd(&sdq[128+o], s2);
                }
            }
        }
    } else {
        #pragma unroll
        for(int ot=0;ot<8;ot++){
            int o = (ot<<4) + m16;
            #pragma unroll
            for(int r=0;r<4;r++){
                D[((b*128+o)<<12) + ybase + (quad<<2) + r] = acc[ot][r];
            }
        }
        #pragma unroll
        for(int ot=0;ot<8;ot++){
            float s = 0.f, s2 = 0.f;
            #pragma unroll
            for(int r=0;r<4;r++){
                float v = acc[ot][r];
                s += v; s2 += v*v;
            }
            #pragma unroll
            for(int msk=16; msk<64; msk<<=1){
                s  += __shfl_xor(s, msk, 64);
                s2 += __shfl_xor(s2, msk, 64);
            }
            if(quad == 0){
                int o = (ot<<4) + m16;
                atomicAdd(&sdq[o], s);
                atomicAdd(&sdq[128+o], s2);
            }
        }
    }
    __syncthreads();
    if(tid < 128){
        atomicAdd(&stats[tid],     sdq[tid]);
        atomicAdd(&stats[128+tid], sdq[128+tid]);
    }
}

// ---------------- K7: fused BN1+GELU + depthwise128 -> Hs, + atomic stats2 partials
__global__ __launch_bounds__(256) void k_bngelu_dw128(const float* Dsrc, float* stats,
                                                      fp g1, fp b1, fp w, fp bias, float* Hs){
    __shared__ float sG[66*68 + 4];
    __shared__ float sd[256], sq[256];
    int bid = blockIdx.x;
    int c = bid & 127, b = bid >> 7;
    int tid = threadIdx.x;
    float mean1 = stats[c] * (1.f/32768.f);
    float var1  = stats[128+c] * (1.f/32768.f) - mean1*mean1;
    float rstd1 = rsqrtf(var1 + 1e-5f);
    float sc = rstd1 * g1[c];
    float sb = b1[c] - mean1*sc;
    for(int j = tid; j < 264; j += 256){
        int idx;
        if(j < 66)       idx = j;
        else if(j < 132) idx = 65*68 + (j-66);
        else if(j < 196) idx = (j-132+1)*68;
        else if(j < 260) idx = (j-196+1)*68 + 65;
        else             idx = 66*68 + (j-260);
        sG[idx] = 0.f;
    }
    const float* dplane = Dsrc + ((size_t)(b*128+c)<<12);
    for(int j = tid; j < 1024; j += 256){
        int yy = j >> 4, x4 = (j & 15) << 2;
        float4 v = *(const float4*)&dplane[(yy<<6) + x4];
        float g0 = v.x*sc+sb, g1v = v.y*sc+sb, g2 = v.z*sc+sb, g3 = v.w*sc+sb;
        float* d = &sG[(yy+1)*68 + x4 + 1];
        d[0] = 0.5f*g0*(1.0f + erff(g0*0.70710678118654752f));
        d[1] = 0.5f*g1v*(1.0f + erff(g1v*0.70710678118654752f));
        d[2] = 0.5f*g2*(1.0f + erff(g2*0.70710678118654752f));
        d[3] = 0.5f*g3*(1.0f + erff(g3*0.70710678118654752f));
    }
    __syncthreads();
    float w0=w[c*9+0], w1=w[c*9+1], w2=w[c*9+2];
    float w3=w[c*9+3], w4=w[c*9+4], w5=w[c*9+5];
    float w6=w[c*9+6], w7=w[c*9+7], w8=w[c*9+8];
    float bv = bias[c];
    float* dst = Hs + ((size_t)(b*128+c)<<12);
    float s = 0.f, s2 = 0.f;
    for(int j = tid; j < 1024; j += 256){
        int y = j >> 4, x0 = (j & 15) << 2;
        float a0=bv, a1=bv, a2=bv, a3=bv;
        #pragma unroll
        for(int ky=0; ky<3; ky++){
            const float* rr = &sG[(y+ky)*68 + x0];
            float4 u0 = *(const float4*)&rr[0];
            float2 u1 = *(const float2*)&rr[4];
            float wA = (ky==0)?w0:((ky==1)?w3:w6);
            float wB = (ky==0)?w1:((ky==1)?w4:w7);
            float wC = (ky==0)?w2:((ky==1)?w5:w8);
            a0 += wA*u0.x + wB*u0.y + wC*u0.z;
            a1 += wA*u0.y + wB*u0.z + wC*u0.w;
            a2 += wA*u0.z + wB*u0.w + wC*u1.x;
            a3 += wA*u0.w + wB*u1.x + wC*u1.y;
        }
        *(float4*)&dst[(y<<6)+x0] = make_float4(a0,a1,a2,a3);
        s += a0+a1+a2+a3;
        s2 += a0*a0 + a1*a1 + a2*a2 + a3*a3;
    }
    sd[tid]=s; sq[tid]=s2; __syncthreads();
    for(int off=128; off>0; off>>=1){
        if(tid<off){ sd[tid]+=sd[tid+off]; sq[tid]+=sq[tid+off]; }
        __syncthreads();
    }
    if(tid==0){
        atomicAdd(&stats[256+c], sd[0]);
        atomicAdd(&stats[384+c], sq[0]);
    }
}

// ---------------- BN2 + ReLU -> f32 out
__global__ __launch_bounds__(256) void k_bn_relu_out(const float* Hs, const float* stats, fp g, fp bb, float* out){
    int idx = blockIdx.x*256+threadIdx.x;
    int c = (idx>>10)&127;
    float mean2 = stats[256+c] * (1.f/32768.f);
    float var2  = stats[384+c] * (1.f/32768.f) - mean2*mean2;
    float rs = rsqrtf(var2 + 1e-5f) * g[c];
    float sb = bb[c] - mean2*rs;
    float4 v = ((const float4*)Hs)[idx];
    float4 o;
    o.x = fmaxf(v.x*rs+sb, 0.f);
    o.y = fmaxf(v.y*rs+sb, 0.f);
    o.z = fmaxf(v.z*rs+sb, 0.f);
    o.w = fmaxf(v.w*rs+sb, 0.f);
    ((float4*)out)[idx] = o;
}

extern "C" void kernel_launch(void* const* d_in, const int* in_sizes, int n_in,
                              void* d_out, int out_size, void* d_ws, size_t ws_size,
                              hipStream_t stream){
    fp x1   = (fp)d_in[0];
    fp x2   = (fp)d_in[1];
    fp dw_w = (fp)d_in[2];  fp dw_b = (fp)d_in[3];
    fp pw_w = (fp)d_in[4];  fp pw_b = (fp)d_in[5];
    fp p_w  = (fp)d_in[6];  fp p_b  = (fp)d_in[7];
    fp m_w  = (fp)d_in[8];  fp m_b  = (fp)d_in[9];
    fp dcn_w= (fp)d_in[10];
    fp bn1g = (fp)d_in[11]; fp bn1b = (fp)d_in[12];
    fp dw2w = (fp)d_in[13]; fp dw2b = (fp)d_in[14];
    fp bn2g = (fp)d_in[15]; fp bn2b = (fp)d_in[16];

    float* ws  = (float*)d_ws;
    float* Bo  = ws;                    // (8,256,4096) ; D reuses after k_pw
    float* Ccl = ws + 8388608;          // (8,4096,128) ; Hs reuses after k_deform
    float* OM  = ws + 12582912;         // (8,27,4096)
    unsigned short* Wbf = (unsigned short*)(ws + 13467648);
    unsigned short* Wpm = (unsigned short*)(ws + 13541376);
    float* stats = ws + 13559808;       // 512 f
    float* Wpwt  = ws + 13560320;       // 32,768 f
    float* D   = Bo;
    float* Hs  = Ccl;
    float* out = (float*)d_out;

    hipMemsetAsync(stats, 0, 512*sizeof(float), stream);
    k_prep         <<<848,   256, 0, stream>>>(dcn_w, p_w, m_w, pw_w, Wbf, Wpm, Wpwt);
    k_updw256      <<<2048,  256, 0, stream>>>(x1, x2, dw_w, dw_b, Bo);
    k_pw           <<<1024,  256, 0, stream>>>(Bo, Wpwt, pw_b, Ccl);
    k_offmask      <<<512,   256, 0, stream>>>(Ccl, Wpm, p_b, m_b, OM);
    k_deform       <<<512,   256, 0, stream>>>(Ccl, OM, Wbf, D, stats);
    k_bngelu_dw128 <<<1024,  256, 0, stream>>>(D, stats, bn1g, bn1b, dw2w, dw2b, Hs);
    k_bn_relu_out  <<<4096,  256, 0, stream>>>(Hs, stats, bn2g, bn2b, out);
}

// Round 10
// 251.482 us; speedup vs baseline: 1.0770x; 1.0770x over previous
//
#include <hip/hip_runtime.h>
#include <math.h>

// Problem constants: B=8, spatial 64x64 (HW=4096), C_mid=256, C=128, N=9 taps.
typedef const float* fp;
typedef __attribute__((ext_vector_type(8))) short short8;   // 8 bf16 = 4 VGPRs (MFMA A/B frag)
typedef __attribute__((ext_vector_type(4))) float f32x4;    // MFMA C/D frag

__device__ __forceinline__ unsigned short f2bf(float f){    // RTNE float->bf16
    unsigned u = __float_as_uint(f);
    u += 0x7fff + ((u >> 16) & 1);
    return (unsigned short)(u >> 16);
}

// ---------------- K0: merged prep — Wbf[n][o][c] bf16, Wpm[n][32q][128c] bf16, Wpwt[c][128o] f32
__global__ __launch_bounds__(256) void k_prep(fp dcn_w, fp pw, fp mw, fp pww,
                                              unsigned short* Wbf, unsigned short* Wpm, float* Wpwt){
    int i = blockIdx.x*256 + threadIdx.x;       // 217088 = 848 blocks
    if(i < 147456){
        int c = i & 127, o = (i >> 7) & 127, n = i >> 14;
        Wbf[i] = f2bf(dcn_w[o*1152 + c*9 + n]);
    } else if(i < 184320){
        int j = i - 147456;
        int c = j & 127, q = (j >> 7) & 31, n = j >> 12;
        float v = 0.f;
        if(q < 18)      v = pw[q*1152 + c*9 + n];
        else if(q < 27) v = mw[(q-18)*1152 + c*9 + n];
        Wpm[j] = f2bf(v);
    } else {
        int j = i - 184320;                     // 32768
        int o = j & 127, c = j >> 7;
        Wpwt[c*128 + o] = pww[o*256 + c];
    }
}

// ---------------- K1: fused upsample+concat+depthwise256 -> Bo (8,256,64,64)
__global__ __launch_bounds__(256) void k_updw256(fp x1, fp x2, fp w, fp bias, float* Bo){
    __shared__ float sA[66*68 + 4];
    int bid = blockIdx.x;
    int c = bid & 255, b = bid >> 8;
    int tid = threadIdx.x;
    for(int j = tid; j < 264; j += 256){
        int idx;
        if(j < 66)       idx = j;
        else if(j < 132) idx = 65*68 + (j-66);
        else if(j < 196) idx = (j-132+1)*68;
        else if(j < 260) idx = (j-196+1)*68 + 65;
        else             idx = 66*68 + (j-260);
        sA[idx] = 0.f;
    }
    if(c < 128){
        const float* src = x2 + ((size_t)(b*128+c)<<12);
        for(int j = tid; j < 1024; j += 256){
            int yy = j >> 4, x4 = (j & 15) << 2;
            float4 v = *(const float4*)&src[(yy<<6) + x4];
            float* d = &sA[(yy+1)*68 + x4 + 1];
            d[0]=v.x; d[1]=v.y; d[2]=v.z; d[3]=v.w;
        }
    } else {
        int cc = c - 128;
        fp src = x1 + ((b*128+cc)<<10);
        const float s = 31.0f/63.0f;
        for(int j = tid; j < 4096; j += 256){
            int yy = j >> 6, xx = j & 63;
            float fy = yy*s, fx = xx*s;
            int iy = (int)fy; if (iy > 30) iy = 30;
            int ix = (int)fx; if (ix > 30) ix = 30;
            float ty = fy - (float)iy, tx = fx - (float)ix;
            float v00 = src[iy*32+ix],     v01 = src[iy*32+ix+1];
            float v10 = src[(iy+1)*32+ix], v11 = src[(iy+1)*32+ix+1];
            sA[(yy+1)*68 + xx + 1] =
                (v00*(1.f-ty)+v10*ty)*(1.f-tx) + (v01*(1.f-ty)+v11*ty)*tx;
        }
    }
    __syncthreads();
    float w0=w[c*9+0], w1=w[c*9+1], w2=w[c*9+2];
    float w3=w[c*9+3], w4=w[c*9+4], w5=w[c*9+5];
    float w6=w[c*9+6], w7=w[c*9+7], w8=w[c*9+8];
    float bv = bias[c];
    float* dst = Bo + ((size_t)(b*256+c)<<12);
    for(int j = tid; j < 1024; j += 256){
        int y = j >> 4, x0 = (j & 15) << 2;
        float a0=bv, a1=bv, a2=bv, a3=bv;
        #pragma unroll
        for(int ky=0; ky<3; ky++){
            const float* rr = &sA[(y+ky)*68 + x0];
            float4 u0 = *(const float4*)&rr[0];
            float2 u1 = *(const float2*)&rr[4];
            float wA = (ky==0)?w0:((ky==1)?w3:w6);
            float wB = (ky==0)?w1:((ky==1)?w4:w7);
            float wC = (ky==0)?w2:((ky==1)?w5:w8);
            a0 += wA*u0.x + wB*u0.y + wC*u0.z;
            a1 += wA*u0.y + wB*u0.z + wC*u0.w;
            a2 += wA*u0.z + wB*u0.w + wC*u1.x;
            a3 += wA*u0.w + wB*u1.x + wC*u1.y;
        }
        *(float4*)&dst[(y<<6)+x0] = make_float4(a0,a1,a2,a3);
    }
}

// ---------------- K3: pointwise 256->128 + bias -> Ccl (channel-last)
__global__ __launch_bounds__(256) void k_pw(const float* Bi, fp Wt, fp bias, float* Ccl){
    __shared__ float sIn[256*32];
    int bid = blockIdx.x;                       // 1024
    int b = bid >> 7;
    int pix0 = (bid & 127) << 5;
    int tid = threadIdx.x;
    for(int j = tid; j < 256*32; j += 256){
        int c = j >> 5, p = j & 31;
        sIn[j] = Bi[((b*256 + c)<<12) + pix0 + p];
    }
    __syncthreads();
    int og = tid >> 3, pg = tid & 7;
    int o0 = og*4, p0 = pg*4;
    float acc[4][4];
    #pragma unroll
    for(int i=0;i<4;i++){ float bv=bias[o0+i];
        #pragma unroll
        for(int j=0;j<4;j++) acc[i][j]=bv; }
    for(int c=0;c<256;c++){
        float4 xv = *(const float4*)&sIn[(c<<5)+p0];
        float4 w4 = *(const float4*)&Wt[(c<<7)+o0];
        acc[0][0]+=w4.x*xv.x; acc[0][1]+=w4.x*xv.y; acc[0][2]+=w4.x*xv.z; acc[0][3]+=w4.x*xv.w;
        acc[1][0]+=w4.y*xv.x; acc[1][1]+=w4.y*xv.y; acc[1][2]+=w4.y*xv.z; acc[1][3]+=w4.y*xv.w;
        acc[2][0]+=w4.z*xv.x; acc[2][1]+=w4.z*xv.y; acc[2][2]+=w4.z*xv.z; acc[2][3]+=w4.z*xv.w;
        acc[3][0]+=w4.w*xv.x; acc[3][1]+=w4.w*xv.y; acc[3][2]+=w4.w*xv.z; acc[3][3]+=w4.w*xv.w;
    }
    #pragma unroll
    for(int j=0;j<4;j++){
        int px = pix0 + p0 + j;
        *(float4*)&Ccl[((size_t)(b<<12) + px)*128 + o0] =
            make_float4(acc[0][j],acc[1][j],acc[2][j],acc[3][j]);
    }
}

// ---------------- K4 v3: offset+mask conv via bf16 MFMA with ONE-SHOT window staging.
// The 9 taps read a fixed +-1 neighborhood -> stage rows y-1..y+1 x 66 cols x 128 ch
// bf16 ONCE (53.9 KB); taps read shifted views, no re-staging. Weights double-
// buffered (2 int4/thread, load-early/write-late); one barrier/tap for sW swap.
// LDS 71,264 B -> 2 blocks/CU (= grid coverage).
__global__ __launch_bounds__(256, 2) void k_offmask(fp Ccl, const unsigned short* Wpm,
                                                    fp pb, fp mb, float* OM){
    __shared__ __align__(16) unsigned short sWin[3*66*136];  // 53,856 B [r][col][c]
    __shared__ __align__(16) unsigned short sW[2][32*136];   // 17,408 B dbuf [q][c]
    int b = blockIdx.x & 7;
    int y = blockIdx.x >> 3;          // output row
    int pix0 = y << 6;
    int tid = threadIdx.x;
    int lane = tid & 63, wave = tid >> 6;
    int m16 = lane & 15, quad = lane >> 4;
    int wp = wave << 4;               // px-subtile
    const float* cb = Ccl + (size_t)(b<<12)*128;

    // ---- probe: D[m][n]=m*(n+100)
    short8 ap = {0,0,0,0,0,0,0,0}, bpr = {0,0,0,0,0,0,0,0};
    if(quad == 0){
        ap[0]  = (short)f2bf((float)m16);
        bpr[0] = (short)f2bf((float)(m16+100));
    }
    f32x4 dp = {0.f,0.f,0.f,0.f};
    dp = __builtin_amdgcn_mfma_f32_16x16x32_bf16(ap, bpr, dp, 0,0,0);
    bool p1 = true;
    #pragma unroll
    for(int r=0;r<4;r++){
        float expP1 = (float)(quad*4+r) * (float)(m16+100);
        p1 = p1 && (fabsf(dp[r]-expP1) < 0.5f);
    }
    bool swapD = (__ballot(p1) != 0xFFFFFFFFFFFFFFFFull);

    f32x4 acc[2];
    acc[0] = (f32x4){0.f,0.f,0.f,0.f};
    acc[1] = (f32x4){0.f,0.f,0.f,0.f};

    // ---- prologue: issue W(0) loads, stage window (covers latency), write sW[0]
    {
        const int4* wsrc = (const int4*)Wpm;
        int4 wA_ = wsrc[tid], wB_ = wsrc[tid + 256];
        for(int i = tid; i < 6336; i += 256){        // 198 pos x 32 cg
            int pos = i >> 5, cg = (i & 31) << 2;
            int r = pos / 66, col = pos - r*66;
            int yy = y + r - 1, xx = col - 1;
            float4 v = make_float4(0.f,0.f,0.f,0.f);
            if(yy>=0 && yy<64 && xx>=0 && xx<64)
                v = *(const float4*)&cb[(size_t)((yy<<6)+xx)*128 + cg];
            unsigned long long pk = (unsigned long long)f2bf(v.x)
                | ((unsigned long long)f2bf(v.y)<<16)
                | ((unsigned long long)f2bf(v.z)<<32)
                | ((unsigned long long)f2bf(v.w)<<48);
            *(unsigned long long*)&sWin[pos*136 + cg] = pk;
        }
        *(int4*)&sW[0][(tid>>4)*136 + ((tid&15)<<3)] = wA_;
        int j = tid + 256;
        *(int4*)&sW[0][(j>>4)*136 + ((j&15)<<3)] = wB_;
    }
    __syncthreads();

    for(int n=0;n<9;n++){
        int4 wA_, wB_;
        if(n<8){
            const int4* wsrc = (const int4*)(Wpm + ((n+1)<<12));
            wA_ = wsrc[tid]; wB_ = wsrc[tid + 256];   // issue early; MFMA covers latency
        }
        int ky = n/3, kx = n - ky*3;
        const unsigned short* base = &sWin[(ky*66 + wp + kx)*136];
        #pragma unroll
        for(int ks=0; ks<4; ks++){
            int k0 = ks << 5;
            short8 bfr = *(const short8*)&base[m16*136 + k0 + (quad<<3)];
            #pragma unroll
            for(int qt=0;qt<2;qt++){
                short8 afr = *(const short8*)&sW[n&1][((qt<<4) + m16)*136 + k0 + (quad<<3)];
                acc[qt] = __builtin_amdgcn_mfma_f32_16x16x32_bf16(afr, bfr, acc[qt], 0,0,0);
            }
        }
        if(n<8){
            *(int4*)&sW[(n+1)&1][(tid>>4)*136 + ((tid&15)<<3)] = wA_;
            int j = tid + 256;
            *(int4*)&sW[(n+1)&1][(j>>4)*136 + ((j&15)<<3)] = wB_;
        }
        __syncthreads();
    }
    if(!swapD){
        #pragma unroll
        for(int qt=0;qt<2;qt++){
            int px = pix0 + wp + m16;
            #pragma unroll
            for(int r=0;r<4;r++){
                int q = (qt<<4) + (quad<<2) + r;
                if(q < 27){
                    float v = acc[qt][r] + ((q<18) ? pb[q] : mb[q-18]);
                    if(q>=18) v = 1.f/(1.f+expf(-v));
                    OM[((b*27+q)<<12) + px] = v;
                }
            }
        }
    } else {
        #pragma unroll
        for(int qt=0;qt<2;qt++){
            int q = (qt<<4) + m16;
            if(q < 27){
                float bias = (q<18) ? pb[q] : mb[q-18];
                #pragma unroll
                for(int r=0;r<4;r++){
                    int px = pix0 + wp + (quad<<2) + r;
                    float v = acc[qt][r] + bias;
                    if(q>=18) v = 1.f/(1.f+expf(-v));
                    OM[((b*27+q)<<12) + px] = v;
                }
            }
        }
    }
}

// ---------------- K5 v6 (verified 62 us): deformable sampling + bf16 MFMA combine.
// sW staged in LDS (2 barriers/tap, bounds(256,3)) + single-buffered sM meta (1 KB)
// computed one slot ahead in the same inter-barrier phase as the sW stage.
// LDS = 34,816 + 17,408 + 1,024 = 53,248 B -> 3 blocks/CU exactly.
// NOTE: 32-px tiles -> REQUIRES grid 1024 (r9 failure was launching this at 512).
#define K5_META(t) do{ if(tid < 128){ \
    int px_ = tid >> 2, k_ = tid & 3; \
    int pix_ = pix0 + px_; \
    int yq_ = pix_ >> 6, xq_ = pix_ & 63; \
    int kyy_ = (t)/3, kxx_ = (t)-kyy_*3; \
    float oxv_ = omb[((t)<<12)+pix_]; \
    float oyv_ = omb[(((t)+9)<<12)+pix_]; \
    float mv_  = omb[(((t)+18)<<12)+pix_]; \
    float pxf_ = (float)(yq_ + kyy_) + oxv_; \
    float pyf_ = (float)(xq_ + kxx_) + oyv_; \
    float fx_ = floorf(pxf_), fy_ = floorf(pyf_); \
    float qx0_ = fminf(fmaxf(fx_,0.f),65.f),  qx1_ = fminf(fmaxf(fx_+1.f,0.f),65.f); \
    float qy0_ = fminf(fmaxf(fy_,0.f),65.f),  qy1_ = fminf(fmaxf(fy_+1.f,0.f),65.f); \
    float pxc_ = fminf(fmaxf(pxf_,0.f),65.f), pyc_ = fminf(fmaxf(pyf_,0.f),65.f); \
    float dx0_ = 1.f+(qx0_-pxc_), dx1_ = 1.f-(qx1_-pxc_); \
    float dy0_ = 1.f+(qy0_-pyc_), dy1_ = 1.f-(qy1_-pyc_); \
    int ax0_=(int)qx0_, ax1_=(int)qx1_, ay0_=(int)qy0_, ay1_=(int)qy1_; \
    bool vx0_ = (ax0_>=1)&&(ax0_<=64), vx1_ = (ax1_>=1)&&(ax1_<=64); \
    bool vy0_ = (ay0_>=1)&&(ay0_<=64), vy1_ = (ay1_>=1)&&(ay1_<=64); \
    int  axs_ = (k_&1) ? ax1_ : ax0_; \
    int  ays_ = (k_==1||k_==2) ? ay1_ : ay0_; \
    bool vxs_ = (k_&1) ? vx1_ : vx0_; \
    bool vys_ = (k_==1||k_==2) ? vy1_ : vy0_; \
    float dxs_ = (k_&1) ? dx1_ : dx0_; \
    float dys_ = (k_==1||k_==2) ? dy1_ : dy0_; \
    bool v_ = vxs_ && vys_; \
    int base_ = v_ ? (((axs_-1)<<6)+(ays_-1)) : 0; \
    float g_ = v_ ? dxs_*dys_*mv_ : 0.f; \
    sM[tid] = make_uint2((unsigned)base_, __float_as_uint(g_)); \
} }while(0)

#define K5_GATHER(bufp) do{ \
    _Pragma("unroll") \
    for(int j_=0;j_<4;j_++){ \
        int px_ = pxb + (j_<<3); \
        uint2 e0_ = sM[(px_<<2)+0]; \
        uint2 e1_ = sM[(px_<<2)+1]; \
        uint2 e2_ = sM[(px_<<2)+2]; \
        uint2 e3_ = sM[(px_<<2)+3]; \
        float g0_ = __uint_as_float(e0_.y), g1_ = __uint_as_float(e1_.y); \
        float g2_ = __uint_as_float(e2_.y), g3_ = __uint_as_float(e3_.y); \
        float4 r0_ = *(const float4*)&cb[((size_t)e0_.x<<7) + cg4]; \
        float4 r1_ = *(const float4*)&cb[((size_t)e1_.x<<7) + cg4]; \
        float4 r2_ = *(const float4*)&cb[((size_t)e2_.x<<7) + cg4]; \
        float4 r3_ = *(const float4*)&cb[((size_t)e3_.x<<7) + cg4]; \
        float vx_ = g0_*r0_.x + g1_*r1_.x + g2_*r2_.x + g3_*r3_.x; \
        float vy_ = g0_*r0_.y + g1_*r1_.y + g2_*r2_.y + g3_*r3_.y; \
        float vz_ = g0_*r0_.z + g1_*r1_.z + g2_*r2_.z + g3_*r3_.z; \
        float vw_ = g0_*r0_.w + g1_*r1_.w + g2_*r2_.w + g3_*r3_.w; \
        unsigned long long pk_ = (unsigned long long)f2bf(vx_) \
            | ((unsigned long long)f2bf(vy_)<<16) \
            | ((unsigned long long)f2bf(vz_)<<32) \
            | ((unsigned long long)f2bf(vw_)<<48); \
        *(unsigned long long*)&(bufp)[px_*136 + cg4] = pk_; \
    } }while(0)

#define K5_STAGE_W(t) do{ \
    const int4* wsrc_ = (const int4*)(Wbf + ((t)<<14)); \
    _Pragma("unroll") \
    for(int k_=0;k_<8;k_++){ int j_ = tid + (k_<<8); \
        *(int4*)&sW[(j_>>4)*136 + ((j_&15)<<3)] = wsrc_[j_]; } }while(0)

#define K5_DOMFMA(srcp) do{ \
    _Pragma("unroll") \
    for(int ks_=0; ks_<4; ks_++){ \
        int k0_ = ks_ << 5; \
        short8 bfr0 = *(const short8*)&(srcp)[(m16)*136 + k0_ + (quad<<3)]; \
        short8 bfr1 = *(const short8*)&(srcp)[(16 + m16)*136 + k0_ + (quad<<3)]; \
        _Pragma("unroll") \
        for(int ot_=0;ot_<2;ot_++){ \
            short8 afr = *(const short8*)&sW[(wo + (ot_<<4) + m16)*136 + k0_ + (quad<<3)]; \
            acc[ot_][0] = __builtin_amdgcn_mfma_f32_16x16x32_bf16(afr, bfr0, acc[ot_][0], 0,0,0); \
            acc[ot_][1] = __builtin_amdgcn_mfma_f32_16x16x32_bf16(afr, bfr1, acc[ot_][1], 0,0,0); \
        } } }while(0)

__global__ __launch_bounds__(256, 3) void k_deform(fp Ccl, fp OM, const unsigned short* Wbf,
                                                   float* D, float* stats){
    __shared__ __align__(16) unsigned short sW[128*136];     // 34,816 B [o][c]
    __shared__ __align__(16) unsigned short sX[2][32*136];   // 17,408 B dbuf [px][c]
    __shared__ __align__(8)  uint2 sM[128];                  //  1,024 B meta (base,weight)
    int b = blockIdx.x & 7;
    int pix0 = (blockIdx.x >> 3) << 5;   // 128 tiles x 32 px
    int tid = threadIdx.x;
    int lane = tid & 63, wave = tid >> 6;
    int m16 = lane & 15, quad = lane >> 4;
    int wo = wave << 5;                  // each wave owns 32 output channels
    int cg4 = (tid & 31) << 2;           // channel group (4 ch)
    int pxb = tid >> 5;                  // base px 0..7 (handles px pxb, +8, +16, +24)
    const float* omb = OM + b*27*4096;
    const float* cb  = Ccl + ((size_t)(b)<<12)*128;

    // ---- probe
    short8 ap = {0,0,0,0,0,0,0,0}, bpr = {0,0,0,0,0,0,0,0};
    if(quad == 0){
        ap[0]  = (short)f2bf((float)m16);
        bpr[0] = (short)f2bf((float)(m16+100));
    }
    f32x4 dp = {0.f,0.f,0.f,0.f};
    dp = __builtin_amdgcn_mfma_f32_16x16x32_bf16(ap, bpr, dp, 0,0,0);
    bool p1 = true;
    #pragma unroll
    for(int r=0;r<4;r++){
        float expP1 = (float)(quad*4+r) * (float)(m16+100);
        p1 = p1 && (fabsf(dp[r]-expP1) < 0.5f);
    }
    bool swapD = (__ballot(p1) != 0xFFFFFFFFFFFFFFFFull);

    f32x4 acc[2][2];                     // [ot][pt]
    #pragma unroll
    for(int i=0;i<2;i++){
        #pragma unroll
        for(int j=0;j<2;j++) acc[i][j] = (f32x4){0.f,0.f,0.f,0.f};
    }

    // ---- prologue
    K5_META(0);
    __syncthreads();                      // sM = meta(0)
    K5_GATHER((&sX[0][0]));               // gather(0) using meta(0)
    K5_STAGE_W(0);
    __syncthreads();                      // sX[0], sW(0) ready; sM reads done
    K5_META(1);
    __syncthreads();                      // sM = meta(1)

    for(int n=0;n<9;n++){
        if(n<8) K5_GATHER((&sX[(n+1)&1][0]));  // uses sM = meta(n+1); overlaps MFMA(n)
        K5_DOMFMA((&sX[n&1][0]));              // operands from LDS (sW, sX)
        __syncthreads();                       // sW/sM reads + sX writes done
        if(n<8){
            K5_STAGE_W(n+1);                   // sW <- W(n+1), transient regs
            if(n<7) K5_META(n+2);              // sM <- meta(n+2)
            __syncthreads();                   // sW, sM ready for next iter
        }
    }

    // epilogue: D writes + per-channel sum/sumsq reduction (stats LDS overlaid on dead sX)
    float* sdq = (float*)&sX[0][0];       // [0..127]=sum, [128..255]=sumsq
    sdq[tid] = 0.f;                       // 256 threads init 256 floats
    __syncthreads();
    if(!swapD){
        #pragma unroll
        for(int ot=0;ot<2;ot++){
            #pragma unroll
            for(int pt=0;pt<2;pt++){
                int px = pix0 + (pt<<4) + m16;
                #pragma unroll
                for(int r=0;r<4;r++){
                    int o = wo + (ot<<4) + (quad<<2) + r;
                    D[((b*128+o)<<12) + px] = acc[ot][pt][r];
                }
            }
        }
        #pragma unroll
        for(int ot=0;ot<2;ot++){
            #pragma unroll
            for(int r=0;r<4;r++){
                float s  = acc[ot][0][r] + acc[ot][1][r];
                float s2 = acc[ot][0][r]*acc[ot][0][r] + acc[ot][1][r]*acc[ot][1][r];
                #pragma unroll
                for(int msk=1; msk<16; msk<<=1){
                    s  += __shfl_xor(s, msk, 64);
                    s2 += __shfl_xor(s2, msk, 64);
                }
                if(m16 == 0){
                    int o = wo + (ot<<4) + (quad<<2) + r;
                    atomicAdd(&sdq[o], s);
                    atomicAdd(&sdq[128+o], s2);
                }
            }
        }
    } else {
        #pragma unroll
        for(int ot=0;ot<2;ot++){
            #pragma unroll
            for(int pt=0;pt<2;pt++){
                int o = wo + (ot<<4) + m16;
                #pragma unroll
                for(int r=0;r<4;r++){
                    int px = pix0 + (pt<<4) + (quad<<2) + r;
                    D[((b*128+o)<<12) + px] = acc[ot][pt][r];
                }
            }
        }
        #pragma unroll
        for(int ot=0;ot<2;ot++){
            float s = 0.f, s2 = 0.f;
            #pragma unroll
            for(int pt=0;pt<2;pt++){
                #pragma unroll
                for(int r=0;r<4;r++){
                    float v = acc[ot][pt][r];
                    s += v; s2 += v*v;
                }
            }
            #pragma unroll
            for(int msk=16; msk<64; msk<<=1){
                s  += __shfl_xor(s, msk, 64);
                s2 += __shfl_xor(s2, msk, 64);
            }
            if(quad == 0){
                int o = wo + (ot<<4) + m16;
                atomicAdd(&sdq[o], s);
                atomicAdd(&sdq[128+o], s2);
            }
        }
    }
    __syncthreads();
    if(tid < 128){
        atomicAdd(&stats[tid],     sdq[tid]);
        atomicAdd(&stats[128+tid], sdq[128+tid]);
    }
}

// ---------------- K7: fused BN1+GELU + depthwise128 -> Hs, + atomic stats2 partials
__global__ __launch_bounds__(256) void k_bngelu_dw128(const float* Dsrc, float* stats,
                                                      fp g1, fp b1, fp w, fp bias, float* Hs){
    __shared__ float sG[66*68 + 4];
    __shared__ float sd[256], sq[256];
    int bid = blockIdx.x;
    int c = bid & 127, b = bid >> 7;
    int tid = threadIdx.x;
    float mean1 = stats[c] * (1.f/32768.f);
    float var1  = stats[128+c] * (1.f/32768.f) - mean1*mean1;
    float rstd1 = rsqrtf(var1 + 1e-5f);
    float sc = rstd1 * g1[c];
    float sb = b1[c] - mean1*sc;
    for(int j = tid; j < 264; j += 256){
        int idx;
        if(j < 66)       idx = j;
        else if(j < 132) idx = 65*68 + (j-66);
        else if(j < 196) idx = (j-132+1)*68;
        else if(j < 260) idx = (j-196+1)*68 + 65;
        else             idx = 66*68 + (j-260);
        sG[idx] = 0.f;
    }
    const float* dplane = Dsrc + ((size_t)(b*128+c)<<12);
    for(int j = tid; j < 1024; j += 256){
        int yy = j >> 4, x4 = (j & 15) << 2;
        float4 v = *(const float4*)&dplane[(yy<<6) + x4];
        float g0 = v.x*sc+sb, g1v = v.y*sc+sb, g2 = v.z*sc+sb, g3 = v.w*sc+sb;
        float* d = &sG[(yy+1)*68 + x4 + 1];
        d[0] = 0.5f*g0*(1.0f + erff(g0*0.70710678118654752f));
        d[1] = 0.5f*g1v*(1.0f + erff(g1v*0.70710678118654752f));
        d[2] = 0.5f*g2*(1.0f + erff(g2*0.70710678118654752f));
        d[3] = 0.5f*g3*(1.0f + erff(g3*0.70710678118654752f));
    }
    __syncthreads();
    float w0=w[c*9+0], w1=w[c*9+1], w2=w[c*9+2];
    float w3=w[c*9+3], w4=w[c*9+4], w5=w[c*9+5];
    float w6=w[c*9+6], w7=w[c*9+7], w8=w[c*9+8];
    float bv = bias[c];
    float* dst = Hs + ((size_t)(b*128+c)<<12);
    float s = 0.f, s2 = 0.f;
    for(int j = tid; j < 1024; j += 256){
        int y = j >> 4, x0 = (j & 15) << 2;
        float a0=bv, a1=bv, a2=bv, a3=bv;
        #pragma unroll
        for(int ky=0; ky<3; ky++){
            const float* rr = &sG[(y+ky)*68 + x0];
            float4 u0 = *(const float4*)&rr[0];
            float2 u1 = *(const float2*)&rr[4];
            float wA = (ky==0)?w0:((ky==1)?w3:w6);
            float wB = (ky==0)?w1:((ky==1)?w4:w7);
            float wC = (ky==0)?w2:((ky==1)?w5:w8);
            a0 += wA*u0.x + wB*u0.y + wC*u0.z;
            a1 += wA*u0.y + wB*u0.z + wC*u0.w;
            a2 += wA*u0.z + wB*u0.w + wC*u1.x;
            a3 += wA*u0.w + wB*u1.x + wC*u1.y;
        }
        *(float4*)&dst[(y<<6)+x0] = make_float4(a0,a1,a2,a3);
        s += a0+a1+a2+a3;
        s2 += a0*a0 + a1*a1 + a2*a2 + a3*a3;
    }
    sd[tid]=s; sq[tid]=s2; __syncthreads();
    for(int off=128; off>0; off>>=1){
        if(tid<off){ sd[tid]+=sd[tid+off]; sq[tid]+=sq[tid+off]; }
        __syncthreads();
    }
    if(tid==0){
        atomicAdd(&stats[256+c], sd[0]);
        atomicAdd(&stats[384+c], sq[0]);
    }
}

// ---------------- BN2 + ReLU -> f32 out
__global__ __launch_bounds__(256) void k_bn_relu_out(const float* Hs, const float* stats, fp g, fp bb, float* out){
    int idx = blockIdx.x*256+threadIdx.x;
    int c = (idx>>10)&127;
    float mean2 = stats[256+c] * (1.f/32768.f);
    float var2  = stats[384+c] * (1.f/32768.f) - mean2*mean2;
    float rs = rsqrtf(var2 + 1e-5f) * g[c];
    float sb = bb[c] - mean2*rs;
    float4 v = ((const float4*)Hs)[idx];
    float4 o;
    o.x = fmaxf(v.x*rs+sb, 0.f);
    o.y = fmaxf(v.y*rs+sb, 0.f);
    o.z = fmaxf(v.z*rs+sb, 0.f);
    o.w = fmaxf(v.w*rs+sb, 0.f);
    ((float4*)out)[idx] = o;
}

extern "C" void kernel_launch(void* const* d_in, const int* in_sizes, int n_in,
                              void* d_out, int out_size, void* d_ws, size_t ws_size,
                              hipStream_t stream){
    fp x1   = (fp)d_in[0];
    fp x2   = (fp)d_in[1];
    fp dw_w = (fp)d_in[2];  fp dw_b = (fp)d_in[3];
    fp pw_w = (fp)d_in[4];  fp pw_b = (fp)d_in[5];
    fp p_w  = (fp)d_in[6];  fp p_b  = (fp)d_in[7];
    fp m_w  = (fp)d_in[8];  fp m_b  = (fp)d_in[9];
    fp dcn_w= (fp)d_in[10];
    fp bn1g = (fp)d_in[11]; fp bn1b = (fp)d_in[12];
    fp dw2w = (fp)d_in[13]; fp dw2b = (fp)d_in[14];
    fp bn2g = (fp)d_in[15]; fp bn2b = (fp)d_in[16];

    float* ws  = (float*)d_ws;
    float* Bo  = ws;                    // (8,256,4096) ; D reuses after k_pw
    float* Ccl = ws + 8388608;          // (8,4096,128) ; Hs reuses after k_deform
    float* OM  = ws + 12582912;         // (8,27,4096)
    unsigned short* Wbf = (unsigned short*)(ws + 13467648);
    unsigned short* Wpm = (unsigned short*)(ws + 13541376);
    float* stats = ws + 13559808;       // 512 f
    float* Wpwt  = ws + 13560320;       // 32,768 f
    float* D   = Bo;
    float* Hs  = Ccl;
    float* out = (float*)d_out;

    hipMemsetAsync(stats, 0, 512*sizeof(float), stream);
    k_prep         <<<848,   256, 0, stream>>>(dcn_w, p_w, m_w, pw_w, Wbf, Wpm, Wpwt);
    k_updw256      <<<2048,  256, 0, stream>>>(x1, x2, dw_w, dw_b, Bo);
    k_pw           <<<1024,  256, 0, stream>>>(Bo, Wpwt, pw_b, Ccl);
    k_offmask      <<<512,   256, 0, stream>>>(Ccl, Wpm, p_b, m_b, OM);
    k_deform       <<<1024,  256, 0, stream>>>(Ccl, OM, Wbf, D, stats);   // v6 needs 1024 (r9 bug: 512)
    k_bngelu_dw128 <<<1024,  256, 0, stream>>>(D, stats, bn1g, bn1b, dw2w, dw2b, Hs);
    k_bn_relu_out  <<<4096,  256, 0, stream>>>(Hs, stats, bn2g, bn2b, out);
}

// Round 11
// 242.241 us; speedup vs baseline: 1.1181x; 1.0381x over previous
//
#include <hip/hip_runtime.h>
#include <math.h>

// Problem constants: B=8, spatial 64x64 (HW=4096), C_mid=256, C=128, N=9 taps.
typedef const float* fp;
typedef __attribute__((ext_vector_type(8))) short short8;   // 8 bf16 = 4 VGPRs (MFMA A/B frag)
typedef __attribute__((ext_vector_type(4))) float f32x4;    // MFMA C/D frag

__device__ __forceinline__ unsigned short f2bf(float f){    // RTNE float->bf16
    unsigned u = __float_as_uint(f);
    u += 0x7fff + ((u >> 16) & 1);
    return (unsigned short)(u >> 16);
}

// ---------------- K0: merged prep — Wbf[n][o][c] bf16, Wpm[n][32q][128c] bf16, Wpwt[c][128o] f32
__global__ __launch_bounds__(256) void k_prep(fp dcn_w, fp pw, fp mw, fp pww,
                                              unsigned short* Wbf, unsigned short* Wpm, float* Wpwt){
    int i = blockIdx.x*256 + threadIdx.x;       // 217088 = 848 blocks
    if(i < 147456){
        int c = i & 127, o = (i >> 7) & 127, n = i >> 14;
        Wbf[i] = f2bf(dcn_w[o*1152 + c*9 + n]);
    } else if(i < 184320){
        int j = i - 147456;
        int c = j & 127, q = (j >> 7) & 31, n = j >> 12;
        float v = 0.f;
        if(q < 18)      v = pw[q*1152 + c*9 + n];
        else if(q < 27) v = mw[(q-18)*1152 + c*9 + n];
        Wpm[j] = f2bf(v);
    } else {
        int j = i - 184320;                     // 32768
        int o = j & 127, c = j >> 7;
        Wpwt[c*128 + o] = pww[o*256 + c];
    }
}

// ---------------- K1: fused upsample+concat+depthwise256 -> Bo (8,256,64,64)
__global__ __launch_bounds__(256) void k_updw256(fp x1, fp x2, fp w, fp bias, float* Bo){
    __shared__ float sA[66*68 + 4];
    int bid = blockIdx.x;
    int c = bid & 255, b = bid >> 8;
    int tid = threadIdx.x;
    for(int j = tid; j < 264; j += 256){
        int idx;
        if(j < 66)       idx = j;
        else if(j < 132) idx = 65*68 + (j-66);
        else if(j < 196) idx = (j-132+1)*68;
        else if(j < 260) idx = (j-196+1)*68 + 65;
        else             idx = 66*68 + (j-260);
        sA[idx] = 0.f;
    }
    if(c < 128){
        const float* src = x2 + ((size_t)(b*128+c)<<12);
        for(int j = tid; j < 1024; j += 256){
            int yy = j >> 4, x4 = (j & 15) << 2;
            float4 v = *(const float4*)&src[(yy<<6) + x4];
            float* d = &sA[(yy+1)*68 + x4 + 1];
            d[0]=v.x; d[1]=v.y; d[2]=v.z; d[3]=v.w;
        }
    } else {
        int cc = c - 128;
        fp src = x1 + ((b*128+cc)<<10);
        const float s = 31.0f/63.0f;
        for(int j = tid; j < 4096; j += 256){
            int yy = j >> 6, xx = j & 63;
            float fy = yy*s, fx = xx*s;
            int iy = (int)fy; if (iy > 30) iy = 30;
            int ix = (int)fx; if (ix > 30) ix = 30;
            float ty = fy - (float)iy, tx = fx - (float)ix;
            float v00 = src[iy*32+ix],     v01 = src[iy*32+ix+1];
            float v10 = src[(iy+1)*32+ix], v11 = src[(iy+1)*32+ix+1];
            sA[(yy+1)*68 + xx + 1] =
                (v00*(1.f-ty)+v10*ty)*(1.f-tx) + (v01*(1.f-ty)+v11*ty)*tx;
        }
    }
    __syncthreads();
    float w0=w[c*9+0], w1=w[c*9+1], w2=w[c*9+2];
    float w3=w[c*9+3], w4=w[c*9+4], w5=w[c*9+5];
    float w6=w[c*9+6], w7=w[c*9+7], w8=w[c*9+8];
    float bv = bias[c];
    float* dst = Bo + ((size_t)(b*256+c)<<12);
    for(int j = tid; j < 1024; j += 256){
        int y = j >> 4, x0 = (j & 15) << 2;
        float a0=bv, a1=bv, a2=bv, a3=bv;
        #pragma unroll
        for(int ky=0; ky<3; ky++){
            const float* rr = &sA[(y+ky)*68 + x0];
            float4 u0 = *(const float4*)&rr[0];
            float2 u1 = *(const float2*)&rr[4];
            float wA = (ky==0)?w0:((ky==1)?w3:w6);
            float wB = (ky==0)?w1:((ky==1)?w4:w7);
            float wC = (ky==0)?w2:((ky==1)?w5:w8);
            a0 += wA*u0.x + wB*u0.y + wC*u0.z;
            a1 += wA*u0.y + wB*u0.z + wC*u0.w;
            a2 += wA*u0.z + wB*u0.w + wC*u1.x;
            a3 += wA*u0.w + wB*u1.x + wC*u1.y;
        }
        *(float4*)&dst[(y<<6)+x0] = make_float4(a0,a1,a2,a3);
    }
}

// ---------------- K3: pointwise 256->128 + bias -> Ccl (channel-last)
__global__ __launch_bounds__(256) void k_pw(const float* Bi, fp Wt, fp bias, float* Ccl){
    __shared__ float sIn[256*32];
    int bid = blockIdx.x;                       // 1024
    int b = bid >> 7;
    int pix0 = (bid & 127) << 5;
    int tid = threadIdx.x;
    for(int j = tid; j < 256*32; j += 256){
        int c = j >> 5, p = j & 31;
        sIn[j] = Bi[((b*256 + c)<<12) + pix0 + p];
    }
    __syncthreads();
    int og = tid >> 3, pg = tid & 7;
    int o0 = og*4, p0 = pg*4;
    float acc[4][4];
    #pragma unroll
    for(int i=0;i<4;i++){ float bv=bias[o0+i];
        #pragma unroll
        for(int j=0;j<4;j++) acc[i][j]=bv; }
    for(int c=0;c<256;c++){
        float4 xv = *(const float4*)&sIn[(c<<5)+p0];
        float4 w4 = *(const float4*)&Wt[(c<<7)+o0];
        acc[0][0]+=w4.x*xv.x; acc[0][1]+=w4.x*xv.y; acc[0][2]+=w4.x*xv.z; acc[0][3]+=w4.x*xv.w;
        acc[1][0]+=w4.y*xv.x; acc[1][1]+=w4.y*xv.y; acc[1][2]+=w4.y*xv.z; acc[1][3]+=w4.y*xv.w;
        acc[2][0]+=w4.z*xv.x; acc[2][1]+=w4.z*xv.y; acc[2][2]+=w4.z*xv.z; acc[2][3]+=w4.z*xv.w;
        acc[3][0]+=w4.w*xv.x; acc[3][1]+=w4.w*xv.y; acc[3][2]+=w4.w*xv.z; acc[3][3]+=w4.w*xv.w;
    }
    #pragma unroll
    for(int j=0;j<4;j++){
        int px = pix0 + p0 + j;
        *(float4*)&Ccl[((size_t)(b<<12) + px)*128 + o0] =
            make_float4(acc[0][j],acc[1][j],acc[2][j],acc[3][j]);
    }
}

// ---------------- K4 v3 (verified): offset+mask conv, one-shot window staging.
__global__ __launch_bounds__(256, 2) void k_offmask(fp Ccl, const unsigned short* Wpm,
                                                    fp pb, fp mb, float* OM){
    __shared__ __align__(16) unsigned short sWin[3*66*136];  // 53,856 B [r][col][c]
    __shared__ __align__(16) unsigned short sW[2][32*136];   // 17,408 B dbuf [q][c]
    int b = blockIdx.x & 7;
    int y = blockIdx.x >> 3;          // output row
    int pix0 = y << 6;
    int tid = threadIdx.x;
    int lane = tid & 63, wave = tid >> 6;
    int m16 = lane & 15, quad = lane >> 4;
    int wp = wave << 4;               // px-subtile
    const float* cb = Ccl + (size_t)(b<<12)*128;

    // ---- probe: D[m][n]=m*(n+100)
    short8 ap = {0,0,0,0,0,0,0,0}, bpr = {0,0,0,0,0,0,0,0};
    if(quad == 0){
        ap[0]  = (short)f2bf((float)m16);
        bpr[0] = (short)f2bf((float)(m16+100));
    }
    f32x4 dp = {0.f,0.f,0.f,0.f};
    dp = __builtin_amdgcn_mfma_f32_16x16x32_bf16(ap, bpr, dp, 0,0,0);
    bool p1 = true;
    #pragma unroll
    for(int r=0;r<4;r++){
        float expP1 = (float)(quad*4+r) * (float)(m16+100);
        p1 = p1 && (fabsf(dp[r]-expP1) < 0.5f);
    }
    bool swapD = (__ballot(p1) != 0xFFFFFFFFFFFFFFFFull);

    f32x4 acc[2];
    acc[0] = (f32x4){0.f,0.f,0.f,0.f};
    acc[1] = (f32x4){0.f,0.f,0.f,0.f};

    // ---- prologue: issue W(0) loads, stage window (covers latency), write sW[0]
    {
        const int4* wsrc = (const int4*)Wpm;
        int4 wA_ = wsrc[tid], wB_ = wsrc[tid + 256];
        for(int i = tid; i < 6336; i += 256){        // 198 pos x 32 cg
            int pos = i >> 5, cg = (i & 31) << 2;
            int r = pos / 66, col = pos - r*66;
            int yy = y + r - 1, xx = col - 1;
            float4 v = make_float4(0.f,0.f,0.f,0.f);
            if(yy>=0 && yy<64 && xx>=0 && xx<64)
                v = *(const float4*)&cb[(size_t)((yy<<6)+xx)*128 + cg];
            unsigned long long pk = (unsigned long long)f2bf(v.x)
                | ((unsigned long long)f2bf(v.y)<<16)
                | ((unsigned long long)f2bf(v.z)<<32)
                | ((unsigned long long)f2bf(v.w)<<48);
            *(unsigned long long*)&sWin[pos*136 + cg] = pk;
        }
        *(int4*)&sW[0][(tid>>4)*136 + ((tid&15)<<3)] = wA_;
        int j = tid + 256;
        *(int4*)&sW[0][(j>>4)*136 + ((j&15)<<3)] = wB_;
    }
    __syncthreads();

    for(int n=0;n<9;n++){
        int4 wA_, wB_;
        if(n<8){
            const int4* wsrc = (const int4*)(Wpm + ((n+1)<<12));
            wA_ = wsrc[tid]; wB_ = wsrc[tid + 256];   // issue early; MFMA covers latency
        }
        int ky = n/3, kx = n - ky*3;
        const unsigned short* base = &sWin[(ky*66 + wp + kx)*136];
        #pragma unroll
        for(int ks=0; ks<4; ks++){
            int k0 = ks << 5;
            short8 bfr = *(const short8*)&base[m16*136 + k0 + (quad<<3)];
            #pragma unroll
            for(int qt=0;qt<2;qt++){
                short8 afr = *(const short8*)&sW[n&1][((qt<<4) + m16)*136 + k0 + (quad<<3)];
                acc[qt] = __builtin_amdgcn_mfma_f32_16x16x32_bf16(afr, bfr, acc[qt], 0,0,0);
            }
        }
        if(n<8){
            *(int4*)&sW[(n+1)&1][(tid>>4)*136 + ((tid&15)<<3)] = wA_;
            int j = tid + 256;
            *(int4*)&sW[(n+1)&1][(j>>4)*136 + ((j&15)<<3)] = wB_;
        }
        __syncthreads();
    }
    if(!swapD){
        #pragma unroll
        for(int qt=0;qt<2;qt++){
            int px = pix0 + wp + m16;
            #pragma unroll
            for(int r=0;r<4;r++){
                int q = (qt<<4) + (quad<<2) + r;
                if(q < 27){
                    float v = acc[qt][r] + ((q<18) ? pb[q] : mb[q-18]);
                    if(q>=18) v = 1.f/(1.f+expf(-v));
                    OM[((b*27+q)<<12) + px] = v;
                }
            }
        }
    } else {
        #pragma unroll
        for(int qt=0;qt<2;qt++){
            int q = (qt<<4) + m16;
            if(q < 27){
                float bias = (q<18) ? pb[q] : mb[q-18];
                #pragma unroll
                for(int r=0;r<4;r++){
                    int px = pix0 + wp + (quad<<2) + r;
                    float v = acc[qt][r] + bias;
                    if(q>=18) v = 1.f/(1.f+expf(-v));
                    OM[((b*27+q)<<12) + px] = v;
                }
            }
        }
    }
}

// ---------------- K5 v9: deformable sampling + bf16 MFMA combine — 512-thr / 64-px blocks.
// v6 machinery re-indexed: grid 512 (one row per tile x 8 b) = exactly 2 blocks/CU,
// ALL blocks resident (zero tail). 8 waves: wave w -> o-range (w&3)*32, px-half w>>2.
// Weight staging (32KB/tap) amortized over 2x pixels; 18 barriers per 2x work.
// LDS = 34,816(sW) + 34,816(sX dbuf) + 2,048(sM) = 71,680 B.
#define K5_META(t) do{ if(tid < 256){ \
    int px_ = tid >> 2, k_ = tid & 3; \
    int pix_ = pix0 + px_; \
    int yq_ = pix_ >> 6, xq_ = pix_ & 63; \
    int kyy_ = (t)/3, kxx_ = (t)-kyy_*3; \
    float oxv_ = omb[((t)<<12)+pix_]; \
    float oyv_ = omb[(((t)+9)<<12)+pix_]; \
    float mv_  = omb[(((t)+18)<<12)+pix_]; \
    float pxf_ = (float)(yq_ + kyy_) + oxv_; \
    float pyf_ = (float)(xq_ + kxx_) + oyv_; \
    float fx_ = floorf(pxf_), fy_ = floorf(pyf_); \
    float qx0_ = fminf(fmaxf(fx_,0.f),65.f),  qx1_ = fminf(fmaxf(fx_+1.f,0.f),65.f); \
    float qy0_ = fminf(fmaxf(fy_,0.f),65.f),  qy1_ = fminf(fmaxf(fy_+1.f,0.f),65.f); \
    float pxc_ = fminf(fmaxf(pxf_,0.f),65.f), pyc_ = fminf(fmaxf(pyf_,0.f),65.f); \
    float dx0_ = 1.f+(qx0_-pxc_), dx1_ = 1.f-(qx1_-pxc_); \
    float dy0_ = 1.f+(qy0_-pyc_), dy1_ = 1.f-(qy1_-pyc_); \
    int ax0_=(int)qx0_, ax1_=(int)qx1_, ay0_=(int)qy0_, ay1_=(int)qy1_; \
    bool vx0_ = (ax0_>=1)&&(ax0_<=64), vx1_ = (ax1_>=1)&&(ax1_<=64); \
    bool vy0_ = (ay0_>=1)&&(ay0_<=64), vy1_ = (ay1_>=1)&&(ay1_<=64); \
    int  axs_ = (k_&1) ? ax1_ : ax0_; \
    int  ays_ = (k_==1||k_==2) ? ay1_ : ay0_; \
    bool vxs_ = (k_&1) ? vx1_ : vx0_; \
    bool vys_ = (k_==1||k_==2) ? vy1_ : vy0_; \
    float dxs_ = (k_&1) ? dx1_ : dx0_; \
    float dys_ = (k_==1||k_==2) ? dy1_ : dy0_; \
    bool v_ = vxs_ && vys_; \
    int base_ = v_ ? (((axs_-1)<<6)+(ays_-1)) : 0; \
    float g_ = v_ ? dxs_*dys_*mv_ : 0.f; \
    sM[tid] = make_uint2((unsigned)base_, __float_as_uint(g_)); \
} }while(0)

#define K5_GATHER(bufp) do{ \
    _Pragma("unroll") \
    for(int j_=0;j_<4;j_++){ \
        int px_ = pxb + (j_<<4); \
        uint2 e0_ = sM[(px_<<2)+0]; \
        uint2 e1_ = sM[(px_<<2)+1]; \
        uint2 e2_ = sM[(px_<<2)+2]; \
        uint2 e3_ = sM[(px_<<2)+3]; \
        float g0_ = __uint_as_float(e0_.y), g1_ = __uint_as_float(e1_.y); \
        float g2_ = __uint_as_float(e2_.y), g3_ = __uint_as_float(e3_.y); \
        float4 r0_ = *(const float4*)&cb[((size_t)e0_.x<<7) + cg4]; \
        float4 r1_ = *(const float4*)&cb[((size_t)e1_.x<<7) + cg4]; \
        float4 r2_ = *(const float4*)&cb[((size_t)e2_.x<<7) + cg4]; \
        float4 r3_ = *(const float4*)&cb[((size_t)e3_.x<<7) + cg4]; \
        float vx_ = g0_*r0_.x + g1_*r1_.x + g2_*r2_.x + g3_*r3_.x; \
        float vy_ = g0_*r0_.y + g1_*r1_.y + g2_*r2_.y + g3_*r3_.y; \
        float vz_ = g0_*r0_.z + g1_*r1_.z + g2_*r2_.z + g3_*r3_.z; \
        float vw_ = g0_*r0_.w + g1_*r1_.w + g2_*r2_.w + g3_*r3_.w; \
        unsigned long long pk_ = (unsigned long long)f2bf(vx_) \
            | ((unsigned long long)f2bf(vy_)<<16) \
            | ((unsigned long long)f2bf(vz_)<<32) \
            | ((unsigned long long)f2bf(vw_)<<48); \
        *(unsigned long long*)&(bufp)[px_*136 + cg4] = pk_; \
    } }while(0)

#define K5_STAGE_W(t) do{ \
    const int4* wsrc_ = (const int4*)(Wbf + ((t)<<14)); \
    _Pragma("unroll") \
    for(int k_=0;k_<4;k_++){ int j_ = tid + (k_<<9); \
        *(int4*)&sW[(j_>>4)*136 + ((j_&15)<<3)] = wsrc_[j_]; } }while(0)

#define K5_DOMFMA(srcp) do{ \
    _Pragma("unroll") \
    for(int ks_=0; ks_<4; ks_++){ \
        int k0_ = ks_ << 5; \
        short8 bfr0 = *(const short8*)&(srcp)[(phb + m16)*136 + k0_ + (quad<<3)]; \
        short8 bfr1 = *(const short8*)&(srcp)[(phb + 16 + m16)*136 + k0_ + (quad<<3)]; \
        _Pragma("unroll") \
        for(int ot_=0;ot_<2;ot_++){ \
            short8 afr = *(const short8*)&sW[(wo + (ot_<<4) + m16)*136 + k0_ + (quad<<3)]; \
            acc[ot_][0] = __builtin_amdgcn_mfma_f32_16x16x32_bf16(afr, bfr0, acc[ot_][0], 0,0,0); \
            acc[ot_][1] = __builtin_amdgcn_mfma_f32_16x16x32_bf16(afr, bfr1, acc[ot_][1], 0,0,0); \
        } } }while(0)

__global__ __launch_bounds__(512, 4) void k_deform(fp Ccl, fp OM, const unsigned short* Wbf,
                                                   float* D, float* stats){
    __shared__ __align__(16) unsigned short sW[128*136];     // 34,816 B [o][c]
    __shared__ __align__(16) unsigned short sX[2][64*136];   // 34,816 B dbuf [px][c]
    __shared__ __align__(8)  uint2 sM[256];                  //  2,048 B meta (base,weight)
    int b = blockIdx.x & 7;
    int pix0 = (blockIdx.x >> 3) << 6;   // 64 tiles (one row each) x 8 b
    int tid = threadIdx.x;               // 0..511
    int lane = tid & 63, wave = tid >> 6;
    int m16 = lane & 15, quad = lane >> 4;
    int wo  = (wave & 3) << 5;           // o-range: 4 groups of 32
    int phb = (wave >> 2) << 5;          // px-half: 0 / 32
    int cg4 = (tid & 31) << 2;           // channel group (4 ch)
    int pxb = tid >> 5;                  // base px 0..15 (handles px pxb, +16, +32, +48)
    const float* omb = OM + b*27*4096;
    const float* cb  = Ccl + ((size_t)(b)<<12)*128;

    // ---- probe
    short8 ap = {0,0,0,0,0,0,0,0}, bpr = {0,0,0,0,0,0,0,0};
    if(quad == 0){
        ap[0]  = (short)f2bf((float)m16);
        bpr[0] = (short)f2bf((float)(m16+100));
    }
    f32x4 dp = {0.f,0.f,0.f,0.f};
    dp = __builtin_amdgcn_mfma_f32_16x16x32_bf16(ap, bpr, dp, 0,0,0);
    bool p1 = true;
    #pragma unroll
    for(int r=0;r<4;r++){
        float expP1 = (float)(quad*4+r) * (float)(m16+100);
        p1 = p1 && (fabsf(dp[r]-expP1) < 0.5f);
    }
    bool swapD = (__ballot(p1) != 0xFFFFFFFFFFFFFFFFull);

    f32x4 acc[2][2];                     // [ot][pt]
    #pragma unroll
    for(int i=0;i<2;i++){
        #pragma unroll
        for(int j=0;j<2;j++) acc[i][j] = (f32x4){0.f,0.f,0.f,0.f};
    }

    // ---- prologue
    K5_META(0);
    __syncthreads();                      // sM = meta(0)
    K5_GATHER((&sX[0][0]));               // gather(0) using meta(0)
    K5_STAGE_W(0);
    __syncthreads();                      // sX[0], sW(0) ready; sM reads done
    K5_META(1);
    __syncthreads();                      // sM = meta(1)

    for(int n=0;n<9;n++){
        if(n<8) K5_GATHER((&sX[(n+1)&1][0]));  // uses sM = meta(n+1); overlaps MFMA(n)
        K5_DOMFMA((&sX[n&1][0]));              // operands from LDS (sW, sX)
        __syncthreads();                       // sW/sM reads + sX writes done
        if(n<8){
            K5_STAGE_W(n+1);                   // sW <- W(n+1), transient regs
            if(n<7) K5_META(n+2);              // sM <- meta(n+2)
            __syncthreads();                   // sW, sM ready for next iter
        }
    }

    // epilogue: D writes + per-channel sum/sumsq reduction (stats LDS overlaid on dead sX)
    float* sdq = (float*)&sX[0][0];       // [0..127]=sum, [128..255]=sumsq
    if(tid < 256) sdq[tid] = 0.f;
    __syncthreads();
    if(!swapD){
        #pragma unroll
        for(int ot=0;ot<2;ot++){
            #pragma unroll
            for(int pt=0;pt<2;pt++){
                int px = pix0 + phb + (pt<<4) + m16;
                #pragma unroll
                for(int r=0;r<4;r++){
                    int o = wo + (ot<<4) + (quad<<2) + r;
                    D[((b*128+o)<<12) + px] = acc[ot][pt][r];
                }
            }
        }
        #pragma unroll
        for(int ot=0;ot<2;ot++){
            #pragma unroll
            for(int r=0;r<4;r++){
                float s  = acc[ot][0][r] + acc[ot][1][r];
                float s2 = acc[ot][0][r]*acc[ot][0][r] + acc[ot][1][r]*acc[ot][1][r];
                #pragma unroll
                for(int msk=1; msk<16; msk<<=1){
                    s  += __shfl_xor(s, msk, 64);
                    s2 += __shfl_xor(s2, msk, 64);
                }
                if(m16 == 0){
                    int o = wo + (ot<<4) + (quad<<2) + r;
                    atomicAdd(&sdq[o], s);
                    atomicAdd(&sdq[128+o], s2);
                }
            }
        }
    } else {
        #pragma unroll
        for(int ot=0;ot<2;ot++){
            #pragma unroll
            for(int pt=0;pt<2;pt++){
                int o = wo + (ot<<4) + m16;
                #pragma unroll
                for(int r=0;r<4;r++){
                    int px = pix0 + phb + (pt<<4) + (quad<<2) + r;
                    D[((b*128+o)<<12) + px] = acc[ot][pt][r];
                }
            }
        }
        #pragma unroll
        for(int ot=0;ot<2;ot++){
            float s = 0.f, s2 = 0.f;
            #pragma unroll
            for(int pt=0;pt<2;pt++){
                #pragma unroll
                for(int r=0;r<4;r++){
                    float v = acc[ot][pt][r];
                    s += v; s2 += v*v;
                }
            }
            #pragma unroll
            for(int msk=16; msk<64; msk<<=1){
                s  += __shfl_xor(s, msk, 64);
                s2 += __shfl_xor(s2, msk, 64);
            }
            if(quad == 0){
                int o = wo + (ot<<4) + m16;
                atomicAdd(&sdq[o], s);
                atomicAdd(&sdq[128+o], s2);
            }
        }
    }
    __syncthreads();
    if(tid < 128){
        atomicAdd(&stats[tid],     sdq[tid]);
        atomicAdd(&stats[128+tid], sdq[128+tid]);
    }
}

// ---------------- K7: fused BN1+GELU + depthwise128 -> Hs, + atomic stats2 partials
__global__ __launch_bounds__(256) void k_bngelu_dw128(const float* Dsrc, float* stats,
                                                      fp g1, fp b1, fp w, fp bias, float* Hs){
    __shared__ float sG[66*68 + 4];
    __shared__ float sd[256], sq[256];
    int bid = blockIdx.x;
    int c = bid & 127, b = bid >> 7;
    int tid = threadIdx.x;
    float mean1 = stats[c] * (1.f/32768.f);
    float var1  = stats[128+c] * (1.f/32768.f) - mean1*mean1;
    float rstd1 = rsqrtf(var1 + 1e-5f);
    float sc = rstd1 * g1[c];
    float sb = b1[c] - mean1*sc;
    for(int j = tid; j < 264; j += 256){
        int idx;
        if(j < 66)       idx = j;
        else if(j < 132) idx = 65*68 + (j-66);
        else if(j < 196) idx = (j-132+1)*68;
        else if(j < 260) idx = (j-196+1)*68 + 65;
        else             idx = 66*68 + (j-260);
        sG[idx] = 0.f;
    }
    const float* dplane = Dsrc + ((size_t)(b*128+c)<<12);
    for(int j = tid; j < 1024; j += 256){
        int yy = j >> 4, x4 = (j & 15) << 2;
        float4 v = *(const float4*)&dplane[(yy<<6) + x4];
        float g0 = v.x*sc+sb, g1v = v.y*sc+sb, g2 = v.z*sc+sb, g3 = v.w*sc+sb;
        float* d = &sG[(yy+1)*68 + x4 + 1];
        d[0] = 0.5f*g0*(1.0f + erff(g0*0.70710678118654752f));
        d[1] = 0.5f*g1v*(1.0f + erff(g1v*0.70710678118654752f));
        d[2] = 0.5f*g2*(1.0f + erff(g2*0.70710678118654752f));
        d[3] = 0.5f*g3*(1.0f + erff(g3*0.70710678118654752f));
    }
    __syncthreads();
    float w0=w[c*9+0], w1=w[c*9+1], w2=w[c*9+2];
    float w3=w[c*9+3], w4=w[c*9+4], w5=w[c*9+5];
    float w6=w[c*9+6], w7=w[c*9+7], w8=w[c*9+8];
    float bv = bias[c];
    float* dst = Hs + ((size_t)(b*128+c)<<12);
    float s = 0.f, s2 = 0.f;
    for(int j = tid; j < 1024; j += 256){
        int y = j >> 4, x0 = (j & 15) << 2;
        float a0=bv, a1=bv, a2=bv, a3=bv;
        #pragma unroll
        for(int ky=0; ky<3; ky++){
            const float* rr = &sG[(y+ky)*68 + x0];
            float4 u0 = *(const float4*)&rr[0];
            float2 u1 = *(const float2*)&rr[4];
            float wA = (ky==0)?w0:((ky==1)?w3:w6);
            float wB = (ky==0)?w1:((ky==1)?w4:w7);
            float wC = (ky==0)?w2:((ky==1)?w5:w8);
            a0 += wA*u0.x + wB*u0.y + wC*u0.z;
            a1 += wA*u0.y + wB*u0.z + wC*u0.w;
            a2 += wA*u0.z + wB*u0.w + wC*u1.x;
            a3 += wA*u0.w + wB*u1.x + wC*u1.y;
        }
        *(float4*)&dst[(y<<6)+x0] = make_float4(a0,a1,a2,a3);
        s += a0+a1+a2+a3;
        s2 += a0*a0 + a1*a1 + a2*a2 + a3*a3;
    }
    sd[tid]=s; sq[tid]=s2; __syncthreads();
    for(int off=128; off>0; off>>=1){
        if(tid<off){ sd[tid]+=sd[tid+off]; sq[tid]+=sq[tid+off]; }
        __syncthreads();
    }
    if(tid==0){
        atomicAdd(&stats[256+c], sd[0]);
        atomicAdd(&stats[384+c], sq[0]);
    }
}

// ---------------- BN2 + ReLU -> f32 out
__global__ __launch_bounds__(256) void k_bn_relu_out(const float* Hs, const float* stats, fp g, fp bb, float* out){
    int idx = blockIdx.x*256+threadIdx.x;
    int c = (idx>>10)&127;
    float mean2 = stats[256+c] * (1.f/32768.f);
    float var2  = stats[384+c] * (1.f/32768.f) - mean2*mean2;
    float rs = rsqrtf(var2 + 1e-5f) * g[c];
    float sb = bb[c] - mean2*rs;
    float4 v = ((const float4*)Hs)[idx];
    float4 o;
    o.x = fmaxf(v.x*rs+sb, 0.f);
    o.y = fmaxf(v.y*rs+sb, 0.f);
    o.z = fmaxf(v.z*rs+sb, 0.f);
    o.w = fmaxf(v.w*rs+sb, 0.f);
    ((float4*)out)[idx] = o;
}

extern "C" void kernel_launch(void* const* d_in, const int* in_sizes, int n_in,
                              void* d_out, int out_size, void* d_ws, size_t ws_size,
                              hipStream_t stream){
    fp x1   = (fp)d_in[0];
    fp x2   = (fp)d_in[1];
    fp dw_w = (fp)d_in[2];  fp dw_b = (fp)d_in[3];
    fp pw_w = (fp)d_in[4];  fp pw_b = (fp)d_in[5];
    fp p_w  = (fp)d_in[6];  fp p_b  = (fp)d_in[7];
    fp m_w  = (fp)d_in[8];  fp m_b  = (fp)d_in[9];
    fp dcn_w= (fp)d_in[10];
    fp bn1g = (fp)d_in[11]; fp bn1b = (fp)d_in[12];
    fp dw2w = (fp)d_in[13]; fp dw2b = (fp)d_in[14];
    fp bn2g = (fp)d_in[15]; fp bn2b = (fp)d_in[16];

    float* ws  = (float*)d_ws;
    float* Bo  = ws;                    // (8,256,4096) ; D reuses after k_pw
    float* Ccl = ws + 8388608;          // (8,4096,128) ; Hs reuses after k_deform
    float* OM  = ws + 12582912;         // (8,27,4096)
    unsigned short* Wbf = (unsigned short*)(ws + 13467648);
    unsigned short* Wpm = (unsigned short*)(ws + 13541376);
    float* stats = ws + 13559808;       // 512 f
    float* Wpwt  = ws + 13560320;       // 32,768 f
    float* D   = Bo;
    float* Hs  = Ccl;
    float* out = (float*)d_out;

    hipMemsetAsync(stats, 0, 512*sizeof(float), stream);
    k_prep         <<<848,   256, 0, stream>>>(dcn_w, p_w, m_w, pw_w, Wbf, Wpm, Wpwt);
    k_updw256      <<<2048,  256, 0, stream>>>(x1, x2, dw_w, dw_b, Bo);
    k_pw           <<<1024,  256, 0, stream>>>(Bo, Wpwt, pw_b, Ccl);
    k_offmask      <<<512,   256, 0, stream>>>(Ccl, Wpm, p_b, m_b, OM);
    k_deform       <<<512,   512, 0, stream>>>(Ccl, OM, Wbf, D, stats);   // v9: 64-px tiles, 512 thr
    k_bngelu_dw128 <<<1024,  256, 0, stream>>>(D, stats, bn1g, bn1b, dw2w, dw2b, Hs);
    k_bn_relu_out  <<<4096,  256, 0, stream>>>(Hs, stats, bn2g, bn2b, out);
}

// Round 12
// 217.994 us; speedup vs baseline: 1.2425x; 1.1112x over previous
//
#include <hip/hip_runtime.h>
#include <math.h>

// Problem constants: B=8, spatial 64x64 (HW=4096), C_mid=256, C=128, N=9 taps.
typedef const float* fp;
typedef __attribute__((ext_vector_type(8))) short short8;   // 8 bf16 = 4 VGPRs (MFMA A/B frag)
typedef __attribute__((ext_vector_type(4))) float f32x4;    // MFMA C/D frag

__device__ __forceinline__ unsigned short f2bf(float f){    // RTNE float->bf16
    unsigned u = __float_as_uint(f);
    u += 0x7fff + ((u >> 16) & 1);
    return (unsigned short)(u >> 16);
}

// ---------------- K0: merged prep — Wbf[n][o][c] bf16, Wpm[n][32q][128c] bf16, Wpwbf[o][256c] bf16
__global__ __launch_bounds__(256) void k_prep(fp dcn_w, fp pw, fp mw, fp pww,
                                              unsigned short* Wbf, unsigned short* Wpm,
                                              unsigned short* Wpwbf){
    int i = blockIdx.x*256 + threadIdx.x;       // 217088 = 848 blocks
    if(i < 147456){
        int c = i & 127, o = (i >> 7) & 127, n = i >> 14;
        Wbf[i] = f2bf(dcn_w[o*1152 + c*9 + n]);
    } else if(i < 184320){
        int j = i - 147456;
        int c = j & 127, q = (j >> 7) & 31, n = j >> 12;
        float v = 0.f;
        if(q < 18)      v = pw[q*1152 + c*9 + n];
        else if(q < 27) v = mw[(q-18)*1152 + c*9 + n];
        Wpm[j] = f2bf(v);
    } else {
        int j = i - 184320;                     // 32768: pointwise weights [o][c] bf16
        Wpwbf[j] = f2bf(pww[j]);
    }
}

// ---------------- K1: fused upsample+concat+depthwise256 -> Bo (8,256,64,64)
__global__ __launch_bounds__(256) void k_updw256(fp x1, fp x2, fp w, fp bias, float* Bo){
    __shared__ float sA[66*68 + 4];
    int bid = blockIdx.x;
    int c = bid & 255, b = bid >> 8;
    int tid = threadIdx.x;
    for(int j = tid; j < 264; j += 256){
        int idx;
        if(j < 66)       idx = j;
        else if(j < 132) idx = 65*68 + (j-66);
        else if(j < 196) idx = (j-132+1)*68;
        else if(j < 260) idx = (j-196+1)*68 + 65;
        else             idx = 66*68 + (j-260);
        sA[idx] = 0.f;
    }
    if(c < 128){
        const float* src = x2 + ((size_t)(b*128+c)<<12);
        for(int j = tid; j < 1024; j += 256){
            int yy = j >> 4, x4 = (j & 15) << 2;
            float4 v = *(const float4*)&src[(yy<<6) + x4];
            float* d = &sA[(yy+1)*68 + x4 + 1];
            d[0]=v.x; d[1]=v.y; d[2]=v.z; d[3]=v.w;
        }
    } else {
        int cc = c - 128;
        fp src = x1 + ((b*128+cc)<<10);
        const float s = 31.0f/63.0f;
        for(int j = tid; j < 4096; j += 256){
            int yy = j >> 6, xx = j & 63;
            float fy = yy*s, fx = xx*s;
            int iy = (int)fy; if (iy > 30) iy = 30;
            int ix = (int)fx; if (ix > 30) ix = 30;
            float ty = fy - (float)iy, tx = fx - (float)ix;
            float v00 = src[iy*32+ix],     v01 = src[iy*32+ix+1];
            float v10 = src[(iy+1)*32+ix], v11 = src[(iy+1)*32+ix+1];
            sA[(yy+1)*68 + xx + 1] =
                (v00*(1.f-ty)+v10*ty)*(1.f-tx) + (v01*(1.f-ty)+v11*ty)*tx;
        }
    }
    __syncthreads();
    float w0=w[c*9+0], w1=w[c*9+1], w2=w[c*9+2];
    float w3=w[c*9+3], w4=w[c*9+4], w5=w[c*9+5];
    float w6=w[c*9+6], w7=w[c*9+7], w8=w[c*9+8];
    float bv = bias[c];
    float* dst = Bo + ((size_t)(b*256+c)<<12);
    for(int j = tid; j < 1024; j += 256){
        int y = j >> 4, x0 = (j & 15) << 2;
        float a0=bv, a1=bv, a2=bv, a3=bv;
        #pragma unroll
        for(int ky=0; ky<3; ky++){
            const float* rr = &sA[(y+ky)*68 + x0];
            float4 u0 = *(const float4*)&rr[0];
            float2 u1 = *(const float2*)&rr[4];
            float wA = (ky==0)?w0:((ky==1)?w3:w6);
            float wB = (ky==0)?w1:((ky==1)?w4:w7);
            float wC = (ky==0)?w2:((ky==1)?w5:w8);
            a0 += wA*u0.x + wB*u0.y + wC*u0.z;
            a1 += wA*u0.y + wB*u0.z + wC*u0.w;
            a2 += wA*u0.z + wB*u0.w + wC*u1.x;
            a3 += wA*u0.w + wB*u1.x + wC*u1.y;
        }
        *(float4*)&dst[(y<<6)+x0] = make_float4(a0,a1,a2,a3);
    }
}

// ---------------- K3 v2: pointwise 256->128 + bias via bf16 MFMA -> Ccl (channel-last).
// GEMM M=32K px, N=128 o, K=256. Cloned from k_deform v9 skeleton: 512 thr,
// 64-px x 128-o tiles, grid 512 (2 blocks/CU all resident). K split in 2 chunks
// of 128; sW chunk + dbuf sX chunk in LDS (69,632 B); chunk-1 X-stage overlaps
// chunk-0 MFMA. Replaces f32 outer-product kernel (~1 GB L2 W-traffic).
#define PW_STAGE_X(kc, bufp) do{ \
    _Pragma("unroll") \
    for(int k_=0;k_<4;k_++){ \
        int j_ = tid + (k_<<9); \
        int cc_ = j_ >> 4, p4_ = (j_ & 15) << 2; \
        int c_ = ((kc)<<7) + cc_; \
        float4 v_ = *(const float4*)&Bo[((size_t)((b<<8)+c_)<<12) + pix0 + p4_]; \
        (bufp)[(p4_+0)*136 + cc_] = f2bf(v_.x); \
        (bufp)[(p4_+1)*136 + cc_] = f2bf(v_.y); \
        (bufp)[(p4_+2)*136 + cc_] = f2bf(v_.z); \
        (bufp)[(p4_+3)*136 + cc_] = f2bf(v_.w); \
    } }while(0)

#define PW_STAGE_W(kc) do{ \
    _Pragma("unroll") \
    for(int k_=0;k_<4;k_++){ \
        int j_ = tid + (k_<<9); \
        int o_ = j_ >> 4, cg_ = j_ & 15; \
        *(int4*)&sW[o_*136 + (cg_<<3)] = \
            *(const int4*)&Wpwbf[o_*256 + ((kc)<<7) + (cg_<<3)]; \
    } }while(0)

#define PW_DOMFMA(srcp) do{ \
    _Pragma("unroll") \
    for(int ks_=0; ks_<4; ks_++){ \
        int k0_ = ks_ << 5; \
        short8 bfr0 = *(const short8*)&(srcp)[(phb + m16)*136 + k0_ + (quad<<3)]; \
        short8 bfr1 = *(const short8*)&(srcp)[(phb + 16 + m16)*136 + k0_ + (quad<<3)]; \
        _Pragma("unroll") \
        for(int ot_=0;ot_<2;ot_++){ \
            short8 afr = *(const short8*)&sW[(wo + (ot_<<4) + m16)*136 + k0_ + (quad<<3)]; \
            acc[ot_][0] = __builtin_amdgcn_mfma_f32_16x16x32_bf16(afr, bfr0, acc[ot_][0], 0,0,0); \
            acc[ot_][1] = __builtin_amdgcn_mfma_f32_16x16x32_bf16(afr, bfr1, acc[ot_][1], 0,0,0); \
        } } }while(0)

__global__ __launch_bounds__(512, 4) void k_pw(const float* Bo, const unsigned short* Wpwbf,
                                               fp bias, float* Ccl){
    __shared__ __align__(16) unsigned short sW[128*136];     // 34,816 B [o][cc]
    __shared__ __align__(16) unsigned short sX[2][64*136];   // 34,816 B dbuf [px][cc]
    int b = blockIdx.x & 7;
    int pix0 = (blockIdx.x >> 3) << 6;   // 64 tiles x 8 b
    int tid = threadIdx.x;               // 0..511
    int lane = tid & 63, wave = tid >> 6;
    int m16 = lane & 15, quad = lane >> 4;
    int wo  = (wave & 3) << 5;           // o-range: 4 groups of 32
    int phb = (wave >> 2) << 5;          // px-half: 0 / 32

    // ---- probe
    short8 ap = {0,0,0,0,0,0,0,0}, bpr = {0,0,0,0,0,0,0,0};
    if(quad == 0){
        ap[0]  = (short)f2bf((float)m16);
        bpr[0] = (short)f2bf((float)(m16+100));
    }
    f32x4 dp = {0.f,0.f,0.f,0.f};
    dp = __builtin_amdgcn_mfma_f32_16x16x32_bf16(ap, bpr, dp, 0,0,0);
    bool p1 = true;
    #pragma unroll
    for(int r=0;r<4;r++){
        float expP1 = (float)(quad*4+r) * (float)(m16+100);
        p1 = p1 && (fabsf(dp[r]-expP1) < 0.5f);
    }
    bool swapD = (__ballot(p1) != 0xFFFFFFFFFFFFFFFFull);

    f32x4 acc[2][2];                     // [ot][pt]
    #pragma unroll
    for(int i=0;i<2;i++){
        #pragma unroll
        for(int j=0;j<2;j++) acc[i][j] = (f32x4){0.f,0.f,0.f,0.f};
    }

    // ---- pipeline: 2 K-chunks
    PW_STAGE_X(0, (&sX[0][0]));
    PW_STAGE_W(0);
    __syncthreads();                      // sX[0], sW(0) ready
    PW_STAGE_X(1, (&sX[1][0]));           // overlaps MFMA(0)
    PW_DOMFMA((&sX[0][0]));
    __syncthreads();                      // MFMA(0) done (sW free), sX[1] writes done
    PW_STAGE_W(1);
    __syncthreads();                      // sW(1) ready
    PW_DOMFMA((&sX[1][0]));

    // ---- epilogue: bias + channel-last write
    if(!swapD){
        #pragma unroll
        for(int ot=0;ot<2;ot++){
            int o0 = wo + (ot<<4) + (quad<<2);
            float4 bv = *(const float4*)&bias[o0];
            #pragma unroll
            for(int pt=0;pt<2;pt++){
                int px = pix0 + phb + (pt<<4) + m16;
                float4 w;
                w.x = acc[ot][pt][0] + bv.x;
                w.y = acc[ot][pt][1] + bv.y;
                w.z = acc[ot][pt][2] + bv.z;
                w.w = acc[ot][pt][3] + bv.w;
                *(float4*)&Ccl[((size_t)((b<<12) + px))*128 + o0] = w;
            }
        }
    } else {
        #pragma unroll
        for(int ot=0;ot<2;ot++){
            int o = wo + (ot<<4) + m16;
            float bv = bias[o];
            #pragma unroll
            for(int pt=0;pt<2;pt++){
                #pragma unroll
                for(int r=0;r<4;r++){
                    int px = pix0 + phb + (pt<<4) + (quad<<2) + r;
                    Ccl[((size_t)((b<<12) + px))*128 + o] = acc[ot][pt][r] + bv;
                }
            }
        }
    }
}

// ---------------- K4 v3 (verified): offset+mask conv, one-shot window staging.
__global__ __launch_bounds__(256, 2) void k_offmask(fp Ccl, const unsigned short* Wpm,
                                                    fp pb, fp mb, float* OM){
    __shared__ __align__(16) unsigned short sWin[3*66*136];  // 53,856 B [r][col][c]
    __shared__ __align__(16) unsigned short sW[2][32*136];   // 17,408 B dbuf [q][c]
    int b = blockIdx.x & 7;
    int y = blockIdx.x >> 3;          // output row
    int pix0 = y << 6;
    int tid = threadIdx.x;
    int lane = tid & 63, wave = tid >> 6;
    int m16 = lane & 15, quad = lane >> 4;
    int wp = wave << 4;               // px-subtile
    const float* cb = Ccl + (size_t)(b<<12)*128;

    // ---- probe: D[m][n]=m*(n+100)
    short8 ap = {0,0,0,0,0,0,0,0}, bpr = {0,0,0,0,0,0,0,0};
    if(quad == 0){
        ap[0]  = (short)f2bf((float)m16);
        bpr[0] = (short)f2bf((float)(m16+100));
    }
    f32x4 dp = {0.f,0.f,0.f,0.f};
    dp = __builtin_amdgcn_mfma_f32_16x16x32_bf16(ap, bpr, dp, 0,0,0);
    bool p1 = true;
    #pragma unroll
    for(int r=0;r<4;r++){
        float expP1 = (float)(quad*4+r) * (float)(m16+100);
        p1 = p1 && (fabsf(dp[r]-expP1) < 0.5f);
    }
    bool swapD = (__ballot(p1) != 0xFFFFFFFFFFFFFFFFull);

    f32x4 acc[2];
    acc[0] = (f32x4){0.f,0.f,0.f,0.f};
    acc[1] = (f32x4){0.f,0.f,0.f,0.f};

    // ---- prologue: issue W(0) loads, stage window (covers latency), write sW[0]
    {
        const int4* wsrc = (const int4*)Wpm;
        int4 wA_ = wsrc[tid], wB_ = wsrc[tid + 256];
        for(int i = tid; i < 6336; i += 256){        // 198 pos x 32 cg
            int pos = i >> 5, cg = (i & 31) << 2;
            int r = pos / 66, col = pos - r*66;
            int yy = y + r - 1, xx = col - 1;
            float4 v = make_float4(0.f,0.f,0.f,0.f);
            if(yy>=0 && yy<64 && xx>=0 && xx<64)
                v = *(const float4*)&cb[(size_t)((yy<<6)+xx)*128 + cg];
            unsigned long long pk = (unsigned long long)f2bf(v.x)
                | ((unsigned long long)f2bf(v.y)<<16)
                | ((unsigned long long)f2bf(v.z)<<32)
                | ((unsigned long long)f2bf(v.w)<<48);
            *(unsigned long long*)&sWin[pos*136 + cg] = pk;
        }
        *(int4*)&sW[0][(tid>>4)*136 + ((tid&15)<<3)] = wA_;
        int j = tid + 256;
        *(int4*)&sW[0][(j>>4)*136 + ((j&15)<<3)] = wB_;
    }
    __syncthreads();

    for(int n=0;n<9;n++){
        int4 wA_, wB_;
        if(n<8){
            const int4* wsrc = (const int4*)(Wpm + ((n+1)<<12));
            wA_ = wsrc[tid]; wB_ = wsrc[tid + 256];   // issue early; MFMA covers latency
        }
        int ky = n/3, kx = n - ky*3;
        const unsigned short* base = &sWin[(ky*66 + wp + kx)*136];
        #pragma unroll
        for(int ks=0; ks<4; ks++){
            int k0 = ks << 5;
            short8 bfr = *(const short8*)&base[m16*136 + k0 + (quad<<3)];
            #pragma unroll
            for(int qt=0;qt<2;qt++){
                short8 afr = *(const short8*)&sW[n&1][((qt<<4) + m16)*136 + k0 + (quad<<3)];
                acc[qt] = __builtin_amdgcn_mfma_f32_16x16x32_bf16(afr, bfr, acc[qt], 0,0,0);
            }
        }
        if(n<8){
            *(int4*)&sW[(n+1)&1][(tid>>4)*136 + ((tid&15)<<3)] = wA_;
            int j = tid + 256;
            *(int4*)&sW[(n+1)&1][(j>>4)*136 + ((j&15)<<3)] = wB_;
        }
        __syncthreads();
    }
    if(!swapD){
        #pragma unroll
        for(int qt=0;qt<2;qt++){
            int px = pix0 + wp + m16;
            #pragma unroll
            for(int r=0;r<4;r++){
                int q = (qt<<4) + (quad<<2) + r;
                if(q < 27){
                    float v = acc[qt][r] + ((q<18) ? pb[q] : mb[q-18]);
                    if(q>=18) v = 1.f/(1.f+expf(-v));
                    OM[((b*27+q)<<12) + px] = v;
                }
            }
        }
    } else {
        #pragma unroll
        for(int qt=0;qt<2;qt++){
            int q = (qt<<4) + m16;
            if(q < 27){
                float bias = (q<18) ? pb[q] : mb[q-18];
                #pragma unroll
                for(int r=0;r<4;r++){
                    int px = pix0 + wp + (quad<<2) + r;
                    float v = acc[qt][r] + bias;
                    if(q>=18) v = 1.f/(1.f+expf(-v));
                    OM[((b*27+q)<<12) + px] = v;
                }
            }
        }
    }
}

// ---------------- K5 v9 (verified 55 us): deformable sampling + bf16 MFMA, 512-thr/64-px.
#define K5_META(t) do{ if(tid < 256){ \
    int px_ = tid >> 2, k_ = tid & 3; \
    int pix_ = pix0 + px_; \
    int yq_ = pix_ >> 6, xq_ = pix_ & 63; \
    int kyy_ = (t)/3, kxx_ = (t)-kyy_*3; \
    float oxv_ = omb[((t)<<12)+pix_]; \
    float oyv_ = omb[(((t)+9)<<12)+pix_]; \
    float mv_  = omb[(((t)+18)<<12)+pix_]; \
    float pxf_ = (float)(yq_ + kyy_) + oxv_; \
    float pyf_ = (float)(xq_ + kxx_) + oyv_; \
    float fx_ = floorf(pxf_), fy_ = floorf(pyf_); \
    float qx0_ = fminf(fmaxf(fx_,0.f),65.f),  qx1_ = fminf(fmaxf(fx_+1.f,0.f),65.f); \
    float qy0_ = fminf(fmaxf(fy_,0.f),65.f),  qy1_ = fminf(fmaxf(fy_+1.f,0.f),65.f); \
    float pxc_ = fminf(fmaxf(pxf_,0.f),65.f), pyc_ = fminf(fmaxf(pyf_,0.f),65.f); \
    float dx0_ = 1.f+(qx0_-pxc_), dx1_ = 1.f-(qx1_-pxc_); \
    float dy0_ = 1.f+(qy0_-pyc_), dy1_ = 1.f-(qy1_-pyc_); \
    int ax0_=(int)qx0_, ax1_=(int)qx1_, ay0_=(int)qy0_, ay1_=(int)qy1_; \
    bool vx0_ = (ax0_>=1)&&(ax0_<=64), vx1_ = (ax1_>=1)&&(ax1_<=64); \
    bool vy0_ = (ay0_>=1)&&(ay0_<=64), vy1_ = (ay1_>=1)&&(ay1_<=64); \
    int  axs_ = (k_&1) ? ax1_ : ax0_; \
    int  ays_ = (k_==1||k_==2) ? ay1_ : ay0_; \
    bool vxs_ = (k_&1) ? vx1_ : vx0_; \
    bool vys_ = (k_==1||k_==2) ? vy1_ : vy0_; \
    float dxs_ = (k_&1) ? dx1_ : dx0_; \
    float dys_ = (k_==1||k_==2) ? dy1_ : dy0_; \
    bool v_ = vxs_ && vys_; \
    int base_ = v_ ? (((axs_-1)<<6)+(ays_-1)) : 0; \
    float g_ = v_ ? dxs_*dys_*mv_ : 0.f; \
    sM[tid] = make_uint2((unsigned)base_, __float_as_uint(g_)); \
} }while(0)

#define K5_GATHER(bufp) do{ \
    _Pragma("unroll") \
    for(int j_=0;j_<4;j_++){ \
        int px_ = pxb + (j_<<4); \
        uint2 e0_ = sM[(px_<<2)+0]; \
        uint2 e1_ = sM[(px_<<2)+1]; \
        uint2 e2_ = sM[(px_<<2)+2]; \
        uint2 e3_ = sM[(px_<<2)+3]; \
        float g0_ = __uint_as_float(e0_.y), g1_ = __uint_as_float(e1_.y); \
        float g2_ = __uint_as_float(e2_.y), g3_ = __uint_as_float(e3_.y); \
        float4 r0_ = *(const float4*)&cb[((size_t)e0_.x<<7) + cg4]; \
        float4 r1_ = *(const float4*)&cb[((size_t)e1_.x<<7) + cg4]; \
        float4 r2_ = *(const float4*)&cb[((size_t)e2_.x<<7) + cg4]; \
        float4 r3_ = *(const float4*)&cb[((size_t)e3_.x<<7) + cg4]; \
        float vx_ = g0_*r0_.x + g1_*r1_.x + g2_*r2_.x + g3_*r3_.x; \
        float vy_ = g0_*r0_.y + g1_*r1_.y + g2_*r2_.y + g3_*r3_.y; \
        float vz_ = g0_*r0_.z + g1_*r1_.z + g2_*r2_.z + g3_*r3_.z; \
        float vw_ = g0_*r0_.w + g1_*r1_.w + g2_*r2_.w + g3_*r3_.w; \
        unsigned long long pk_ = (unsigned long long)f2bf(vx_) \
            | ((unsigned long long)f2bf(vy_)<<16) \
            | ((unsigned long long)f2bf(vz_)<<32) \
            | ((unsigned long long)f2bf(vw_)<<48); \
        *(unsigned long long*)&(bufp)[px_*136 + cg4] = pk_; \
    } }while(0)

#define K5_STAGE_W(t) do{ \
    const int4* wsrc_ = (const int4*)(Wbf + ((t)<<14)); \
    _Pragma("unroll") \
    for(int k_=0;k_<4;k_++){ int j_ = tid + (k_<<9); \
        *(int4*)&sW[(j_>>4)*136 + ((j_&15)<<3)] = wsrc_[j_]; } }while(0)

#define K5_DOMFMA(srcp) do{ \
    _Pragma("unroll") \
    for(int ks_=0; ks_<4; ks_++){ \
        int k0_ = ks_ << 5; \
        short8 bfr0 = *(const short8*)&(srcp)[(phb + m16)*136 + k0_ + (quad<<3)]; \
        short8 bfr1 = *(const short8*)&(srcp)[(phb + 16 + m16)*136 + k0_ + (quad<<3)]; \
        _Pragma("unroll") \
        for(int ot_=0;ot_<2;ot_++){ \
            short8 afr = *(const short8*)&sW[(wo + (ot_<<4) + m16)*136 + k0_ + (quad<<3)]; \
            acc[ot_][0] = __builtin_amdgcn_mfma_f32_16x16x32_bf16(afr, bfr0, acc[ot_][0], 0,0,0); \
            acc[ot_][1] = __builtin_amdgcn_mfma_f32_16x16x32_bf16(afr, bfr1, acc[ot_][1], 0,0,0); \
        } } }while(0)

__global__ __launch_bounds__(512, 4) void k_deform(fp Ccl, fp OM, const unsigned short* Wbf,
                                                   float* D, float* stats){
    __shared__ __align__(16) unsigned short sW[128*136];     // 34,816 B [o][c]
    __shared__ __align__(16) unsigned short sX[2][64*136];   // 34,816 B dbuf [px][c]
    __shared__ __align__(8)  uint2 sM[256];                  //  2,048 B meta (base,weight)
    int b = blockIdx.x & 7;
    int pix0 = (blockIdx.x >> 3) << 6;   // 64 tiles (one row each) x 8 b
    int tid = threadIdx.x;               // 0..511
    int lane = tid & 63, wave = tid >> 6;
    int m16 = lane & 15, quad = lane >> 4;
    int wo  = (wave & 3) << 5;           // o-range: 4 groups of 32
    int phb = (wave >> 2) << 5;          // px-half: 0 / 32
    int cg4 = (tid & 31) << 2;           // channel group (4 ch)
    int pxb = tid >> 5;                  // base px 0..15 (handles px pxb, +16, +32, +48)
    const float* omb = OM + b*27*4096;
    const float* cb  = Ccl + ((size_t)(b)<<12)*128;

    // ---- probe
    short8 ap = {0,0,0,0,0,0,0,0}, bpr = {0,0,0,0,0,0,0,0};
    if(quad == 0){
        ap[0]  = (short)f2bf((float)m16);
        bpr[0] = (short)f2bf((float)(m16+100));
    }
    f32x4 dp = {0.f,0.f,0.f,0.f};
    dp = __builtin_amdgcn_mfma_f32_16x16x32_bf16(ap, bpr, dp, 0,0,0);
    bool p1 = true;
    #pragma unroll
    for(int r=0;r<4;r++){
        float expP1 = (float)(quad*4+r) * (float)(m16+100);
        p1 = p1 && (fabsf(dp[r]-expP1) < 0.5f);
    }
    bool swapD = (__ballot(p1) != 0xFFFFFFFFFFFFFFFFull);

    f32x4 acc[2][2];                     // [ot][pt]
    #pragma unroll
    for(int i=0;i<2;i++){
        #pragma unroll
        for(int j=0;j<2;j++) acc[i][j] = (f32x4){0.f,0.f,0.f,0.f};
    }

    // ---- prologue
    K5_META(0);
    __syncthreads();                      // sM = meta(0)
    K5_GATHER((&sX[0][0]));               // gather(0) using meta(0)
    K5_STAGE_W(0);
    __syncthreads();                      // sX[0], sW(0) ready; sM reads done
    K5_META(1);
    __syncthreads();                      // sM = meta(1)

    for(int n=0;n<9;n++){
        if(n<8) K5_GATHER((&sX[(n+1)&1][0]));  // uses sM = meta(n+1); overlaps MFMA(n)
        K5_DOMFMA((&sX[n&1][0]));              // operands from LDS (sW, sX)
        __syncthreads();                       // sW/sM reads + sX writes done
        if(n<8){
            K5_STAGE_W(n+1);                   // sW <- W(n+1), transient regs
            if(n<7) K5_META(n+2);              // sM <- meta(n+2)
            __syncthreads();                   // sW, sM ready for next iter
        }
    }

    // epilogue: D writes + per-channel sum/sumsq reduction (stats LDS overlaid on dead sX)
    float* sdq = (float*)&sX[0][0];       // [0..127]=sum, [128..255]=sumsq
    if(tid < 256) sdq[tid] = 0.f;
    __syncthreads();
    if(!swapD){
        #pragma unroll
        for(int ot=0;ot<2;ot++){
            #pragma unroll
            for(int pt=0;pt<2;pt++){
                int px = pix0 + phb + (pt<<4) + m16;
                #pragma unroll
                for(int r=0;r<4;r++){
                    int o = wo + (ot<<4) + (quad<<2) + r;
                    D[((b*128+o)<<12) + px] = acc[ot][pt][r];
                }
            }
        }
        #pragma unroll
        for(int ot=0;ot<2;ot++){
            #pragma unroll
            for(int r=0;r<4;r++){
                float s  = acc[ot][0][r] + acc[ot][1][r];
                float s2 = acc[ot][0][r]*acc[ot][0][r] + acc[ot][1][r]*acc[ot][1][r];
                #pragma unroll
                for(int msk=1; msk<16; msk<<=1){
                    s  += __shfl_xor(s, msk, 64);
                    s2 += __shfl_xor(s2, msk, 64);
                }
                if(m16 == 0){
                    int o = wo + (ot<<4) + (quad<<2) + r;
                    atomicAdd(&sdq[o], s);
                    atomicAdd(&sdq[128+o], s2);
                }
            }
        }
    } else {
        #pragma unroll
        for(int ot=0;ot<2;ot++){
            #pragma unroll
            for(int pt=0;pt<2;pt++){
                int o = wo + (ot<<4) + m16;
                #pragma unroll
                for(int r=0;r<4;r++){
                    int px = pix0 + phb + (pt<<4) + (quad<<2) + r;
                    D[((b*128+o)<<12) + px] = acc[ot][pt][r];
                }
            }
        }
        #pragma unroll
        for(int ot=0;ot<2;ot++){
            float s = 0.f, s2 = 0.f;
            #pragma unroll
            for(int pt=0;pt<2;pt++){
                #pragma unroll
                for(int r=0;r<4;r++){
                    float v = acc[ot][pt][r];
                    s += v; s2 += v*v;
                }
            }
            #pragma unroll
            for(int msk=16; msk<64; msk<<=1){
                s  += __shfl_xor(s, msk, 64);
                s2 += __shfl_xor(s2, msk, 64);
            }
            if(quad == 0){
                int o = wo + (ot<<4) + m16;
                atomicAdd(&sdq[o], s);
                atomicAdd(&sdq[128+o], s2);
            }
        }
    }
    __syncthreads();
    if(tid < 128){
        atomicAdd(&stats[tid],     sdq[tid]);
        atomicAdd(&stats[128+tid], sdq[128+tid]);
    }
}

// ---------------- K7: fused BN1+GELU + depthwise128 -> Hs, + atomic stats2 partials
__global__ __launch_bounds__(256) void k_bngelu_dw128(const float* Dsrc, float* stats,
                                                      fp g1, fp b1, fp w, fp bias, float* Hs){
    __shared__ float sG[66*68 + 4];
    __shared__ float sd[256], sq[256];
    int bid = blockIdx.x;
    int c = bid & 127, b = bid >> 7;
    int tid = threadIdx.x;
    float mean1 = stats[c] * (1.f/32768.f);
    float var1  = stats[128+c] * (1.f/32768.f) - mean1*mean1;
    float rstd1 = rsqrtf(var1 + 1e-5f);
    float sc = rstd1 * g1[c];
    float sb = b1[c] - mean1*sc;
    for(int j = tid; j < 264; j += 256){
        int idx;
        if(j < 66)       idx = j;
        else if(j < 132) idx = 65*68 + (j-66);
        else if(j < 196) idx = (j-132+1)*68;
        else if(j < 260) idx = (j-196+1)*68 + 65;
        else             idx = 66*68 + (j-260);
        sG[idx] = 0.f;
    }
    const float* dplane = Dsrc + ((size_t)(b*128+c)<<12);
    for(int j = tid; j < 1024; j += 256){
        int yy = j >> 4, x4 = (j & 15) << 2;
        float4 v = *(const float4*)&dplane[(yy<<6) + x4];
        float g0 = v.x*sc+sb, g1v = v.y*sc+sb, g2 = v.z*sc+sb, g3 = v.w*sc+sb;
        float* d = &sG[(yy+1)*68 + x4 + 1];
        d[0] = 0.5f*g0*(1.0f + erff(g0*0.70710678118654752f));
        d[1] = 0.5f*g1v*(1.0f + erff(g1v*0.70710678118654752f));
        d[2] = 0.5f*g2*(1.0f + erff(g2*0.70710678118654752f));
        d[3] = 0.5f*g3*(1.0f + erff(g3*0.70710678118654752f));
    }
    __syncthreads();
    float w0=w[c*9+0], w1=w[c*9+1], w2=w[c*9+2];
    float w3=w[c*9+3], w4=w[c*9+4], w5=w[c*9+5];
    float w6=w[c*9+6], w7=w[c*9+7], w8=w[c*9+8];
    float bv = bias[c];
    float* dst = Hs + ((size_t)(b*128+c)<<12);
    float s = 0.f, s2 = 0.f;
    for(int j = tid; j < 1024; j += 256){
        int y = j >> 4, x0 = (j & 15) << 2;
        float a0=bv, a1=bv, a2=bv, a3=bv;
        #pragma unroll
        for(int ky=0; ky<3; ky++){
            const float* rr = &sG[(y+ky)*68 + x0];
            float4 u0 = *(const float4*)&rr[0];
            float2 u1 = *(const float2*)&rr[4];
            float wA = (ky==0)?w0:((ky==1)?w3:w6);
            float wB = (ky==0)?w1:((ky==1)?w4:w7);
            float wC = (ky==0)?w2:((ky==1)?w5:w8);
            a0 += wA*u0.x + wB*u0.y + wC*u0.z;
            a1 += wA*u0.y + wB*u0.z + wC*u0.w;
            a2 += wA*u0.z + wB*u0.w + wC*u1.x;
            a3 += wA*u0.w + wB*u1.x + wC*u1.y;
        }
        *(float4*)&dst[(y<<6)+x0] = make_float4(a0,a1,a2,a3);
        s += a0+a1+a2+a3;
        s2 += a0*a0 + a1*a1 + a2*a2 + a3*a3;
    }
    sd[tid]=s; sq[tid]=s2; __syncthreads();
    for(int off=128; off>0; off>>=1){
        if(tid<off){ sd[tid]+=sd[tid+off]; sq[tid]+=sq[tid+off]; }
        __syncthreads();
    }
    if(tid==0){
        atomicAdd(&stats[256+c], sd[0]);
        atomicAdd(&stats[384+c], sq[0]);
    }
}

// ---------------- BN2 + ReLU -> f32 out
__global__ __launch_bounds__(256) void k_bn_relu_out(const float* Hs, const float* stats, fp g, fp bb, float* out){
    int idx = blockIdx.x*256+threadIdx.x;
    int c = (idx>>10)&127;
    float mean2 = stats[256+c] * (1.f/32768.f);
    float var2  = stats[384+c] * (1.f/32768.f) - mean2*mean2;
    float rs = rsqrtf(var2 + 1e-5f) * g[c];
    float sb = bb[c] - mean2*rs;
    float4 v = ((const float4*)Hs)[idx];
    float4 o;
    o.x = fmaxf(v.x*rs+sb, 0.f);
    o.y = fmaxf(v.y*rs+sb, 0.f);
    o.z = fmaxf(v.z*rs+sb, 0.f);
    o.w = fmaxf(v.w*rs+sb, 0.f);
    ((float4*)out)[idx] = o;
}

extern "C" void kernel_launch(void* const* d_in, const int* in_sizes, int n_in,
                              void* d_out, int out_size, void* d_ws, size_t ws_size,
                              hipStream_t stream){
    fp x1   = (fp)d_in[0];
    fp x2   = (fp)d_in[1];
    fp dw_w = (fp)d_in[2];  fp dw_b = (fp)d_in[3];
    fp pw_w = (fp)d_in[4];  fp pw_b = (fp)d_in[5];
    fp p_w  = (fp)d_in[6];  fp p_b  = (fp)d_in[7];
    fp m_w  = (fp)d_in[8];  fp m_b  = (fp)d_in[9];
    fp dcn_w= (fp)d_in[10];
    fp bn1g = (fp)d_in[11]; fp bn1b = (fp)d_in[12];
    fp dw2w = (fp)d_in[13]; fp dw2b = (fp)d_in[14];
    fp bn2g = (fp)d_in[15]; fp bn2b = (fp)d_in[16];

    float* ws  = (float*)d_ws;
    float* Bo  = ws;                    // (8,256,4096) ; D reuses after k_pw
    float* Ccl = ws + 8388608;          // (8,4096,128) ; Hs reuses after k_deform
    float* OM  = ws + 12582912;         // (8,27,4096)
    unsigned short* Wbf = (unsigned short*)(ws + 13467648);
    unsigned short* Wpm = (unsigned short*)(ws + 13541376);
    float* stats = ws + 13559808;       // 512 f
    unsigned short* Wpwbf = (unsigned short*)(ws + 13560320);  // 32,768 bf16 (16,384 f; reuses old Wpwt slot)
    float* D   = Bo;
    float* Hs  = Ccl;
    float* out = (float*)d_out;

    hipMemsetAsync(stats, 0, 512*sizeof(float), stream);
    k_prep         <<<848,   256, 0, stream>>>(dcn_w, p_w, m_w, pw_w, Wbf, Wpm, Wpwbf);
    k_updw256      <<<2048,  256, 0, stream>>>(x1, x2, dw_w, dw_b, Bo);
    k_pw           <<<512,   512, 0, stream>>>(Bo, Wpwbf, pw_b, Ccl);
    k_offmask      <<<512,   256, 0, stream>>>(Ccl, Wpm, p_b, m_b, OM);
    k_deform       <<<512,   512, 0, stream>>>(Ccl, OM, Wbf, D, stats);   // v9: 64-px tiles, 512 thr
    k_bngelu_dw128 <<<1024,  256, 0, stream>>>(D, stats, bn1g, bn1b, dw2w, dw2b, Hs);
    k_bn_relu_out  <<<4096,  256, 0, stream>>>(Hs, stats, bn2g, bn2b, out);
}

// Round 13
// 205.524 us; speedup vs baseline: 1.3178x; 1.0607x over previous
//
#include <hip/hip_runtime.h>
#include <math.h>

// Problem constants: B=8, spatial 64x64 (HW=4096), C_mid=256, C=128, N=9 taps.
typedef const float* fp;
typedef __attribute__((ext_vector_type(8))) short short8;   // 8 bf16 = 4 VGPRs (MFMA A/B frag)
typedef __attribute__((ext_vector_type(4))) float f32x4;    // MFMA C/D frag

__device__ __forceinline__ unsigned short f2bf(float f){    // RTNE float->bf16
    unsigned u = __float_as_uint(f);
    u += 0x7fff + ((u >> 16) & 1);
    return (unsigned short)(u >> 16);
}
__device__ __forceinline__ float bflo(unsigned u){ return __uint_as_float(u << 16); }
__device__ __forceinline__ float bfhi(unsigned u){ return __uint_as_float(u & 0xffff0000u); }

// ---------------- K0: merged prep — Wbf[n][o][c] bf16, Wpm[n][32q][128c] bf16, Wpwbf[o][256c] bf16
__global__ __launch_bounds__(256) void k_prep(fp dcn_w, fp pw, fp mw, fp pww,
                                              unsigned short* Wbf, unsigned short* Wpm,
                                              unsigned short* Wpwbf){
    int i = blockIdx.x*256 + threadIdx.x;       // 217088 = 848 blocks
    if(i < 147456){
        int c = i & 127, o = (i >> 7) & 127, n = i >> 14;
        Wbf[i] = f2bf(dcn_w[o*1152 + c*9 + n]);
    } else if(i < 184320){
        int j = i - 147456;
        int c = j & 127, q = (j >> 7) & 31, n = j >> 12;
        float v = 0.f;
        if(q < 18)      v = pw[q*1152 + c*9 + n];
        else if(q < 27) v = mw[(q-18)*1152 + c*9 + n];
        Wpm[j] = f2bf(v);
    } else {
        int j = i - 184320;                     // 32768: pointwise weights [o][c] bf16
        Wpwbf[j] = f2bf(pww[j]);
    }
}

// ---------------- K1: fused upsample+concat+depthwise256 -> Bo (8,256,64,64)
__global__ __launch_bounds__(256) void k_updw256(fp x1, fp x2, fp w, fp bias, float* Bo){
    __shared__ float sA[66*68 + 4];
    int bid = blockIdx.x;
    int c = bid & 255, b = bid >> 8;
    int tid = threadIdx.x;
    for(int j = tid; j < 264; j += 256){
        int idx;
        if(j < 66)       idx = j;
        else if(j < 132) idx = 65*68 + (j-66);
        else if(j < 196) idx = (j-132+1)*68;
        else if(j < 260) idx = (j-196+1)*68 + 65;
        else             idx = 66*68 + (j-260);
        sA[idx] = 0.f;
    }
    if(c < 128){
        const float* src = x2 + ((size_t)(b*128+c)<<12);
        for(int j = tid; j < 1024; j += 256){
            int yy = j >> 4, x4 = (j & 15) << 2;
            float4 v = *(const float4*)&src[(yy<<6) + x4];
            float* d = &sA[(yy+1)*68 + x4 + 1];
            d[0]=v.x; d[1]=v.y; d[2]=v.z; d[3]=v.w;
        }
    } else {
        int cc = c - 128;
        fp src = x1 + ((b*128+cc)<<10);
        const float s = 31.0f/63.0f;
        for(int j = tid; j < 4096; j += 256){
            int yy = j >> 6, xx = j & 63;
            float fy = yy*s, fx = xx*s;
            int iy = (int)fy; if (iy > 30) iy = 30;
            int ix = (int)fx; if (ix > 30) ix = 30;
            float ty = fy - (float)iy, tx = fx - (float)ix;
            float v00 = src[iy*32+ix],     v01 = src[iy*32+ix+1];
            float v10 = src[(iy+1)*32+ix], v11 = src[(iy+1)*32+ix+1];
            sA[(yy+1)*68 + xx + 1] =
                (v00*(1.f-ty)+v10*ty)*(1.f-tx) + (v01*(1.f-ty)+v11*ty)*tx;
        }
    }
    __syncthreads();
    float w0=w[c*9+0], w1=w[c*9+1], w2=w[c*9+2];
    float w3=w[c*9+3], w4=w[c*9+4], w5=w[c*9+5];
    float w6=w[c*9+6], w7=w[c*9+7], w8=w[c*9+8];
    float bv = bias[c];
    float* dst = Bo + ((size_t)(b*256+c)<<12);
    for(int j = tid; j < 1024; j += 256){
        int y = j >> 4, x0 = (j & 15) << 2;
        float a0=bv, a1=bv, a2=bv, a3=bv;
        #pragma unroll
        for(int ky=0; ky<3; ky++){
            const float* rr = &sA[(y+ky)*68 + x0];
            float4 u0 = *(const float4*)&rr[0];
            float2 u1 = *(const float2*)&rr[4];
            float wA = (ky==0)?w0:((ky==1)?w3:w6);
            float wB = (ky==0)?w1:((ky==1)?w4:w7);
            float wC = (ky==0)?w2:((ky==1)?w5:w8);
            a0 += wA*u0.x + wB*u0.y + wC*u0.z;
            a1 += wA*u0.y + wB*u0.z + wC*u0.w;
            a2 += wA*u0.z + wB*u0.w + wC*u1.x;
            a3 += wA*u0.w + wB*u1.x + wC*u1.y;
        }
        *(float4*)&dst[(y<<6)+x0] = make_float4(a0,a1,a2,a3);
    }
}

// ---------------- K3 v3: pointwise 256->128 + bias via bf16 MFMA -> Cbf (channel-last bf16).
// Every downstream consumer rounds Ccl to bf16 before MFMA anyway -> store bf16 directly.
#define PW_STAGE_X(kc, bufp) do{ \
    _Pragma("unroll") \
    for(int k_=0;k_<4;k_++){ \
        int j_ = tid + (k_<<9); \
        int cc_ = j_ >> 4, p4_ = (j_ & 15) << 2; \
        int c_ = ((kc)<<7) + cc_; \
        float4 v_ = *(const float4*)&Bo[((size_t)((b<<8)+c_)<<12) + pix0 + p4_]; \
        (bufp)[(p4_+0)*136 + cc_] = f2bf(v_.x); \
        (bufp)[(p4_+1)*136 + cc_] = f2bf(v_.y); \
        (bufp)[(p4_+2)*136 + cc_] = f2bf(v_.z); \
        (bufp)[(p4_+3)*136 + cc_] = f2bf(v_.w); \
    } }while(0)

#define PW_STAGE_W(kc) do{ \
    _Pragma("unroll") \
    for(int k_=0;k_<4;k_++){ \
        int j_ = tid + (k_<<9); \
        int o_ = j_ >> 4, cg_ = j_ & 15; \
        *(int4*)&sW[o_*136 + (cg_<<3)] = \
            *(const int4*)&Wpwbf[o_*256 + ((kc)<<7) + (cg_<<3)]; \
    } }while(0)

#define PW_DOMFMA(srcp) do{ \
    _Pragma("unroll") \
    for(int ks_=0; ks_<4; ks_++){ \
        int k0_ = ks_ << 5; \
        short8 bfr0 = *(const short8*)&(srcp)[(phb + m16)*136 + k0_ + (quad<<3)]; \
        short8 bfr1 = *(const short8*)&(srcp)[(phb + 16 + m16)*136 + k0_ + (quad<<3)]; \
        _Pragma("unroll") \
        for(int ot_=0;ot_<2;ot_++){ \
            short8 afr = *(const short8*)&sW[(wo + (ot_<<4) + m16)*136 + k0_ + (quad<<3)]; \
            acc[ot_][0] = __builtin_amdgcn_mfma_f32_16x16x32_bf16(afr, bfr0, acc[ot_][0], 0,0,0); \
            acc[ot_][1] = __builtin_amdgcn_mfma_f32_16x16x32_bf16(afr, bfr1, acc[ot_][1], 0,0,0); \
        } } }while(0)

__global__ __launch_bounds__(512, 4) void k_pw(const float* Bo, const unsigned short* Wpwbf,
                                               fp bias, unsigned short* Cbf){
    __shared__ __align__(16) unsigned short sW[128*136];     // 34,816 B [o][cc]
    __shared__ __align__(16) unsigned short sX[2][64*136];   // 34,816 B dbuf [px][cc]
    int b = blockIdx.x & 7;
    int pix0 = (blockIdx.x >> 3) << 6;   // 64 tiles x 8 b
    int tid = threadIdx.x;               // 0..511
    int lane = tid & 63, wave = tid >> 6;
    int m16 = lane & 15, quad = lane >> 4;
    int wo  = (wave & 3) << 5;           // o-range: 4 groups of 32
    int phb = (wave >> 2) << 5;          // px-half: 0 / 32

    // ---- probe
    short8 ap = {0,0,0,0,0,0,0,0}, bpr = {0,0,0,0,0,0,0,0};
    if(quad == 0){
        ap[0]  = (short)f2bf((float)m16);
        bpr[0] = (short)f2bf((float)(m16+100));
    }
    f32x4 dp = {0.f,0.f,0.f,0.f};
    dp = __builtin_amdgcn_mfma_f32_16x16x32_bf16(ap, bpr, dp, 0,0,0);
    bool p1 = true;
    #pragma unroll
    for(int r=0;r<4;r++){
        float expP1 = (float)(quad*4+r) * (float)(m16+100);
        p1 = p1 && (fabsf(dp[r]-expP1) < 0.5f);
    }
    bool swapD = (__ballot(p1) != 0xFFFFFFFFFFFFFFFFull);

    f32x4 acc[2][2];                     // [ot][pt]
    #pragma unroll
    for(int i=0;i<2;i++){
        #pragma unroll
        for(int j=0;j<2;j++) acc[i][j] = (f32x4){0.f,0.f,0.f,0.f};
    }

    // ---- pipeline: 2 K-chunks
    PW_STAGE_X(0, (&sX[0][0]));
    PW_STAGE_W(0);
    __syncthreads();                      // sX[0], sW(0) ready
    PW_STAGE_X(1, (&sX[1][0]));           // overlaps MFMA(0)
    PW_DOMFMA((&sX[0][0]));
    __syncthreads();                      // MFMA(0) done (sW free), sX[1] writes done
    PW_STAGE_W(1);
    __syncthreads();                      // sW(1) ready
    PW_DOMFMA((&sX[1][0]));

    // ---- epilogue: bias + channel-last bf16 write
    if(!swapD){
        #pragma unroll
        for(int ot=0;ot<2;ot++){
            int o0 = wo + (ot<<4) + (quad<<2);
            float4 bv = *(const float4*)&bias[o0];
            #pragma unroll
            for(int pt=0;pt<2;pt++){
                int px = pix0 + phb + (pt<<4) + m16;
                unsigned long long pk = (unsigned long long)f2bf(acc[ot][pt][0] + bv.x)
                    | ((unsigned long long)f2bf(acc[ot][pt][1] + bv.y)<<16)
                    | ((unsigned long long)f2bf(acc[ot][pt][2] + bv.z)<<32)
                    | ((unsigned long long)f2bf(acc[ot][pt][3] + bv.w)<<48);
                *(unsigned long long*)&Cbf[((size_t)((b<<12) + px))*128 + o0] = pk;
            }
        }
    } else {
        #pragma unroll
        for(int ot=0;ot<2;ot++){
            int o = wo + (ot<<4) + m16;
            float bv = bias[o];
            #pragma unroll
            for(int pt=0;pt<2;pt++){
                #pragma unroll
                for(int r=0;r<4;r++){
                    int px = pix0 + phb + (pt<<4) + (quad<<2) + r;
                    Cbf[((size_t)((b<<12) + px))*128 + o] = f2bf(acc[ot][pt][r] + bv);
                }
            }
        }
    }
}

// ---------------- K4 v4: offset+mask conv, one-shot window staging from bf16 Cbf (pure copy).
__global__ __launch_bounds__(256, 2) void k_offmask(const unsigned short* Cbf, const unsigned short* Wpm,
                                                    fp pb, fp mb, float* OM){
    __shared__ __align__(16) unsigned short sWin[3*66*136];  // 53,856 B [r][col][c]
    __shared__ __align__(16) unsigned short sW[2][32*136];   // 17,408 B dbuf [q][c]
    int b = blockIdx.x & 7;
    int y = blockIdx.x >> 3;          // output row
    int pix0 = y << 6;
    int tid = threadIdx.x;
    int lane = tid & 63, wave = tid >> 6;
    int m16 = lane & 15, quad = lane >> 4;
    int wp = wave << 4;               // px-subtile
    const unsigned short* cbf = Cbf + ((size_t)b<<12)*128;

    // ---- probe: D[m][n]=m*(n+100)
    short8 ap = {0,0,0,0,0,0,0,0}, bpr = {0,0,0,0,0,0,0,0};
    if(quad == 0){
        ap[0]  = (short)f2bf((float)m16);
        bpr[0] = (short)f2bf((float)(m16+100));
    }
    f32x4 dp = {0.f,0.f,0.f,0.f};
    dp = __builtin_amdgcn_mfma_f32_16x16x32_bf16(ap, bpr, dp, 0,0,0);
    bool p1 = true;
    #pragma unroll
    for(int r=0;r<4;r++){
        float expP1 = (float)(quad*4+r) * (float)(m16+100);
        p1 = p1 && (fabsf(dp[r]-expP1) < 0.5f);
    }
    bool swapD = (__ballot(p1) != 0xFFFFFFFFFFFFFFFFull);

    f32x4 acc[2];
    acc[0] = (f32x4){0.f,0.f,0.f,0.f};
    acc[1] = (f32x4){0.f,0.f,0.f,0.f};

    // ---- prologue: issue W(0) loads, stage window (16B copies), write sW[0]
    {
        const int4* wsrc = (const int4*)Wpm;
        int4 wA_ = wsrc[tid], wB_ = wsrc[tid + 256];
        for(int i = tid; i < 3168; i += 256){        // 198 pos x 16 groups of 8 ch
            int pos = i >> 4, g = i & 15;
            int r = pos / 66, col = pos - r*66;
            int yy = y + r - 1, xx = col - 1;
            int4 v = make_int4(0,0,0,0);
            if(yy>=0 && yy<64 && xx>=0 && xx<64)
                v = *(const int4*)&cbf[(size_t)((yy<<6)+xx)*128 + (g<<3)];
            *(int4*)&sWin[pos*136 + (g<<3)] = v;
        }
        *(int4*)&sW[0][(tid>>4)*136 + ((tid&15)<<3)] = wA_;
        int j = tid + 256;
        *(int4*)&sW[0][(j>>4)*136 + ((j&15)<<3)] = wB_;
    }
    __syncthreads();

    for(int n=0;n<9;n++){
        int4 wA_, wB_;
        if(n<8){
            const int4* wsrc = (const int4*)(Wpm + ((n+1)<<12));
            wA_ = wsrc[tid]; wB_ = wsrc[tid + 256];   // issue early; MFMA covers latency
        }
        int ky = n/3, kx = n - ky*3;
        const unsigned short* base = &sWin[(ky*66 + wp + kx)*136];
        #pragma unroll
        for(int ks=0; ks<4; ks++){
            int k0 = ks << 5;
            short8 bfr = *(const short8*)&base[m16*136 + k0 + (quad<<3)];
            #pragma unroll
            for(int qt=0;qt<2;qt++){
                short8 afr = *(const short8*)&sW[n&1][((qt<<4) + m16)*136 + k0 + (quad<<3)];
                acc[qt] = __builtin_amdgcn_mfma_f32_16x16x32_bf16(afr, bfr, acc[qt], 0,0,0);
            }
        }
        if(n<8){
            *(int4*)&sW[(n+1)&1][(tid>>4)*136 + ((tid&15)<<3)] = wA_;
            int j = tid + 256;
            *(int4*)&sW[(n+1)&1][(j>>4)*136 + ((j&15)<<3)] = wB_;
        }
        __syncthreads();
    }
    if(!swapD){
        #pragma unroll
        for(int qt=0;qt<2;qt++){
            int px = pix0 + wp + m16;
            #pragma unroll
            for(int r=0;r<4;r++){
                int q = (qt<<4) + (quad<<2) + r;
                if(q < 27){
                    float v = acc[qt][r] + ((q<18) ? pb[q] : mb[q-18]);
                    if(q>=18) v = 1.f/(1.f+expf(-v));
                    OM[((b*27+q)<<12) + px] = v;
                }
            }
        }
    } else {
        #pragma unroll
        for(int qt=0;qt<2;qt++){
            int q = (qt<<4) + m16;
            if(q < 27){
                float bias = (q<18) ? pb[q] : mb[q-18];
                #pragma unroll
                for(int r=0;r<4;r++){
                    int px = pix0 + wp + (quad<<2) + r;
                    float v = acc[qt][r] + bias;
                    if(q>=18) v = 1.f/(1.f+expf(-v));
                    OM[((b*27+q)<<12) + px] = v;
                }
            }
        }
    }
}

// ---------------- K5 v10: deformable sampling from bf16 Cbf (gather bytes HALVED) + MFMA.
#define K5_META(t) do{ if(tid < 256){ \
    int px_ = tid >> 2, k_ = tid & 3; \
    int pix_ = pix0 + px_; \
    int yq_ = pix_ >> 6, xq_ = pix_ & 63; \
    int kyy_ = (t)/3, kxx_ = (t)-kyy_*3; \
    float oxv_ = omb[((t)<<12)+pix_]; \
    float oyv_ = omb[(((t)+9)<<12)+pix_]; \
    float mv_  = omb[(((t)+18)<<12)+pix_]; \
    float pxf_ = (float)(yq_ + kyy_) + oxv_; \
    float pyf_ = (float)(xq_ + kxx_) + oyv_; \
    float fx_ = floorf(pxf_), fy_ = floorf(pyf_); \
    float qx0_ = fminf(fmaxf(fx_,0.f),65.f),  qx1_ = fminf(fmaxf(fx_+1.f,0.f),65.f); \
    float qy0_ = fminf(fmaxf(fy_,0.f),65.f),  qy1_ = fminf(fmaxf(fy_+1.f,0.f),65.f); \
    float pxc_ = fminf(fmaxf(pxf_,0.f),65.f), pyc_ = fminf(fmaxf(pyf_,0.f),65.f); \
    float dx0_ = 1.f+(qx0_-pxc_), dx1_ = 1.f-(qx1_-pxc_); \
    float dy0_ = 1.f+(qy0_-pyc_), dy1_ = 1.f-(qy1_-pyc_); \
    int ax0_=(int)qx0_, ax1_=(int)qx1_, ay0_=(int)qy0_, ay1_=(int)qy1_; \
    bool vx0_ = (ax0_>=1)&&(ax0_<=64), vx1_ = (ax1_>=1)&&(ax1_<=64); \
    bool vy0_ = (ay0_>=1)&&(ay0_<=64), vy1_ = (ay1_>=1)&&(ay1_<=64); \
    int  axs_ = (k_&1) ? ax1_ : ax0_; \
    int  ays_ = (k_==1||k_==2) ? ay1_ : ay0_; \
    bool vxs_ = (k_&1) ? vx1_ : vx0_; \
    bool vys_ = (k_==1||k_==2) ? vy1_ : vy0_; \
    float dxs_ = (k_&1) ? dx1_ : dx0_; \
    float dys_ = (k_==1||k_==2) ? dy1_ : dy0_; \
    bool v_ = vxs_ && vys_; \
    int base_ = v_ ? (((axs_-1)<<6)+(ays_-1)) : 0; \
    float g_ = v_ ? dxs_*dys_*mv_ : 0.f; \
    sM[tid] = make_uint2((unsigned)base_, __float_as_uint(g_)); \
} }while(0)

#define K5_GATHER(bufp) do{ \
    _Pragma("unroll") \
    for(int j_=0;j_<4;j_++){ \
        int px_ = pxb + (j_<<4); \
        uint2 e0_ = sM[(px_<<2)+0]; \
        uint2 e1_ = sM[(px_<<2)+1]; \
        uint2 e2_ = sM[(px_<<2)+2]; \
        uint2 e3_ = sM[(px_<<2)+3]; \
        float g0_ = __uint_as_float(e0_.y), g1_ = __uint_as_float(e1_.y); \
        float g2_ = __uint_as_float(e2_.y), g3_ = __uint_as_float(e3_.y); \
        uint2 c0_ = *(const uint2*)&cb[((size_t)e0_.x<<7) + cg4]; \
        uint2 c1_ = *(const uint2*)&cb[((size_t)e1_.x<<7) + cg4]; \
        uint2 c2_ = *(const uint2*)&cb[((size_t)e2_.x<<7) + cg4]; \
        uint2 c3_ = *(const uint2*)&cb[((size_t)e3_.x<<7) + cg4]; \
        float vx_ = g0_*bflo(c0_.x) + g1_*bflo(c1_.x) + g2_*bflo(c2_.x) + g3_*bflo(c3_.x); \
        float vy_ = g0_*bfhi(c0_.x) + g1_*bfhi(c1_.x) + g2_*bfhi(c2_.x) + g3_*bfhi(c3_.x); \
        float vz_ = g0_*bflo(c0_.y) + g1_*bflo(c1_.y) + g2_*bflo(c2_.y) + g3_*bflo(c3_.y); \
        float vw_ = g0_*bfhi(c0_.y) + g1_*bfhi(c1_.y) + g2_*bfhi(c2_.y) + g3_*bfhi(c3_.y); \
        unsigned long long pk_ = (unsigned long long)f2bf(vx_) \
            | ((unsigned long long)f2bf(vy_)<<16) \
            | ((unsigned long long)f2bf(vz_)<<32) \
            | ((unsigned long long)f2bf(vw_)<<48); \
        *(unsigned long long*)&(bufp)[px_*136 + cg4] = pk_; \
    } }while(0)

#define K5_STAGE_W(t) do{ \
    const int4* wsrc_ = (const int4*)(Wbf + ((t)<<14)); \
    _Pragma("unroll") \
    for(int k_=0;k_<4;k_++){ int j_ = tid + (k_<<9); \
        *(int4*)&sW[(j_>>4)*136 + ((j_&15)<<3)] = wsrc_[j_]; } }while(0)

#define K5_DOMFMA(srcp) do{ \
    _Pragma("unroll") \
    for(int ks_=0; ks_<4; ks_++){ \
        int k0_ = ks_ << 5; \
        short8 bfr0 = *(const short8*)&(srcp)[(phb + m16)*136 + k0_ + (quad<<3)]; \
        short8 bfr1 = *(const short8*)&(srcp)[(phb + 16 + m16)*136 + k0_ + (quad<<3)]; \
        _Pragma("unroll") \
        for(int ot_=0;ot_<2;ot_++){ \
            short8 afr = *(const short8*)&sW[(wo + (ot_<<4) + m16)*136 + k0_ + (quad<<3)]; \
            acc[ot_][0] = __builtin_amdgcn_mfma_f32_16x16x32_bf16(afr, bfr0, acc[ot_][0], 0,0,0); \
            acc[ot_][1] = __builtin_amdgcn_mfma_f32_16x16x32_bf16(afr, bfr1, acc[ot_][1], 0,0,0); \
        } } }while(0)

__global__ __launch_bounds__(512, 4) void k_deform(const unsigned short* Cbf, fp OM,
                                                   const unsigned short* Wbf,
                                                   float* D, float* stats){
    __shared__ __align__(16) unsigned short sW[128*136];     // 34,816 B [o][c]
    __shared__ __align__(16) unsigned short sX[2][64*136];   // 34,816 B dbuf [px][c]
    __shared__ __align__(8)  uint2 sM[256];                  //  2,048 B meta (base,weight)
    int b = blockIdx.x & 7;
    int pix0 = (blockIdx.x >> 3) << 6;   // 64 tiles (one row each) x 8 b
    int tid = threadIdx.x;               // 0..511
    int lane = tid & 63, wave = tid >> 6;
    int m16 = lane & 15, quad = lane >> 4;
    int wo  = (wave & 3) << 5;           // o-range: 4 groups of 32
    int phb = (wave >> 2) << 5;          // px-half: 0 / 32
    int cg4 = (tid & 31) << 2;           // channel group (4 ch)
    int pxb = tid >> 5;                  // base px 0..15 (handles px pxb, +16, +32, +48)
    const float* omb = OM + b*27*4096;
    const unsigned short* cb = Cbf + ((size_t)b<<12)*128;

    // ---- probe
    short8 ap = {0,0,0,0,0,0,0,0}, bpr = {0,0,0,0,0,0,0,0};
    if(quad == 0){
        ap[0]  = (short)f2bf((float)m16);
        bpr[0] = (short)f2bf((float)(m16+100));
    }
    f32x4 dp = {0.f,0.f,0.f,0.f};
    dp = __builtin_amdgcn_mfma_f32_16x16x32_bf16(ap, bpr, dp, 0,0,0);
    bool p1 = true;
    #pragma unroll
    for(int r=0;r<4;r++){
        float expP1 = (float)(quad*4+r) * (float)(m16+100);
        p1 = p1 && (fabsf(dp[r]-expP1) < 0.5f);
    }
    bool swapD = (__ballot(p1) != 0xFFFFFFFFFFFFFFFFull);

    f32x4 acc[2][2];                     // [ot][pt]
    #pragma unroll
    for(int i=0;i<2;i++){
        #pragma unroll
        for(int j=0;j<2;j++) acc[i][j] = (f32x4){0.f,0.f,0.f,0.f};
    }

    // ---- prologue
    K5_META(0);
    __syncthreads();                      // sM = meta(0)
    K5_GATHER((&sX[0][0]));               // gather(0) using meta(0)
    K5_STAGE_W(0);
    __syncthreads();                      // sX[0], sW(0) ready; sM reads done
    K5_META(1);
    __syncthreads();                      // sM = meta(1)

    for(int n=0;n<9;n++){
        if(n<8) K5_GATHER((&sX[(n+1)&1][0]));  // uses sM = meta(n+1); overlaps MFMA(n)
        K5_DOMFMA((&sX[n&1][0]));              // operands from LDS (sW, sX)
        __syncthreads();                       // sW/sM reads + sX writes done
        if(n<8){
            K5_STAGE_W(n+1);                   // sW <- W(n+1), transient regs
            if(n<7) K5_META(n+2);              // sM <- meta(n+2)
            __syncthreads();                   // sW, sM ready for next iter
        }
    }

    // epilogue: D writes + per-channel sum/sumsq reduction (stats LDS overlaid on dead sX)
    float* sdq = (float*)&sX[0][0];       // [0..127]=sum, [128..255]=sumsq
    if(tid < 256) sdq[tid] = 0.f;
    __syncthreads();
    if(!swapD){
        #pragma unroll
        for(int ot=0;ot<2;ot++){
            #pragma unroll
            for(int pt=0;pt<2;pt++){
                int px = pix0 + phb + (pt<<4) + m16;
                #pragma unroll
                for(int r=0;r<4;r++){
                    int o = wo + (ot<<4) + (quad<<2) + r;
                    D[((b*128+o)<<12) + px] = acc[ot][pt][r];
                }
            }
        }
        #pragma unroll
        for(int ot=0;ot<2;ot++){
            #pragma unroll
            for(int r=0;r<4;r++){
                float s  = acc[ot][0][r] + acc[ot][1][r];
                float s2 = acc[ot][0][r]*acc[ot][0][r] + acc[ot][1][r]*acc[ot][1][r];
                #pragma unroll
                for(int msk=1; msk<16; msk<<=1){
                    s  += __shfl_xor(s, msk, 64);
                    s2 += __shfl_xor(s2, msk, 64);
                }
                if(m16 == 0){
                    int o = wo + (ot<<4) + (quad<<2) + r;
                    atomicAdd(&sdq[o], s);
                    atomicAdd(&sdq[128+o], s2);
                }
            }
        }
    } else {
        #pragma unroll
        for(int ot=0;ot<2;ot++){
            #pragma unroll
            for(int pt=0;pt<2;pt++){
                int o = wo + (ot<<4) + m16;
                #pragma unroll
                for(int r=0;r<4;r++){
                    int px = pix0 + phb + (pt<<4) + (quad<<2) + r;
                    D[((b*128+o)<<12) + px] = acc[ot][pt][r];
                }
            }
        }
        #pragma unroll
        for(int ot=0;ot<2;ot++){
            float s = 0.f, s2 = 0.f;
            #pragma unroll
            for(int pt=0;pt<2;pt++){
                #pragma unroll
                for(int r=0;r<4;r++){
                    float v = acc[ot][pt][r];
                    s += v; s2 += v*v;
                }
            }
            #pragma unroll
            for(int msk=16; msk<64; msk<<=1){
                s  += __shfl_xor(s, msk, 64);
                s2 += __shfl_xor(s2, msk, 64);
            }
            if(quad == 0){
                int o = wo + (ot<<4) + m16;
                atomicAdd(&sdq[o], s);
                atomicAdd(&sdq[128+o], s2);
            }
        }
    }
    __syncthreads();
    if(tid < 128){
        atomicAdd(&stats[tid],     sdq[tid]);
        atomicAdd(&stats[128+tid], sdq[128+tid]);
    }
}

// ---------------- K7: fused BN1+GELU + depthwise128 -> Hs, + atomic stats2 partials
__global__ __launch_bounds__(256) void k_bngelu_dw128(const float* Dsrc, float* stats,
                                                      fp g1, fp b1, fp w, fp bias, float* Hs){
    __shared__ float sG[66*68 + 4];
    __shared__ float sd[256], sq[256];
    int bid = blockIdx.x;
    int c = bid & 127, b = bid >> 7;
    int tid = threadIdx.x;
    float mean1 = stats[c] * (1.f/32768.f);
    float var1  = stats[128+c] * (1.f/32768.f) - mean1*mean1;
    float rstd1 = rsqrtf(var1 + 1e-5f);
    float sc = rstd1 * g1[c];
    float sb = b1[c] - mean1*sc;
    for(int j = tid; j < 264; j += 256){
        int idx;
        if(j < 66)       idx = j;
        else if(j < 132) idx = 65*68 + (j-66);
        else if(j < 196) idx = (j-132+1)*68;
        else if(j < 260) idx = (j-196+1)*68 + 65;
        else             idx = 66*68 + (j-260);
        sG[idx] = 0.f;
    }
    const float* dplane = Dsrc + ((size_t)(b*128+c)<<12);
    for(int j = tid; j < 1024; j += 256){
        int yy = j >> 4, x4 = (j & 15) << 2;
        float4 v = *(const float4*)&dplane[(yy<<6) + x4];
        float g0 = v.x*sc+sb, g1v = v.y*sc+sb, g2 = v.z*sc+sb, g3 = v.w*sc+sb;
        float* d = &sG[(yy+1)*68 + x4 + 1];
        d[0] = 0.5f*g0*(1.0f + erff(g0*0.70710678118654752f));
        d[1] = 0.5f*g1v*(1.0f + erff(g1v*0.70710678118654752f));
        d[2] = 0.5f*g2*(1.0f + erff(g2*0.70710678118654752f));
        d[3] = 0.5f*g3*(1.0f + erff(g3*0.70710678118654752f));
    }
    __syncthreads();
    float w0=w[c*9+0], w1=w[c*9+1], w2=w[c*9+2];
    float w3=w[c*9+3], w4=w[c*9+4], w5=w[c*9+5];
    float w6=w[c*9+6], w7=w[c*9+7], w8=w[c*9+8];
    float bv = bias[c];
    float* dst = Hs + ((size_t)(b*128+c)<<12);
    float s = 0.f, s2 = 0.f;
    for(int j = tid; j < 1024; j += 256){
        int y = j >> 4, x0 = (j & 15) << 2;
        float a0=bv, a1=bv, a2=bv, a3=bv;
        #pragma unroll
        for(int ky=0; ky<3; ky++){
            const float* rr = &sG[(y+ky)*68 + x0];
            float4 u0 = *(const float4*)&rr[0];
            float2 u1 = *(const float2*)&rr[4];
            float wA = (ky==0)?w0:((ky==1)?w3:w6);
            float wB = (ky==0)?w1:((ky==1)?w4:w7);
            float wC = (ky==0)?w2:((ky==1)?w5:w8);
            a0 += wA*u0.x + wB*u0.y + wC*u0.z;
            a1 += wA*u0.y + wB*u0.z + wC*u0.w;
            a2 += wA*u0.z + wB*u0.w + wC*u1.x;
            a3 += wA*u0.w + wB*u1.x + wC*u1.y;
        }
        *(float4*)&dst[(y<<6)+x0] = make_float4(a0,a1,a2,a3);
        s += a0+a1+a2+a3;
        s2 += a0*a0 + a1*a1 + a2*a2 + a3*a3;
    }
    sd[tid]=s; sq[tid]=s2; __syncthreads();
    for(int off=128; off>0; off>>=1){
        if(tid<off){ sd[tid]+=sd[tid+off]; sq[tid]+=sq[tid+off]; }
        __syncthreads();
    }
    if(tid==0){
        atomicAdd(&stats[256+c], sd[0]);
        atomicAdd(&stats[384+c], sq[0]);
    }
}

// ---------------- BN2 + ReLU -> f32 out
__global__ __launch_bounds__(256) void k_bn_relu_out(const float* Hs, const float* stats, fp g, fp bb, float* out){
    int idx = blockIdx.x*256+threadIdx.x;
    int c = (idx>>10)&127;
    float mean2 = stats[256+c] * (1.f/32768.f);
    float var2  = stats[384+c] * (1.f/32768.f) - mean2*mean2;
    float rs = rsqrtf(var2 + 1e-5f) * g[c];
    float sb = bb[c] - mean2*rs;
    float4 v = ((const float4*)Hs)[idx];
    float4 o;
    o.x = fmaxf(v.x*rs+sb, 0.f);
    o.y = fmaxf(v.y*rs+sb, 0.f);
    o.z = fmaxf(v.z*rs+sb, 0.f);
    o.w = fmaxf(v.w*rs+sb, 0.f);
    ((float4*)out)[idx] = o;
}

extern "C" void kernel_launch(void* const* d_in, const int* in_sizes, int n_in,
                              void* d_out, int out_size, void* d_ws, size_t ws_size,
                              hipStream_t stream){
    fp x1   = (fp)d_in[0];
    fp x2   = (fp)d_in[1];
    fp dw_w = (fp)d_in[2];  fp dw_b = (fp)d_in[3];
    fp pw_w = (fp)d_in[4];  fp pw_b = (fp)d_in[5];
    fp p_w  = (fp)d_in[6];  fp p_b  = (fp)d_in[7];
    fp m_w  = (fp)d_in[8];  fp m_b  = (fp)d_in[9];
    fp dcn_w= (fp)d_in[10];
    fp bn1g = (fp)d_in[11]; fp bn1b = (fp)d_in[12];
    fp dw2w = (fp)d_in[13]; fp dw2b = (fp)d_in[14];
    fp bn2g = (fp)d_in[15]; fp bn2b = (fp)d_in[16];

    float* ws  = (float*)d_ws;
    float* Bo  = ws;                    // (8,256,4096) f32 ; D reuses after k_pw
    unsigned short* Cbf = (unsigned short*)(ws + 8388608);   // (8,4096,128) bf16 ; Hs overlays after k_deform
    float* Hs  = ws + 8388608;          // f32 (8,128,4096) — Cbf dead once k_deform finishes
    float* OM  = ws + 12582912;         // (8,27,4096)
    unsigned short* Wbf = (unsigned short*)(ws + 13467648);
    unsigned short* Wpm = (unsigned short*)(ws + 13541376);
    float* stats = ws + 13559808;       // 512 f
    unsigned short* Wpwbf = (unsigned short*)(ws + 13560320);  // 32,768 bf16
    float* D   = Bo;
    float* out = (float*)d_out;

    hipMemsetAsync(stats, 0, 512*sizeof(float), stream);
    k_prep         <<<848,   256, 0, stream>>>(dcn_w, p_w, m_w, pw_w, Wbf, Wpm, Wpwbf);
    k_updw256      <<<2048,  256, 0, stream>>>(x1, x2, dw_w, dw_b, Bo);
    k_pw           <<<512,   512, 0, stream>>>(Bo, Wpwbf, pw_b, Cbf);
    k_offmask      <<<512,   256, 0, stream>>>(Cbf, Wpm, p_b, m_b, OM);
    k_deform       <<<512,   512, 0, stream>>>(Cbf, OM, Wbf, D, stats);
    k_bngelu_dw128 <<<1024,  256, 0, stream>>>(D, stats, bn1g, bn1b, dw2w, dw2b, Hs);
    k_bn_relu_out  <<<4096,  256, 0, stream>>>(Hs, stats, bn2g, bn2b, out);
}

// Round 14
// 200.389 us; speedup vs baseline: 1.3516x; 1.0256x over previous
//
#include <hip/hip_runtime.h>
#include <math.h>

// Problem constants: B=8, spatial 64x64 (HW=4096), C_mid=256, C=128, N=9 taps.
typedef const float* fp;
typedef __attribute__((ext_vector_type(8))) short short8;   // 8 bf16 = 4 VGPRs (MFMA A/B frag)
typedef __attribute__((ext_vector_type(4))) float f32x4;    // MFMA C/D frag

__device__ __forceinline__ unsigned short f2bf(float f){    // RTNE float->bf16
    unsigned u = __float_as_uint(f);
    u += 0x7fff + ((u >> 16) & 1);
    return (unsigned short)(u >> 16);
}
__device__ __forceinline__ float bflo(unsigned u){ return __uint_as_float(u << 16); }
__device__ __forceinline__ float bfhi(unsigned u){ return __uint_as_float(u & 0xffff0000u); }
__device__ __forceinline__ unsigned long long pk4(float a, float b, float c, float d){
    return (unsigned long long)f2bf(a) | ((unsigned long long)f2bf(b)<<16)
         | ((unsigned long long)f2bf(c)<<32) | ((unsigned long long)f2bf(d)<<48);
}

// ---------------- K0: merged prep — Wbf[n][o][c] bf16, Wpm[n][32q][128c] bf16, Wpwbf[o][256c] bf16
__global__ __launch_bounds__(256) void k_prep(fp dcn_w, fp pw, fp mw, fp pww,
                                              unsigned short* Wbf, unsigned short* Wpm,
                                              unsigned short* Wpwbf){
    int i = blockIdx.x*256 + threadIdx.x;       // 217088 = 848 blocks
    if(i < 147456){
        int c = i & 127, o = (i >> 7) & 127, n = i >> 14;
        Wbf[i] = f2bf(dcn_w[o*1152 + c*9 + n]);
    } else if(i < 184320){
        int j = i - 147456;
        int c = j & 127, q = (j >> 7) & 31, n = j >> 12;
        float v = 0.f;
        if(q < 18)      v = pw[q*1152 + c*9 + n];
        else if(q < 27) v = mw[(q-18)*1152 + c*9 + n];
        Wpm[j] = f2bf(v);
    } else {
        int j = i - 184320;                     // 32768: pointwise weights [o][c] bf16
        Wpwbf[j] = f2bf(pww[j]);
    }
}

// ---------------- K1 v2: fused upsample+concat+depthwise256 -> Bo (8,256,4096) BF16
__global__ __launch_bounds__(256) void k_updw256(fp x1, fp x2, fp w, fp bias, unsigned short* Bo){
    __shared__ float sA[66*68 + 4];
    int bid = blockIdx.x;
    int c = bid & 255, b = bid >> 8;
    int tid = threadIdx.x;
    for(int j = tid; j < 264; j += 256){
        int idx;
        if(j < 66)       idx = j;
        else if(j < 132) idx = 65*68 + (j-66);
        else if(j < 196) idx = (j-132+1)*68;
        else if(j < 260) idx = (j-196+1)*68 + 65;
        else             idx = 66*68 + (j-260);
        sA[idx] = 0.f;
    }
    if(c < 128){
        const float* src = x2 + ((size_t)(b*128+c)<<12);
        for(int j = tid; j < 1024; j += 256){
            int yy = j >> 4, x4 = (j & 15) << 2;
            float4 v = *(const float4*)&src[(yy<<6) + x4];
            float* d = &sA[(yy+1)*68 + x4 + 1];
            d[0]=v.x; d[1]=v.y; d[2]=v.z; d[3]=v.w;
        }
    } else {
        int cc = c - 128;
        fp src = x1 + ((b*128+cc)<<10);
        const float s = 31.0f/63.0f;
        for(int j = tid; j < 4096; j += 256){
            int yy = j >> 6, xx = j & 63;
            float fy = yy*s, fx = xx*s;
            int iy = (int)fy; if (iy > 30) iy = 30;
            int ix = (int)fx; if (ix > 30) ix = 30;
            float ty = fy - (float)iy, tx = fx - (float)ix;
            float v00 = src[iy*32+ix],     v01 = src[iy*32+ix+1];
            float v10 = src[(iy+1)*32+ix], v11 = src[(iy+1)*32+ix+1];
            sA[(yy+1)*68 + xx + 1] =
                (v00*(1.f-ty)+v10*ty)*(1.f-tx) + (v01*(1.f-ty)+v11*ty)*tx;
        }
    }
    __syncthreads();
    float w0=w[c*9+0], w1=w[c*9+1], w2=w[c*9+2];
    float w3=w[c*9+3], w4=w[c*9+4], w5=w[c*9+5];
    float w6=w[c*9+6], w7=w[c*9+7], w8=w[c*9+8];
    float bv = bias[c];
    unsigned short* dst = Bo + ((size_t)(b*256+c)<<12);
    for(int j = tid; j < 1024; j += 256){
        int y = j >> 4, x0 = (j & 15) << 2;
        float a0=bv, a1=bv, a2=bv, a3=bv;
        #pragma unroll
        for(int ky=0; ky<3; ky++){
            const float* rr = &sA[(y+ky)*68 + x0];
            float4 u0 = *(const float4*)&rr[0];
            float2 u1 = *(const float2*)&rr[4];
            float wA = (ky==0)?w0:((ky==1)?w3:w6);
            float wB = (ky==0)?w1:((ky==1)?w4:w7);
            float wC = (ky==0)?w2:((ky==1)?w5:w8);
            a0 += wA*u0.x + wB*u0.y + wC*u0.z;
            a1 += wA*u0.y + wB*u0.z + wC*u0.w;
            a2 += wA*u0.z + wB*u0.w + wC*u1.x;
            a3 += wA*u0.w + wB*u1.x + wC*u1.y;
        }
        *(unsigned long long*)&dst[(y<<6)+x0] = pk4(a0,a1,a2,a3);
    }
}

// ---------------- K3 v4: pointwise 256->128 + bias via bf16 MFMA; Bo bf16 in, Cbf bf16 out.
#define PW_STAGE_X(kc, bufp) do{ \
    _Pragma("unroll") \
    for(int k_=0;k_<4;k_++){ \
        int j_ = tid + (k_<<9); \
        int cc_ = j_ >> 4, p4_ = (j_ & 15) << 2; \
        int c_ = ((kc)<<7) + cc_; \
        uint2 v_ = *(const uint2*)&Bo[((size_t)((b<<8)+c_)<<12) + pix0 + p4_]; \
        (bufp)[(p4_+0)*136 + cc_] = (unsigned short)(v_.x & 0xffffu); \
        (bufp)[(p4_+1)*136 + cc_] = (unsigned short)(v_.x >> 16); \
        (bufp)[(p4_+2)*136 + cc_] = (unsigned short)(v_.y & 0xffffu); \
        (bufp)[(p4_+3)*136 + cc_] = (unsigned short)(v_.y >> 16); \
    } }while(0)

#define PW_STAGE_W(kc) do{ \
    _Pragma("unroll") \
    for(int k_=0;k_<4;k_++){ \
        int j_ = tid + (k_<<9); \
        int o_ = j_ >> 4, cg_ = j_ & 15; \
        *(int4*)&sW[o_*136 + (cg_<<3)] = \
            *(const int4*)&Wpwbf[o_*256 + ((kc)<<7) + (cg_<<3)]; \
    } }while(0)

#define PW_DOMFMA(srcp) do{ \
    _Pragma("unroll") \
    for(int ks_=0; ks_<4; ks_++){ \
        int k0_ = ks_ << 5; \
        short8 bfr0 = *(const short8*)&(srcp)[(phb + m16)*136 + k0_ + (quad<<3)]; \
        short8 bfr1 = *(const short8*)&(srcp)[(phb + 16 + m16)*136 + k0_ + (quad<<3)]; \
        _Pragma("unroll") \
        for(int ot_=0;ot_<2;ot_++){ \
            short8 afr = *(const short8*)&sW[(wo + (ot_<<4) + m16)*136 + k0_ + (quad<<3)]; \
            acc[ot_][0] = __builtin_amdgcn_mfma_f32_16x16x32_bf16(afr, bfr0, acc[ot_][0], 0,0,0); \
            acc[ot_][1] = __builtin_amdgcn_mfma_f32_16x16x32_bf16(afr, bfr1, acc[ot_][1], 0,0,0); \
        } } }while(0)

__global__ __launch_bounds__(512, 4) void k_pw(const unsigned short* Bo, const unsigned short* Wpwbf,
                                               fp bias, unsigned short* Cbf){
    __shared__ __align__(16) unsigned short sW[128*136];     // 34,816 B [o][cc]
    __shared__ __align__(16) unsigned short sX[2][64*136];   // 34,816 B dbuf [px][cc]
    int b = blockIdx.x & 7;
    int pix0 = (blockIdx.x >> 3) << 6;   // 64 tiles x 8 b
    int tid = threadIdx.x;               // 0..511
    int lane = tid & 63, wave = tid >> 6;
    int m16 = lane & 15, quad = lane >> 4;
    int wo  = (wave & 3) << 5;           // o-range: 4 groups of 32
    int phb = (wave >> 2) << 5;          // px-half: 0 / 32

    // ---- probe
    short8 ap = {0,0,0,0,0,0,0,0}, bpr = {0,0,0,0,0,0,0,0};
    if(quad == 0){
        ap[0]  = (short)f2bf((float)m16);
        bpr[0] = (short)f2bf((float)(m16+100));
    }
    f32x4 dp = {0.f,0.f,0.f,0.f};
    dp = __builtin_amdgcn_mfma_f32_16x16x32_bf16(ap, bpr, dp, 0,0,0);
    bool p1 = true;
    #pragma unroll
    for(int r=0;r<4;r++){
        float expP1 = (float)(quad*4+r) * (float)(m16+100);
        p1 = p1 && (fabsf(dp[r]-expP1) < 0.5f);
    }
    bool swapD = (__ballot(p1) != 0xFFFFFFFFFFFFFFFFull);

    f32x4 acc[2][2];                     // [ot][pt]
    #pragma unroll
    for(int i=0;i<2;i++){
        #pragma unroll
        for(int j=0;j<2;j++) acc[i][j] = (f32x4){0.f,0.f,0.f,0.f};
    }

    // ---- pipeline: 2 K-chunks
    PW_STAGE_X(0, (&sX[0][0]));
    PW_STAGE_W(0);
    __syncthreads();                      // sX[0], sW(0) ready
    PW_STAGE_X(1, (&sX[1][0]));           // overlaps MFMA(0)
    PW_DOMFMA((&sX[0][0]));
    __syncthreads();                      // MFMA(0) done (sW free), sX[1] writes done
    PW_STAGE_W(1);
    __syncthreads();                      // sW(1) ready
    PW_DOMFMA((&sX[1][0]));

    // ---- epilogue: bias + channel-last bf16 write
    if(!swapD){
        #pragma unroll
        for(int ot=0;ot<2;ot++){
            int o0 = wo + (ot<<4) + (quad<<2);
            float4 bv = *(const float4*)&bias[o0];
            #pragma unroll
            for(int pt=0;pt<2;pt++){
                int px = pix0 + phb + (pt<<4) + m16;
                *(unsigned long long*)&Cbf[((size_t)((b<<12) + px))*128 + o0] =
                    pk4(acc[ot][pt][0]+bv.x, acc[ot][pt][1]+bv.y,
                        acc[ot][pt][2]+bv.z, acc[ot][pt][3]+bv.w);
            }
        }
    } else {
        #pragma unroll
        for(int ot=0;ot<2;ot++){
            int o = wo + (ot<<4) + m16;
            float bv = bias[o];
            #pragma unroll
            for(int pt=0;pt<2;pt++){
                #pragma unroll
                for(int r=0;r<4;r++){
                    int px = pix0 + phb + (pt<<4) + (quad<<2) + r;
                    Cbf[((size_t)((b<<12) + px))*128 + o] = f2bf(acc[ot][pt][r] + bv);
                }
            }
        }
    }
}

// ---------------- K4 v4 (verified): offset+mask conv, one-shot window staging from bf16 Cbf.
__global__ __launch_bounds__(256, 2) void k_offmask(const unsigned short* Cbf, const unsigned short* Wpm,
                                                    fp pb, fp mb, float* OM){
    __shared__ __align__(16) unsigned short sWin[3*66*136];  // 53,856 B [r][col][c]
    __shared__ __align__(16) unsigned short sW[2][32*136];   // 17,408 B dbuf [q][c]
    int b = blockIdx.x & 7;
    int y = blockIdx.x >> 3;          // output row
    int pix0 = y << 6;
    int tid = threadIdx.x;
    int lane = tid & 63, wave = tid >> 6;
    int m16 = lane & 15, quad = lane >> 4;
    int wp = wave << 4;               // px-subtile
    const unsigned short* cbf = Cbf + ((size_t)b<<12)*128;

    // ---- probe: D[m][n]=m*(n+100)
    short8 ap = {0,0,0,0,0,0,0,0}, bpr = {0,0,0,0,0,0,0,0};
    if(quad == 0){
        ap[0]  = (short)f2bf((float)m16);
        bpr[0] = (short)f2bf((float)(m16+100));
    }
    f32x4 dp = {0.f,0.f,0.f,0.f};
    dp = __builtin_amdgcn_mfma_f32_16x16x32_bf16(ap, bpr, dp, 0,0,0);
    bool p1 = true;
    #pragma unroll
    for(int r=0;r<4;r++){
        float expP1 = (float)(quad*4+r) * (float)(m16+100);
        p1 = p1 && (fabsf(dp[r]-expP1) < 0.5f);
    }
    bool swapD = (__ballot(p1) != 0xFFFFFFFFFFFFFFFFull);

    f32x4 acc[2];
    acc[0] = (f32x4){0.f,0.f,0.f,0.f};
    acc[1] = (f32x4){0.f,0.f,0.f,0.f};

    // ---- prologue: issue W(0) loads, stage window (16B copies), write sW[0]
    {
        const int4* wsrc = (const int4*)Wpm;
        int4 wA_ = wsrc[tid], wB_ = wsrc[tid + 256];
        for(int i = tid; i < 3168; i += 256){        // 198 pos x 16 groups of 8 ch
            int pos = i >> 4, g = i & 15;
            int r = pos / 66, col = pos - r*66;
            int yy = y + r - 1, xx = col - 1;
            int4 v = make_int4(0,0,0,0);
            if(yy>=0 && yy<64 && xx>=0 && xx<64)
                v = *(const int4*)&cbf[(size_t)((yy<<6)+xx)*128 + (g<<3)];
            *(int4*)&sWin[pos*136 + (g<<3)] = v;
        }
        *(int4*)&sW[0][(tid>>4)*136 + ((tid&15)<<3)] = wA_;
        int j = tid + 256;
        *(int4*)&sW[0][(j>>4)*136 + ((j&15)<<3)] = wB_;
    }
    __syncthreads();

    for(int n=0;n<9;n++){
        int4 wA_, wB_;
        if(n<8){
            const int4* wsrc = (const int4*)(Wpm + ((n+1)<<12));
            wA_ = wsrc[tid]; wB_ = wsrc[tid + 256];   // issue early; MFMA covers latency
        }
        int ky = n/3, kx = n - ky*3;
        const unsigned short* base = &sWin[(ky*66 + wp + kx)*136];
        #pragma unroll
        for(int ks=0; ks<4; ks++){
            int k0 = ks << 5;
            short8 bfr = *(const short8*)&base[m16*136 + k0 + (quad<<3)];
            #pragma unroll
            for(int qt=0;qt<2;qt++){
                short8 afr = *(const short8*)&sW[n&1][((qt<<4) + m16)*136 + k0 + (quad<<3)];
                acc[qt] = __builtin_amdgcn_mfma_f32_16x16x32_bf16(afr, bfr, acc[qt], 0,0,0);
            }
        }
        if(n<8){
            *(int4*)&sW[(n+1)&1][(tid>>4)*136 + ((tid&15)<<3)] = wA_;
            int j = tid + 256;
            *(int4*)&sW[(n+1)&1][(j>>4)*136 + ((j&15)<<3)] = wB_;
        }
        __syncthreads();
    }
    if(!swapD){
        #pragma unroll
        for(int qt=0;qt<2;qt++){
            int px = pix0 + wp + m16;
            #pragma unroll
            for(int r=0;r<4;r++){
                int q = (qt<<4) + (quad<<2) + r;
                if(q < 27){
                    float v = acc[qt][r] + ((q<18) ? pb[q] : mb[q-18]);
                    if(q>=18) v = 1.f/(1.f+expf(-v));
                    OM[((b*27+q)<<12) + px] = v;
                }
            }
        }
    } else {
        #pragma unroll
        for(int qt=0;qt<2;qt++){
            int q = (qt<<4) + m16;
            if(q < 27){
                float bias = (q<18) ? pb[q] : mb[q-18];
                #pragma unroll
                for(int r=0;r<4;r++){
                    int px = pix0 + wp + (quad<<2) + r;
                    float v = acc[qt][r] + bias;
                    if(q>=18) v = 1.f/(1.f+expf(-v));
                    OM[((b*27+q)<<12) + px] = v;
                }
            }
        }
    }
}

// ---------------- K5 v11: deformable sampling from bf16 Cbf + MFMA; D stored bf16.
#define K5_META(t) do{ if(tid < 256){ \
    int px_ = tid >> 2, k_ = tid & 3; \
    int pix_ = pix0 + px_; \
    int yq_ = pix_ >> 6, xq_ = pix_ & 63; \
    int kyy_ = (t)/3, kxx_ = (t)-kyy_*3; \
    float oxv_ = omb[((t)<<12)+pix_]; \
    float oyv_ = omb[(((t)+9)<<12)+pix_]; \
    float mv_  = omb[(((t)+18)<<12)+pix_]; \
    float pxf_ = (float)(yq_ + kyy_) + oxv_; \
    float pyf_ = (float)(xq_ + kxx_) + oyv_; \
    float fx_ = floorf(pxf_), fy_ = floorf(pyf_); \
    float qx0_ = fminf(fmaxf(fx_,0.f),65.f),  qx1_ = fminf(fmaxf(fx_+1.f,0.f),65.f); \
    float qy0_ = fminf(fmaxf(fy_,0.f),65.f),  qy1_ = fminf(fmaxf(fy_+1.f,0.f),65.f); \
    float pxc_ = fminf(fmaxf(pxf_,0.f),65.f), pyc_ = fminf(fmaxf(pyf_,0.f),65.f); \
    float dx0_ = 1.f+(qx0_-pxc_), dx1_ = 1.f-(qx1_-pxc_); \
    float dy0_ = 1.f+(qy0_-pyc_), dy1_ = 1.f-(qy1_-pyc_); \
    int ax0_=(int)qx0_, ax1_=(int)qx1_, ay0_=(int)qy0_, ay1_=(int)qy1_; \
    bool vx0_ = (ax0_>=1)&&(ax0_<=64), vx1_ = (ax1_>=1)&&(ax1_<=64); \
    bool vy0_ = (ay0_>=1)&&(ay0_<=64), vy1_ = (ay1_>=1)&&(ay1_<=64); \
    int  axs_ = (k_&1) ? ax1_ : ax0_; \
    int  ays_ = (k_==1||k_==2) ? ay1_ : ay0_; \
    bool vxs_ = (k_&1) ? vx1_ : vx0_; \
    bool vys_ = (k_==1||k_==2) ? vy1_ : vy0_; \
    float dxs_ = (k_&1) ? dx1_ : dx0_; \
    float dys_ = (k_==1||k_==2) ? dy1_ : dy0_; \
    bool v_ = vxs_ && vys_; \
    int base_ = v_ ? (((axs_-1)<<6)+(ays_-1)) : 0; \
    float g_ = v_ ? dxs_*dys_*mv_ : 0.f; \
    sM[tid] = make_uint2((unsigned)base_, __float_as_uint(g_)); \
} }while(0)

#define K5_GATHER(bufp) do{ \
    _Pragma("unroll") \
    for(int j_=0;j_<4;j_++){ \
        int px_ = pxb + (j_<<4); \
        uint2 e0_ = sM[(px_<<2)+0]; \
        uint2 e1_ = sM[(px_<<2)+1]; \
        uint2 e2_ = sM[(px_<<2)+2]; \
        uint2 e3_ = sM[(px_<<2)+3]; \
        float g0_ = __uint_as_float(e0_.y), g1_ = __uint_as_float(e1_.y); \
        float g2_ = __uint_as_float(e2_.y), g3_ = __uint_as_float(e3_.y); \
        uint2 c0_ = *(const uint2*)&cb[((size_t)e0_.x<<7) + cg4]; \
        uint2 c1_ = *(const uint2*)&cb[((size_t)e1_.x<<7) + cg4]; \
        uint2 c2_ = *(const uint2*)&cb[((size_t)e2_.x<<7) + cg4]; \
        uint2 c3_ = *(const uint2*)&cb[((size_t)e3_.x<<7) + cg4]; \
        float vx_ = g0_*bflo(c0_.x) + g1_*bflo(c1_.x) + g2_*bflo(c2_.x) + g3_*bflo(c3_.x); \
        float vy_ = g0_*bfhi(c0_.x) + g1_*bfhi(c1_.x) + g2_*bfhi(c2_.x) + g3_*bfhi(c3_.x); \
        float vz_ = g0_*bflo(c0_.y) + g1_*bflo(c1_.y) + g2_*bflo(c2_.y) + g3_*bflo(c3_.y); \
        float vw_ = g0_*bfhi(c0_.y) + g1_*bfhi(c1_.y) + g2_*bfhi(c2_.y) + g3_*bfhi(c3_.y); \
        *(unsigned long long*)&(bufp)[px_*136 + cg4] = pk4(vx_,vy_,vz_,vw_); \
    } }while(0)

#define K5_STAGE_W(t) do{ \
    const int4* wsrc_ = (const int4*)(Wbf + ((t)<<14)); \
    _Pragma("unroll") \
    for(int k_=0;k_<4;k_++){ int j_ = tid + (k_<<9); \
        *(int4*)&sW[(j_>>4)*136 + ((j_&15)<<3)] = wsrc_[j_]; } }while(0)

#define K5_DOMFMA(srcp) do{ \
    _Pragma("unroll") \
    for(int ks_=0; ks_<4; ks_++){ \
        int k0_ = ks_ << 5; \
        short8 bfr0 = *(const short8*)&(srcp)[(phb + m16)*136 + k0_ + (quad<<3)]; \
        short8 bfr1 = *(const short8*)&(srcp)[(phb + 16 + m16)*136 + k0_ + (quad<<3)]; \
        _Pragma("unroll") \
        for(int ot_=0;ot_<2;ot_++){ \
            short8 afr = *(const short8*)&sW[(wo + (ot_<<4) + m16)*136 + k0_ + (quad<<3)]; \
            acc[ot_][0] = __builtin_amdgcn_mfma_f32_16x16x32_bf16(afr, bfr0, acc[ot_][0], 0,0,0); \
            acc[ot_][1] = __builtin_amdgcn_mfma_f32_16x16x32_bf16(afr, bfr1, acc[ot_][1], 0,0,0); \
        } } }while(0)

__global__ __launch_bounds__(512, 4) void k_deform(const unsigned short* Cbf, fp OM,
                                                   const unsigned short* Wbf,
                                                   unsigned short* D, float* stats){
    __shared__ __align__(16) unsigned short sW[128*136];     // 34,816 B [o][c]
    __shared__ __align__(16) unsigned short sX[2][64*136];   // 34,816 B dbuf [px][c]
    __shared__ __align__(8)  uint2 sM[256];                  //  2,048 B meta (base,weight)
    int b = blockIdx.x & 7;
    int pix0 = (blockIdx.x >> 3) << 6;   // 64 tiles (one row each) x 8 b
    int tid = threadIdx.x;               // 0..511
    int lane = tid & 63, wave = tid >> 6;
    int m16 = lane & 15, quad = lane >> 4;
    int wo  = (wave & 3) << 5;           // o-range: 4 groups of 32
    int phb = (wave >> 2) << 5;          // px-half: 0 / 32
    int cg4 = (tid & 31) << 2;           // channel group (4 ch)
    int pxb = tid >> 5;                  // base px 0..15 (handles px pxb, +16, +32, +48)
    const float* omb = OM + b*27*4096;
    const unsigned short* cb = Cbf + ((size_t)b<<12)*128;

    // ---- probe
    short8 ap = {0,0,0,0,0,0,0,0}, bpr = {0,0,0,0,0,0,0,0};
    if(quad == 0){
        ap[0]  = (short)f2bf((float)m16);
        bpr[0] = (short)f2bf((float)(m16+100));
    }
    f32x4 dp = {0.f,0.f,0.f,0.f};
    dp = __builtin_amdgcn_mfma_f32_16x16x32_bf16(ap, bpr, dp, 0,0,0);
    bool p1 = true;
    #pragma unroll
    for(int r=0;r<4;r++){
        float expP1 = (float)(quad*4+r) * (float)(m16+100);
        p1 = p1 && (fabsf(dp[r]-expP1) < 0.5f);
    }
    bool swapD = (__ballot(p1) != 0xFFFFFFFFFFFFFFFFull);

    f32x4 acc[2][2];                     // [ot][pt]
    #pragma unroll
    for(int i=0;i<2;i++){
        #pragma unroll
        for(int j=0;j<2;j++) acc[i][j] = (f32x4){0.f,0.f,0.f,0.f};
    }

    // ---- prologue
    K5_META(0);
    __syncthreads();                      // sM = meta(0)
    K5_GATHER((&sX[0][0]));               // gather(0) using meta(0)
    K5_STAGE_W(0);
    __syncthreads();                      // sX[0], sW(0) ready; sM reads done
    K5_META(1);
    __syncthreads();                      // sM = meta(1)

    for(int n=0;n<9;n++){
        if(n<8) K5_GATHER((&sX[(n+1)&1][0]));  // uses sM = meta(n+1); overlaps MFMA(n)
        K5_DOMFMA((&sX[n&1][0]));              // operands from LDS (sW, sX)
        __syncthreads();                       // sW/sM reads + sX writes done
        if(n<8){
            K5_STAGE_W(n+1);                   // sW <- W(n+1), transient regs
            if(n<7) K5_META(n+2);              // sM <- meta(n+2)
            __syncthreads();                   // sW, sM ready for next iter
        }
    }

    // epilogue: bf16 D writes + per-channel sum/sumsq reduction (stats from f32 acc)
    float* sdq = (float*)&sX[0][0];       // [0..127]=sum, [128..255]=sumsq
    if(tid < 256) sdq[tid] = 0.f;
    __syncthreads();
    if(!swapD){
        #pragma unroll
        for(int ot=0;ot<2;ot++){
            #pragma unroll
            for(int pt=0;pt<2;pt++){
                int px = pix0 + phb + (pt<<4) + m16;
                #pragma unroll
                for(int r=0;r<4;r++){
                    int o = wo + (ot<<4) + (quad<<2) + r;
                    D[((size_t)(b*128+o)<<12) + px] = f2bf(acc[ot][pt][r]);
                }
            }
        }
        #pragma unroll
        for(int ot=0;ot<2;ot++){
            #pragma unroll
            for(int r=0;r<4;r++){
                float s  = acc[ot][0][r] + acc[ot][1][r];
                float s2 = acc[ot][0][r]*acc[ot][0][r] + acc[ot][1][r]*acc[ot][1][r];
                #pragma unroll
                for(int msk=1; msk<16; msk<<=1){
                    s  += __shfl_xor(s, msk, 64);
                    s2 += __shfl_xor(s2, msk, 64);
                }
                if(m16 == 0){
                    int o = wo + (ot<<4) + (quad<<2) + r;
                    atomicAdd(&sdq[o], s);
                    atomicAdd(&sdq[128+o], s2);
                }
            }
        }
    } else {
        #pragma unroll
        for(int ot=0;ot<2;ot++){
            #pragma unroll
            for(int pt=0;pt<2;pt++){
                int o = wo + (ot<<4) + m16;
                #pragma unroll
                for(int r=0;r<4;r++){
                    int px = pix0 + phb + (pt<<4) + (quad<<2) + r;
                    D[((size_t)(b*128+o)<<12) + px] = f2bf(acc[ot][pt][r]);
                }
            }
        }
        #pragma unroll
        for(int ot=0;ot<2;ot++){
            float s = 0.f, s2 = 0.f;
            #pragma unroll
            for(int pt=0;pt<2;pt++){
                #pragma unroll
                for(int r=0;r<4;r++){
                    float v = acc[ot][pt][r];
                    s += v; s2 += v*v;
                }
            }
            #pragma unroll
            for(int msk=16; msk<64; msk<<=1){
                s  += __shfl_xor(s, msk, 64);
                s2 += __shfl_xor(s2, msk, 64);
            }
            if(quad == 0){
                int o = wo + (ot<<4) + m16;
                atomicAdd(&sdq[o], s);
                atomicAdd(&sdq[128+o], s2);
            }
        }
    }
    __syncthreads();
    if(tid < 128){
        atomicAdd(&stats[tid],     sdq[tid]);
        atomicAdd(&stats[128+tid], sdq[128+tid]);
    }
}

// ---------------- K7 v2: fused BN1+GELU + depthwise128 (bf16 D in, bf16 Hs out)
__global__ __launch_bounds__(256) void k_bngelu_dw128(const unsigned short* Dsrc, float* stats,
                                                      fp g1, fp b1, fp w, fp bias, unsigned short* Hs){
    __shared__ float sG[66*68 + 4];
    __shared__ float sd[256], sq[256];
    int bid = blockIdx.x;
    int c = bid & 127, b = bid >> 7;
    int tid = threadIdx.x;
    float mean1 = stats[c] * (1.f/32768.f);
    float var1  = stats[128+c] * (1.f/32768.f) - mean1*mean1;
    float rstd1 = rsqrtf(var1 + 1e-5f);
    float sc = rstd1 * g1[c];
    float sb = b1[c] - mean1*sc;
    for(int j = tid; j < 264; j += 256){
        int idx;
        if(j < 66)       idx = j;
        else if(j < 132) idx = 65*68 + (j-66);
        else if(j < 196) idx = (j-132+1)*68;
        else if(j < 260) idx = (j-196+1)*68 + 65;
        else             idx = 66*68 + (j-260);
        sG[idx] = 0.f;
    }
    const unsigned short* dplane = Dsrc + ((size_t)(b*128+c)<<12);
    for(int j = tid; j < 1024; j += 256){           // 64 rows x 16 groups of 4 px
        int yy = j >> 4, x4 = (j & 15) << 2;
        uint2 v = *(const uint2*)&dplane[(yy<<6) + x4];
        float g0 = bflo(v.x)*sc+sb, g1v = bfhi(v.x)*sc+sb;
        float g2 = bflo(v.y)*sc+sb, g3 = bfhi(v.y)*sc+sb;
        float* d = &sG[(yy+1)*68 + x4 + 1];
        d[0] = 0.5f*g0*(1.0f + erff(g0*0.70710678118654752f));
        d[1] = 0.5f*g1v*(1.0f + erff(g1v*0.70710678118654752f));
        d[2] = 0.5f*g2*(1.0f + erff(g2*0.70710678118654752f));
        d[3] = 0.5f*g3*(1.0f + erff(g3*0.70710678118654752f));
    }
    __syncthreads();
    float w0=w[c*9+0], w1=w[c*9+1], w2=w[c*9+2];
    float w3=w[c*9+3], w4=w[c*9+4], w5=w[c*9+5];
    float w6=w[c*9+6], w7=w[c*9+7], w8=w[c*9+8];
    float bv = bias[c];
    unsigned short* dst = Hs + ((size_t)(b*128+c)<<12);
    float s = 0.f, s2 = 0.f;
    for(int j = tid; j < 1024; j += 256){           // 64 rows x 16 groups of 4 px
        int y = j >> 4, x0 = (j & 15) << 2;
        float a0=bv, a1=bv, a2=bv, a3=bv;
        #pragma unroll
        for(int ky=0; ky<3; ky++){
            const float* rr = &sG[(y+ky)*68 + x0];
            float4 u0 = *(const float4*)&rr[0];
            float2 u1 = *(const float2*)&rr[4];
            float wA = (ky==0)?w0:((ky==1)?w3:w6);
            float wB = (ky==0)?w1:((ky==1)?w4:w7);
            float wC = (ky==0)?w2:((ky==1)?w5:w8);
            a0 += wA*u0.x + wB*u0.y + wC*u0.z;
            a1 += wA*u0.y + wB*u0.z + wC*u0.w;
            a2 += wA*u0.z + wB*u0.w + wC*u1.x;
            a3 += wA*u0.w + wB*u1.x + wC*u1.y;
        }
        *(unsigned long long*)&dst[(y<<6)+x0] = pk4(a0,a1,a2,a3);
        s += a0+a1+a2+a3;
        s2 += a0*a0 + a1*a1 + a2*a2 + a3*a3;
    }
    sd[tid]=s; sq[tid]=s2; __syncthreads();
    for(int off=128; off>0; off>>=1){
        if(tid<off){ sd[tid]+=sd[tid+off]; sq[tid]+=sq[tid+off]; }
        __syncthreads();
    }
    if(tid==0){
        atomicAdd(&stats[256+c], sd[0]);
        atomicAdd(&stats[384+c], sq[0]);
    }
}

// ---------------- BN2 + ReLU -> f32 out (bf16 Hs in)
__global__ __launch_bounds__(256) void k_bn_relu_out(const unsigned short* Hs, const float* stats,
                                                     fp g, fp bb, float* out){
    int idx = blockIdx.x*256+threadIdx.x;       // 1,048,576 groups of 4 px
    int c = (idx>>10)&127;
    float mean2 = stats[256+c] * (1.f/32768.f);
    float var2  = stats[384+c] * (1.f/32768.f) - mean2*mean2;
    float rs = rsqrtf(var2 + 1e-5f) * g[c];
    float sb = bb[c] - mean2*rs;
    uint2 v = ((const uint2*)Hs)[idx];
    float4 o;
    o.x = fmaxf(bflo(v.x)*rs+sb, 0.f);
    o.y = fmaxf(bfhi(v.x)*rs+sb, 0.f);
    o.z = fmaxf(bflo(v.y)*rs+sb, 0.f);
    o.w = fmaxf(bfhi(v.y)*rs+sb, 0.f);
    ((float4*)out)[idx] = o;
}

extern "C" void kernel_launch(void* const* d_in, const int* in_sizes, int n_in,
                              void* d_out, int out_size, void* d_ws, size_t ws_size,
                              hipStream_t stream){
    fp x1   = (fp)d_in[0];
    fp x2   = (fp)d_in[1];
    fp dw_w = (fp)d_in[2];  fp dw_b = (fp)d_in[3];
    fp pw_w = (fp)d_in[4];  fp pw_b = (fp)d_in[5];
    fp p_w  = (fp)d_in[6];  fp p_b  = (fp)d_in[7];
    fp m_w  = (fp)d_in[8];  fp m_b  = (fp)d_in[9];
    fp dcn_w= (fp)d_in[10];
    fp bn1g = (fp)d_in[11]; fp bn1b = (fp)d_in[12];
    fp dw2w = (fp)d_in[13]; fp dw2b = (fp)d_in[14];
    fp bn2g = (fp)d_in[15]; fp bn2b = (fp)d_in[16];

    float* ws  = (float*)d_ws;
    unsigned short* Bo  = (unsigned short*)ws;               // (8,256,4096) bf16 ; D overlays after k_pw
    unsigned short* Cbf = (unsigned short*)(ws + 8388608);   // (8,4096,128) bf16 ; Hs overlays after k_deform
    unsigned short* Hs  = (unsigned short*)(ws + 8388608);   // (8,128,4096) bf16
    float* OM  = ws + 12582912;         // (8,27,4096)
    unsigned short* Wbf = (unsigned short*)(ws + 13467648);
    unsigned short* Wpm = (unsigned short*)(ws + 13541376);
    float* stats = ws + 13559808;       // 512 f
    unsigned short* Wpwbf = (unsigned short*)(ws + 13560320);  // 32,768 bf16
    unsigned short* D   = Bo;           // Bo dead after k_pw
    float* out = (float*)d_out;

    hipMemsetAsync(stats, 0, 512*sizeof(float), stream);
    k_prep         <<<848,   256, 0, stream>>>(dcn_w, p_w, m_w, pw_w, Wbf, Wpm, Wpwbf);
    k_updw256      <<<2048,  256, 0, stream>>>(x1, x2, dw_w, dw_b, Bo);
    k_pw           <<<512,   512, 0, stream>>>(Bo, Wpwbf, pw_b, Cbf);
    k_offmask      <<<512,   256, 0, stream>>>(Cbf, Wpm, p_b, m_b, OM);
    k_deform       <<<512,   512, 0, stream>>>(Cbf, OM, Wbf, D, stats);
    k_bngelu_dw128 <<<1024,  256, 0, stream>>>(D, stats, bn1g, bn1b, dw2w, dw2b, Hs);
    k_bn_relu_out  <<<4096,  256, 0, stream>>>(Hs, stats, bn2g, bn2b, out);
}

// Round 15
// 198.509 us; speedup vs baseline: 1.3644x; 1.0095x over previous
//
#include <hip/hip_runtime.h>
#include <math.h>

// Problem constants: B=8, spatial 64x64 (HW=4096), C_mid=256, C=128, N=9 taps.
typedef const float* fp;
typedef __attribute__((ext_vector_type(8))) short short8;   // 8 bf16 = 4 VGPRs (MFMA A/B frag)
typedef __attribute__((ext_vector_type(4))) float f32x4;    // MFMA C/D frag

__device__ __forceinline__ unsigned short f2bf(float f){    // RTNE float->bf16
    unsigned u = __float_as_uint(f);
    u += 0x7fff + ((u >> 16) & 1);
    return (unsigned short)(u >> 16);
}
__device__ __forceinline__ float bflo(unsigned u){ return __uint_as_float(u << 16); }
__device__ __forceinline__ float bfhi(unsigned u){ return __uint_as_float(u & 0xffff0000u); }
__device__ __forceinline__ unsigned long long pk4(float a, float b, float c, float d){
    return (unsigned long long)f2bf(a) | ((unsigned long long)f2bf(b)<<16)
         | ((unsigned long long)f2bf(c)<<32) | ((unsigned long long)f2bf(d)<<48);
}

// ---------------- K0: merged prep — Wbf[n][o][c] bf16, Wpm[n][32q][128c] bf16, Wpwbf[o][256c] bf16
__global__ __launch_bounds__(256) void k_prep(fp dcn_w, fp pw, fp mw, fp pww,
                                              unsigned short* Wbf, unsigned short* Wpm,
                                              unsigned short* Wpwbf){
    int i = blockIdx.x*256 + threadIdx.x;       // 217088 = 848 blocks
    if(i < 147456){
        int c = i & 127, o = (i >> 7) & 127, n = i >> 14;
        Wbf[i] = f2bf(dcn_w[o*1152 + c*9 + n]);
    } else if(i < 184320){
        int j = i - 147456;
        int c = j & 127, q = (j >> 7) & 31, n = j >> 12;
        float v = 0.f;
        if(q < 18)      v = pw[q*1152 + c*9 + n];
        else if(q < 27) v = mw[(q-18)*1152 + c*9 + n];
        Wpm[j] = f2bf(v);
    } else {
        int j = i - 184320;                     // 32768: pointwise weights [o][c] bf16
        Wpwbf[j] = f2bf(pww[j]);
    }
}

// ---------------- K1 v2: fused upsample+concat+depthwise256 -> Bo (8,256,4096) BF16
__global__ __launch_bounds__(256) void k_updw256(fp x1, fp x2, fp w, fp bias, unsigned short* Bo){
    __shared__ float sA[66*68 + 4];
    int bid = blockIdx.x;
    int c = bid & 255, b = bid >> 8;
    int tid = threadIdx.x;
    for(int j = tid; j < 264; j += 256){
        int idx;
        if(j < 66)       idx = j;
        else if(j < 132) idx = 65*68 + (j-66);
        else if(j < 196) idx = (j-132+1)*68;
        else if(j < 260) idx = (j-196+1)*68 + 65;
        else             idx = 66*68 + (j-260);
        sA[idx] = 0.f;
    }
    if(c < 128){
        const float* src = x2 + ((size_t)(b*128+c)<<12);
        for(int j = tid; j < 1024; j += 256){
            int yy = j >> 4, x4 = (j & 15) << 2;
            float4 v = *(const float4*)&src[(yy<<6) + x4];
            float* d = &sA[(yy+1)*68 + x4 + 1];
            d[0]=v.x; d[1]=v.y; d[2]=v.z; d[3]=v.w;
        }
    } else {
        int cc = c - 128;
        fp src = x1 + ((b*128+cc)<<10);
        const float s = 31.0f/63.0f;
        for(int j = tid; j < 4096; j += 256){
            int yy = j >> 6, xx = j & 63;
            float fy = yy*s, fx = xx*s;
            int iy = (int)fy; if (iy > 30) iy = 30;
            int ix = (int)fx; if (ix > 30) ix = 30;
            float ty = fy - (float)iy, tx = fx - (float)ix;
            float v00 = src[iy*32+ix],     v01 = src[iy*32+ix+1];
            float v10 = src[(iy+1)*32+ix], v11 = src[(iy+1)*32+ix+1];
            sA[(yy+1)*68 + xx + 1] =
                (v00*(1.f-ty)+v10*ty)*(1.f-tx) + (v01*(1.f-ty)+v11*ty)*tx;
        }
    }
    __syncthreads();
    float w0=w[c*9+0], w1=w[c*9+1], w2=w[c*9+2];
    float w3=w[c*9+3], w4=w[c*9+4], w5=w[c*9+5];
    float w6=w[c*9+6], w7=w[c*9+7], w8=w[c*9+8];
    float bv = bias[c];
    unsigned short* dst = Bo + ((size_t)(b*256+c)<<12);
    for(int j = tid; j < 1024; j += 256){
        int y = j >> 4, x0 = (j & 15) << 2;
        float a0=bv, a1=bv, a2=bv, a3=bv;
        #pragma unroll
        for(int ky=0; ky<3; ky++){
            const float* rr = &sA[(y+ky)*68 + x0];
            float4 u0 = *(const float4*)&rr[0];
            float2 u1 = *(const float2*)&rr[4];
            float wA = (ky==0)?w0:((ky==1)?w3:w6);
            float wB = (ky==0)?w1:((ky==1)?w4:w7);
            float wC = (ky==0)?w2:((ky==1)?w5:w8);
            a0 += wA*u0.x + wB*u0.y + wC*u0.z;
            a1 += wA*u0.y + wB*u0.z + wC*u0.w;
            a2 += wA*u0.z + wB*u0.w + wC*u1.x;
            a3 += wA*u0.w + wB*u1.x + wC*u1.y;
        }
        *(unsigned long long*)&dst[(y<<6)+x0] = pk4(a0,a1,a2,a3);
    }
}

// ---------------- K3 v5: pointwise 256->128 + bias via bf16 MFMA; Bo bf16 in, Cbf bf16 out.
// bounds(512,2): LDS (69,632 B) limits to 2 blocks/CU anyway — free the VGPR cap.
#define PW_STAGE_X(kc, bufp) do{ \
    _Pragma("unroll") \
    for(int k_=0;k_<4;k_++){ \
        int j_ = tid + (k_<<9); \
        int cc_ = j_ >> 4, p4_ = (j_ & 15) << 2; \
        int c_ = ((kc)<<7) + cc_; \
        uint2 v_ = *(const uint2*)&Bo[((size_t)((b<<8)+c_)<<12) + pix0 + p4_]; \
        (bufp)[(p4_+0)*136 + cc_] = (unsigned short)(v_.x & 0xffffu); \
        (bufp)[(p4_+1)*136 + cc_] = (unsigned short)(v_.x >> 16); \
        (bufp)[(p4_+2)*136 + cc_] = (unsigned short)(v_.y & 0xffffu); \
        (bufp)[(p4_+3)*136 + cc_] = (unsigned short)(v_.y >> 16); \
    } }while(0)

#define PW_STAGE_W(kc) do{ \
    _Pragma("unroll") \
    for(int k_=0;k_<4;k_++){ \
        int j_ = tid + (k_<<9); \
        int o_ = j_ >> 4, cg_ = j_ & 15; \
        *(int4*)&sW[o_*136 + (cg_<<3)] = \
            *(const int4*)&Wpwbf[o_*256 + ((kc)<<7) + (cg_<<3)]; \
    } }while(0)

#define PW_DOMFMA(srcp) do{ \
    _Pragma("unroll") \
    for(int ks_=0; ks_<4; ks_++){ \
        int k0_ = ks_ << 5; \
        short8 bfr0 = *(const short8*)&(srcp)[(phb + m16)*136 + k0_ + (quad<<3)]; \
        short8 bfr1 = *(const short8*)&(srcp)[(phb + 16 + m16)*136 + k0_ + (quad<<3)]; \
        _Pragma("unroll") \
        for(int ot_=0;ot_<2;ot_++){ \
            short8 afr = *(const short8*)&sW[(wo + (ot_<<4) + m16)*136 + k0_ + (quad<<3)]; \
            acc[ot_][0] = __builtin_amdgcn_mfma_f32_16x16x32_bf16(afr, bfr0, acc[ot_][0], 0,0,0); \
            acc[ot_][1] = __builtin_amdgcn_mfma_f32_16x16x32_bf16(afr, bfr1, acc[ot_][1], 0,0,0); \
        } } }while(0)

__global__ __launch_bounds__(512, 2) void k_pw(const unsigned short* Bo, const unsigned short* Wpwbf,
                                               fp bias, unsigned short* Cbf){
    __shared__ __align__(16) unsigned short sW[128*136];     // 34,816 B [o][cc]
    __shared__ __align__(16) unsigned short sX[2][64*136];   // 34,816 B dbuf [px][cc]
    int b = blockIdx.x & 7;
    int pix0 = (blockIdx.x >> 3) << 6;   // 64 tiles x 8 b
    int tid = threadIdx.x;               // 0..511
    int lane = tid & 63, wave = tid >> 6;
    int m16 = lane & 15, quad = lane >> 4;
    int wo  = (wave & 3) << 5;           // o-range: 4 groups of 32
    int phb = (wave >> 2) << 5;          // px-half: 0 / 32

    // ---- probe
    short8 ap = {0,0,0,0,0,0,0,0}, bpr = {0,0,0,0,0,0,0,0};
    if(quad == 0){
        ap[0]  = (short)f2bf((float)m16);
        bpr[0] = (short)f2bf((float)(m16+100));
    }
    f32x4 dp = {0.f,0.f,0.f,0.f};
    dp = __builtin_amdgcn_mfma_f32_16x16x32_bf16(ap, bpr, dp, 0,0,0);
    bool p1 = true;
    #pragma unroll
    for(int r=0;r<4;r++){
        float expP1 = (float)(quad*4+r) * (float)(m16+100);
        p1 = p1 && (fabsf(dp[r]-expP1) < 0.5f);
    }
    bool swapD = (__ballot(p1) != 0xFFFFFFFFFFFFFFFFull);

    f32x4 acc[2][2];                     // [ot][pt]
    #pragma unroll
    for(int i=0;i<2;i++){
        #pragma unroll
        for(int j=0;j<2;j++) acc[i][j] = (f32x4){0.f,0.f,0.f,0.f};
    }

    // ---- pipeline: 2 K-chunks
    PW_STAGE_X(0, (&sX[0][0]));
    PW_STAGE_W(0);
    __syncthreads();                      // sX[0], sW(0) ready
    PW_STAGE_X(1, (&sX[1][0]));           // overlaps MFMA(0)
    PW_DOMFMA((&sX[0][0]));
    __syncthreads();                      // MFMA(0) done (sW free), sX[1] writes done
    PW_STAGE_W(1);
    __syncthreads();                      // sW(1) ready
    PW_DOMFMA((&sX[1][0]));

    // ---- epilogue: bias + channel-last bf16 write
    if(!swapD){
        #pragma unroll
        for(int ot=0;ot<2;ot++){
            int o0 = wo + (ot<<4) + (quad<<2);
            float4 bv = *(const float4*)&bias[o0];
            #pragma unroll
            for(int pt=0;pt<2;pt++){
                int px = pix0 + phb + (pt<<4) + m16;
                *(unsigned long long*)&Cbf[((size_t)((b<<12) + px))*128 + o0] =
                    pk4(acc[ot][pt][0]+bv.x, acc[ot][pt][1]+bv.y,
                        acc[ot][pt][2]+bv.z, acc[ot][pt][3]+bv.w);
            }
        }
    } else {
        #pragma unroll
        for(int ot=0;ot<2;ot++){
            int o = wo + (ot<<4) + m16;
            float bv = bias[o];
            #pragma unroll
            for(int pt=0;pt<2;pt++){
                #pragma unroll
                for(int r=0;r<4;r++){
                    int px = pix0 + phb + (pt<<4) + (quad<<2) + r;
                    Cbf[((size_t)((b<<12) + px))*128 + o] = f2bf(acc[ot][pt][r] + bv);
                }
            }
        }
    }
}

// ---------------- K4 v4 (verified): offset+mask conv, one-shot window staging from bf16 Cbf.
__global__ __launch_bounds__(256, 2) void k_offmask(const unsigned short* Cbf, const unsigned short* Wpm,
                                                    fp pb, fp mb, float* OM){
    __shared__ __align__(16) unsigned short sWin[3*66*136];  // 53,856 B [r][col][c]
    __shared__ __align__(16) unsigned short sW[2][32*136];   // 17,408 B dbuf [q][c]
    int b = blockIdx.x & 7;
    int y = blockIdx.x >> 3;          // output row
    int pix0 = y << 6;
    int tid = threadIdx.x;
    int lane = tid & 63, wave = tid >> 6;
    int m16 = lane & 15, quad = lane >> 4;
    int wp = wave << 4;               // px-subtile
    const unsigned short* cbf = Cbf + ((size_t)b<<12)*128;

    // ---- probe: D[m][n]=m*(n+100)
    short8 ap = {0,0,0,0,0,0,0,0}, bpr = {0,0,0,0,0,0,0,0};
    if(quad == 0){
        ap[0]  = (short)f2bf((float)m16);
        bpr[0] = (short)f2bf((float)(m16+100));
    }
    f32x4 dp = {0.f,0.f,0.f,0.f};
    dp = __builtin_amdgcn_mfma_f32_16x16x32_bf16(ap, bpr, dp, 0,0,0);
    bool p1 = true;
    #pragma unroll
    for(int r=0;r<4;r++){
        float expP1 = (float)(quad*4+r) * (float)(m16+100);
        p1 = p1 && (fabsf(dp[r]-expP1) < 0.5f);
    }
    bool swapD = (__ballot(p1) != 0xFFFFFFFFFFFFFFFFull);

    f32x4 acc[2];
    acc[0] = (f32x4){0.f,0.f,0.f,0.f};
    acc[1] = (f32x4){0.f,0.f,0.f,0.f};

    // ---- prologue: issue W(0) loads, stage window (16B copies), write sW[0]
    {
        const int4* wsrc = (const int4*)Wpm;
        int4 wA_ = wsrc[tid], wB_ = wsrc[tid + 256];
        for(int i = tid; i < 3168; i += 256){        // 198 pos x 16 groups of 8 ch
            int pos = i >> 4, g = i & 15;
            int r = pos / 66, col = pos - r*66;
            int yy = y + r - 1, xx = col - 1;
            int4 v = make_int4(0,0,0,0);
            if(yy>=0 && yy<64 && xx>=0 && xx<64)
                v = *(const int4*)&cbf[(size_t)((yy<<6)+xx)*128 + (g<<3)];
            *(int4*)&sWin[pos*136 + (g<<3)] = v;
        }
        *(int4*)&sW[0][(tid>>4)*136 + ((tid&15)<<3)] = wA_;
        int j = tid + 256;
        *(int4*)&sW[0][(j>>4)*136 + ((j&15)<<3)] = wB_;
    }
    __syncthreads();

    for(int n=0;n<9;n++){
        int4 wA_, wB_;
        if(n<8){
            const int4* wsrc = (const int4*)(Wpm + ((n+1)<<12));
            wA_ = wsrc[tid]; wB_ = wsrc[tid + 256];   // issue early; MFMA covers latency
        }
        int ky = n/3, kx = n - ky*3;
        const unsigned short* base = &sWin[(ky*66 + wp + kx)*136];
        #pragma unroll
        for(int ks=0; ks<4; ks++){
            int k0 = ks << 5;
            short8 bfr = *(const short8*)&base[m16*136 + k0 + (quad<<3)];
            #pragma unroll
            for(int qt=0;qt<2;qt++){
                short8 afr = *(const short8*)&sW[n&1][((qt<<4) + m16)*136 + k0 + (quad<<3)];
                acc[qt] = __builtin_amdgcn_mfma_f32_16x16x32_bf16(afr, bfr, acc[qt], 0,0,0);
            }
        }
        if(n<8){
            *(int4*)&sW[(n+1)&1][(tid>>4)*136 + ((tid&15)<<3)] = wA_;
            int j = tid + 256;
            *(int4*)&sW[(n+1)&1][(j>>4)*136 + ((j&15)<<3)] = wB_;
        }
        __syncthreads();
    }
    if(!swapD){
        #pragma unroll
        for(int qt=0;qt<2;qt++){
            int px = pix0 + wp + m16;
            #pragma unroll
            for(int r=0;r<4;r++){
                int q = (qt<<4) + (quad<<2) + r;
                if(q < 27){
                    float v = acc[qt][r] + ((q<18) ? pb[q] : mb[q-18]);
                    if(q>=18) v = 1.f/(1.f+expf(-v));
                    OM[((b*27+q)<<12) + px] = v;
                }
            }
        }
    } else {
        #pragma unroll
        for(int qt=0;qt<2;qt++){
            int q = (qt<<4) + m16;
            if(q < 27){
                float bias = (q<18) ? pb[q] : mb[q-18];
                #pragma unroll
                for(int r=0;r<4;r++){
                    int px = pix0 + wp + (quad<<2) + r;
                    float v = acc[qt][r] + bias;
                    if(q>=18) v = 1.f/(1.f+expf(-v));
                    OM[((b*27+q)<<12) + px] = v;
                }
            }
        }
    }
}

// ---------------- K5 v12: deformable sampling from bf16 Cbf + MFMA; D bf16.
// bounds(512,2): LDS (71,680 B) limits to 2 blocks/CU anyway — free the VGPR cap
// (was 56 under bounds(512,4); gather wants 16+ loads in flight).
#define K5_META(t) do{ if(tid < 256){ \
    int px_ = tid >> 2, k_ = tid & 3; \
    int pix_ = pix0 + px_; \
    int yq_ = pix_ >> 6, xq_ = pix_ & 63; \
    int kyy_ = (t)/3, kxx_ = (t)-kyy_*3; \
    float oxv_ = omb[((t)<<12)+pix_]; \
    float oyv_ = omb[(((t)+9)<<12)+pix_]; \
    float mv_  = omb[(((t)+18)<<12)+pix_]; \
    float pxf_ = (float)(yq_ + kyy_) + oxv_; \
    float pyf_ = (float)(xq_ + kxx_) + oyv_; \
    float fx_ = floorf(pxf_), fy_ = floorf(pyf_); \
    float qx0_ = fminf(fmaxf(fx_,0.f),65.f),  qx1_ = fminf(fmaxf(fx_+1.f,0.f),65.f); \
    float qy0_ = fminf(fmaxf(fy_,0.f),65.f),  qy1_ = fminf(fmaxf(fy_+1.f,0.f),65.f); \
    float pxc_ = fminf(fmaxf(pxf_,0.f),65.f), pyc_ = fminf(fmaxf(pyf_,0.f),65.f); \
    float dx0_ = 1.f+(qx0_-pxc_), dx1_ = 1.f-(qx1_-pxc_); \
    float dy0_ = 1.f+(qy0_-pyc_), dy1_ = 1.f-(qy1_-pyc_); \
    int ax0_=(int)qx0_, ax1_=(int)qx1_, ay0_=(int)qy0_, ay1_=(int)qy1_; \
    bool vx0_ = (ax0_>=1)&&(ax0_<=64), vx1_ = (ax1_>=1)&&(ax1_<=64); \
    bool vy0_ = (ay0_>=1)&&(ay0_<=64), vy1_ = (ay1_>=1)&&(ay1_<=64); \
    int  axs_ = (k_&1) ? ax1_ : ax0_; \
    int  ays_ = (k_==1||k_==2) ? ay1_ : ay0_; \
    bool vxs_ = (k_&1) ? vx1_ : vx0_; \
    bool vys_ = (k_==1||k_==2) ? vy1_ : vy0_; \
    float dxs_ = (k_&1) ? dx1_ : dx0_; \
    float dys_ = (k_==1||k_==2) ? dy1_ : dy0_; \
    bool v_ = vxs_ && vys_; \
    int base_ = v_ ? (((axs_-1)<<6)+(ays_-1)) : 0; \
    float g_ = v_ ? dxs_*dys_*mv_ : 0.f; \
    sM[tid] = make_uint2((unsigned)base_, __float_as_uint(g_)); \
} }while(0)

#define K5_GATHER(bufp) do{ \
    _Pragma("unroll") \
    for(int j_=0;j_<4;j_++){ \
        int px_ = pxb + (j_<<4); \
        uint2 e0_ = sM[(px_<<2)+0]; \
        uint2 e1_ = sM[(px_<<2)+1]; \
        uint2 e2_ = sM[(px_<<2)+2]; \
        uint2 e3_ = sM[(px_<<2)+3]; \
        float g0_ = __uint_as_float(e0_.y), g1_ = __uint_as_float(e1_.y); \
        float g2_ = __uint_as_float(e2_.y), g3_ = __uint_as_float(e3_.y); \
        uint2 c0_ = *(const uint2*)&cb[((size_t)e0_.x<<7) + cg4]; \
        uint2 c1_ = *(const uint2*)&cb[((size_t)e1_.x<<7) + cg4]; \
        uint2 c2_ = *(const uint2*)&cb[((size_t)e2_.x<<7) + cg4]; \
        uint2 c3_ = *(const uint2*)&cb[((size_t)e3_.x<<7) + cg4]; \
        float vx_ = g0_*bflo(c0_.x) + g1_*bflo(c1_.x) + g2_*bflo(c2_.x) + g3_*bflo(c3_.x); \
        float vy_ = g0_*bfhi(c0_.x) + g1_*bfhi(c1_.x) + g2_*bfhi(c2_.x) + g3_*bfhi(c3_.x); \
        float vz_ = g0_*bflo(c0_.y) + g1_*bflo(c1_.y) + g2_*bflo(c2_.y) + g3_*bflo(c3_.y); \
        float vw_ = g0_*bfhi(c0_.y) + g1_*bfhi(c1_.y) + g2_*bfhi(c2_.y) + g3_*bfhi(c3_.y); \
        *(unsigned long long*)&(bufp)[px_*136 + cg4] = pk4(vx_,vy_,vz_,vw_); \
    } }while(0)

#define K5_STAGE_W(t) do{ \
    const int4* wsrc_ = (const int4*)(Wbf + ((t)<<14)); \
    _Pragma("unroll") \
    for(int k_=0;k_<4;k_++){ int j_ = tid + (k_<<9); \
        *(int4*)&sW[(j_>>4)*136 + ((j_&15)<<3)] = wsrc_[j_]; } }while(0)

#define K5_DOMFMA(srcp) do{ \
    _Pragma("unroll") \
    for(int ks_=0; ks_<4; ks_++){ \
        int k0_ = ks_ << 5; \
        short8 bfr0 = *(const short8*)&(srcp)[(phb + m16)*136 + k0_ + (quad<<3)]; \
        short8 bfr1 = *(const short8*)&(srcp)[(phb + 16 + m16)*136 + k0_ + (quad<<3)]; \
        _Pragma("unroll") \
        for(int ot_=0;ot_<2;ot_++){ \
            short8 afr = *(const short8*)&sW[(wo + (ot_<<4) + m16)*136 + k0_ + (quad<<3)]; \
            acc[ot_][0] = __builtin_amdgcn_mfma_f32_16x16x32_bf16(afr, bfr0, acc[ot_][0], 0,0,0); \
            acc[ot_][1] = __builtin_amdgcn_mfma_f32_16x16x32_bf16(afr, bfr1, acc[ot_][1], 0,0,0); \
        } } }while(0)

__global__ __launch_bounds__(512, 2) void k_deform(const unsigned short* Cbf, fp OM,
                                                   const unsigned short* Wbf,
                                                   unsigned short* D, float* stats){
    __shared__ __align__(16) unsigned short sW[128*136];     // 34,816 B [o][c]
    __shared__ __align__(16) unsigned short sX[2][64*136];   // 34,816 B dbuf [px][c]
    __shared__ __align__(8)  uint2 sM[256];                  //  2,048 B meta (base,weight)
    int b = blockIdx.x & 7;
    int pix0 = (blockIdx.x >> 3) << 6;   // 64 tiles (one row each) x 8 b
    int tid = threadIdx.x;               // 0..511
    int lane = tid & 63, wave = tid >> 6;
    int m16 = lane & 15, quad = lane >> 4;
    int wo  = (wave & 3) << 5;           // o-range: 4 groups of 32
    int phb = (wave >> 2) << 5;          // px-half: 0 / 32
    int cg4 = (tid & 31) << 2;           // channel group (4 ch)
    int pxb = tid >> 5;                  // base px 0..15 (handles px pxb, +16, +32, +48)
    const float* omb = OM + b*27*4096;
    const unsigned short* cb = Cbf + ((size_t)b<<12)*128;

    // ---- probe
    short8 ap = {0,0,0,0,0,0,0,0}, bpr = {0,0,0,0,0,0,0,0};
    if(quad == 0){
        ap[0]  = (short)f2bf((float)m16);
        bpr[0] = (short)f2bf((float)(m16+100));
    }
    f32x4 dp = {0.f,0.f,0.f,0.f};
    dp = __builtin_amdgcn_mfma_f32_16x16x32_bf16(ap, bpr, dp, 0,0,0);
    bool p1 = true;
    #pragma unroll
    for(int r=0;r<4;r++){
        float expP1 = (float)(quad*4+r) * (float)(m16+100);
        p1 = p1 && (fabsf(dp[r]-expP1) < 0.5f);
    }
    bool swapD = (__ballot(p1) != 0xFFFFFFFFFFFFFFFFull);

    f32x4 acc[2][2];                     // [ot][pt]
    #pragma unroll
    for(int i=0;i<2;i++){
        #pragma unroll
        for(int j=0;j<2;j++) acc[i][j] = (f32x4){0.f,0.f,0.f,0.f};
    }

    // ---- prologue
    K5_META(0);
    __syncthreads();                      // sM = meta(0)
    K5_GATHER((&sX[0][0]));               // gather(0) using meta(0)
    K5_STAGE_W(0);
    __syncthreads();                      // sX[0], sW(0) ready; sM reads done
    K5_META(1);
    __syncthreads();                      // sM = meta(1)

    for(int n=0;n<9;n++){
        if(n<8) K5_GATHER((&sX[(n+1)&1][0]));  // uses sM = meta(n+1); overlaps MFMA(n)
        K5_DOMFMA((&sX[n&1][0]));              // operands from LDS (sW, sX)
        __syncthreads();                       // sW/sM reads + sX writes done
        if(n<8){
            K5_STAGE_W(n+1);                   // sW <- W(n+1), transient regs
            if(n<7) K5_META(n+2);              // sM <- meta(n+2)
            __syncthreads();                   // sW, sM ready for next iter
        }
    }

    // epilogue: bf16 D writes + per-channel sum/sumsq reduction (stats from f32 acc)
    float* sdq = (float*)&sX[0][0];       // [0..127]=sum, [128..255]=sumsq
    if(tid < 256) sdq[tid] = 0.f;
    __syncthreads();
    if(!swapD){
        #pragma unroll
        for(int ot=0;ot<2;ot++){
            #pragma unroll
            for(int pt=0;pt<2;pt++){
                int px = pix0 + phb + (pt<<4) + m16;
                #pragma unroll
                for(int r=0;r<4;r++){
                    int o = wo + (ot<<4) + (quad<<2) + r;
                    D[((size_t)(b*128+o)<<12) + px] = f2bf(acc[ot][pt][r]);
                }
            }
        }
        #pragma unroll
        for(int ot=0;ot<2;ot++){
            #pragma unroll
            for(int r=0;r<4;r++){
                float s  = acc[ot][0][r] + acc[ot][1][r];
                float s2 = acc[ot][0][r]*acc[ot][0][r] + acc[ot][1][r]*acc[ot][1][r];
                #pragma unroll
                for(int msk=1; msk<16; msk<<=1){
                    s  += __shfl_xor(s, msk, 64);
                    s2 += __shfl_xor(s2, msk, 64);
                }
                if(m16 == 0){
                    int o = wo + (ot<<4) + (quad<<2) + r;
                    atomicAdd(&sdq[o], s);
                    atomicAdd(&sdq[128+o], s2);
                }
            }
        }
    } else {
        #pragma unroll
        for(int ot=0;ot<2;ot++){
            #pragma unroll
            for(int pt=0;pt<2;pt++){
                int o = wo + (ot<<4) + m16;
                #pragma unroll
                for(int r=0;r<4;r++){
                    int px = pix0 + phb + (pt<<4) + (quad<<2) + r;
                    D[((size_t)(b*128+o)<<12) + px] = f2bf(acc[ot][pt][r]);
                }
            }
        }
        #pragma unroll
        for(int ot=0;ot<2;ot++){
            float s = 0.f, s2 = 0.f;
            #pragma unroll
            for(int pt=0;pt<2;pt++){
                #pragma unroll
                for(int r=0;r<4;r++){
                    float v = acc[ot][pt][r];
                    s += v; s2 += v*v;
                }
            }
            #pragma unroll
            for(int msk=16; msk<64; msk<<=1){
                s  += __shfl_xor(s, msk, 64);
                s2 += __shfl_xor(s2, msk, 64);
            }
            if(quad == 0){
                int o = wo + (ot<<4) + m16;
                atomicAdd(&sdq[o], s);
                atomicAdd(&sdq[128+o], s2);
            }
        }
    }
    __syncthreads();
    if(tid < 128){
        atomicAdd(&stats[tid],     sdq[tid]);
        atomicAdd(&stats[128+tid], sdq[128+tid]);
    }
}

// ---------------- K7 v2: fused BN1+GELU + depthwise128 (bf16 D in, bf16 Hs out)
__global__ __launch_bounds__(256) void k_bngelu_dw128(const unsigned short* Dsrc, float* stats,
                                                      fp g1, fp b1, fp w, fp bias, unsigned short* Hs){
    __shared__ float sG[66*68 + 4];
    __shared__ float sd[256], sq[256];
    int bid = blockIdx.x;
    int c = bid & 127, b = bid >> 7;
    int tid = threadIdx.x;
    float mean1 = stats[c] * (1.f/32768.f);
    float var1  = stats[128+c] * (1.f/32768.f) - mean1*mean1;
    float rstd1 = rsqrtf(var1 + 1e-5f);
    float sc = rstd1 * g1[c];
    float sb = b1[c] - mean1*sc;
    for(int j = tid; j < 264; j += 256){
        int idx;
        if(j < 66)       idx = j;
        else if(j < 132) idx = 65*68 + (j-66);
        else if(j < 196) idx = (j-132+1)*68;
        else if(j < 260) idx = (j-196+1)*68 + 65;
        else             idx = 66*68 + (j-260);
        sG[idx] = 0.f;
    }
    const unsigned short* dplane = Dsrc + ((size_t)(b*128+c)<<12);
    for(int j = tid; j < 1024; j += 256){           // 64 rows x 16 groups of 4 px
        int yy = j >> 4, x4 = (j & 15) << 2;
        uint2 v = *(const uint2*)&dplane[(yy<<6) + x4];
        float g0 = bflo(v.x)*sc+sb, g1v = bfhi(v.x)*sc+sb;
        float g2 = bflo(v.y)*sc+sb, g3 = bfhi(v.y)*sc+sb;
        float* d = &sG[(yy+1)*68 + x4 + 1];
        d[0] = 0.5f*g0*(1.0f + erff(g0*0.70710678118654752f));
        d[1] = 0.5f*g1v*(1.0f + erff(g1v*0.70710678118654752f));
        d[2] = 0.5f*g2*(1.0f + erff(g2*0.70710678118654752f));
        d[3] = 0.5f*g3*(1.0f + erff(g3*0.70710678118654752f));
    }
    __syncthreads();
    float w0=w[c*9+0], w1=w[c*9+1], w2=w[c*9+2];
    float w3=w[c*9+3], w4=w[c*9+4], w5=w[c*9+5];
    float w6=w[c*9+6], w7=w[c*9+7], w8=w[c*9+8];
    float bv = bias[c];
    unsigned short* dst = Hs + ((size_t)(b*128+c)<<12);
    float s = 0.f, s2 = 0.f;
    for(int j = tid; j < 1024; j += 256){           // 64 rows x 16 groups of 4 px
        int y = j >> 4, x0 = (j & 15) << 2;
        float a0=bv, a1=bv, a2=bv, a3=bv;
        #pragma unroll
        for(int ky=0; ky<3; ky++){
            const float* rr = &sG[(y+ky)*68 + x0];
            float4 u0 = *(const float4*)&rr[0];
            float2 u1 = *(const float2*)&rr[4];
            float wA = (ky==0)?w0:((ky==1)?w3:w6);
            float wB = (ky==0)?w1:((ky==1)?w4:w7);
            float wC = (ky==0)?w2:((ky==1)?w5:w8);
            a0 += wA*u0.x + wB*u0.y + wC*u0.z;
            a1 += wA*u0.y + wB*u0.z + wC*u0.w;
            a2 += wA*u0.z + wB*u0.w + wC*u1.x;
            a3 += wA*u0.w + wB*u1.x + wC*u1.y;
        }
        *(unsigned long long*)&dst[(y<<6)+x0] = pk4(a0,a1,a2,a3);
        s += a0+a1+a2+a3;
        s2 += a0*a0 + a1*a1 + a2*a2 + a3*a3;
    }
    sd[tid]=s; sq[tid]=s2; __syncthreads();
    for(int off=128; off>0; off>>=1){
        if(tid<off){ sd[tid]+=sd[tid+off]; sq[tid]+=sq[tid+off]; }
        __syncthreads();
    }
    if(tid==0){
        atomicAdd(&stats[256+c], sd[0]);
        atomicAdd(&stats[384+c], sq[0]);
    }
}

// ---------------- BN2 + ReLU -> f32 out (bf16 Hs in)
__global__ __launch_bounds__(256) void k_bn_relu_out(const unsigned short* Hs, const float* stats,
                                                     fp g, fp bb, float* out){
    int idx = blockIdx.x*256+threadIdx.x;       // 1,048,576 groups of 4 px
    int c = (idx>>10)&127;
    float mean2 = stats[256+c] * (1.f/32768.f);
    float var2  = stats[384+c] * (1.f/32768.f) - mean2*mean2;
    float rs = rsqrtf(var2 + 1e-5f) * g[c];
    float sb = bb[c] - mean2*rs;
    uint2 v = ((const uint2*)Hs)[idx];
    float4 o;
    o.x = fmaxf(bflo(v.x)*rs+sb, 0.f);
    o.y = fmaxf(bfhi(v.x)*rs+sb, 0.f);
    o.z = fmaxf(bflo(v.y)*rs+sb, 0.f);
    o.w = fmaxf(bfhi(v.y)*rs+sb, 0.f);
    ((float4*)out)[idx] = o;
}

extern "C" void kernel_launch(void* const* d_in, const int* in_sizes, int n_in,
                              void* d_out, int out_size, void* d_ws, size_t ws_size,
                              hipStream_t stream){
    fp x1   = (fp)d_in[0];
    fp x2   = (fp)d_in[1];
    fp dw_w = (fp)d_in[2];  fp dw_b = (fp)d_in[3];
    fp pw_w = (fp)d_in[4];  fp pw_b = (fp)d_in[5];
    fp p_w  = (fp)d_in[6];  fp p_b  = (fp)d_in[7];
    fp m_w  = (fp)d_in[8];  fp m_b  = (fp)d_in[9];
    fp dcn_w= (fp)d_in[10];
    fp bn1g = (fp)d_in[11]; fp bn1b = (fp)d_in[12];
    fp dw2w = (fp)d_in[13]; fp dw2b = (fp)d_in[14];
    fp bn2g = (fp)d_in[15]; fp bn2b = (fp)d_in[16];

    float* ws  = (float*)d_ws;
    unsigned short* Bo  = (unsigned short*)ws;               // (8,256,4096) bf16 ; D overlays after k_pw
    unsigned short* Cbf = (unsigned short*)(ws + 8388608);   // (8,4096,128) bf16 ; Hs overlays after k_deform
    unsigned short* Hs  = (unsigned short*)(ws + 8388608);   // (8,128,4096) bf16
    float* OM  = ws + 12582912;         // (8,27,4096)
    unsigned short* Wbf = (unsigned short*)(ws + 13467648);
    unsigned short* Wpm = (unsigned short*)(ws + 13541376);
    float* stats = ws + 13559808;       // 512 f
    unsigned short* Wpwbf = (unsigned short*)(ws + 13560320);  // 32,768 bf16
    unsigned short* D   = Bo;           // Bo dead after k_pw
    float* out = (float*)d_out;

    hipMemsetAsync(stats, 0, 512*sizeof(float), stream);
    k_prep         <<<848,   256, 0, stream>>>(dcn_w, p_w, m_w, pw_w, Wbf, Wpm, Wpwbf);
    k_updw256      <<<2048,  256, 0, stream>>>(x1, x2, dw_w, dw_b, Bo);
    k_pw           <<<512,   512, 0, stream>>>(Bo, Wpwbf, pw_b, Cbf);
    k_offmask      <<<512,   256, 0, stream>>>(Cbf, Wpm, p_b, m_b, OM);
    k_deform       <<<512,   512, 0, stream>>>(Cbf, OM, Wbf, D, stats);
    k_bngelu_dw128 <<<1024,  256, 0, stream>>>(D, stats, bn1g, bn1b, dw2w, dw2b, Hs);
    k_bn_relu_out  <<<4096,  256, 0, stream>>>(Hs, stats, bn2g, bn2b, out);
}

// Round 16
// 196.146 us; speedup vs baseline: 1.3808x; 1.0120x over previous
//
#include <hip/hip_runtime.h>
#include <math.h>

// Problem constants: B=8, spatial 64x64 (HW=4096), C_mid=256, C=128, N=9 taps.
typedef const float* fp;
typedef __attribute__((ext_vector_type(8))) short short8;   // 8 bf16 = 4 VGPRs (MFMA A/B frag)
typedef __attribute__((ext_vector_type(4))) float f32x4;    // MFMA C/D frag

__device__ __forceinline__ unsigned short f2bf(float f){    // RTNE float->bf16 (scalar/cold paths)
    unsigned u = __float_as_uint(f);
    u += 0x7fff + ((u >> 16) & 1);
    return (unsigned short)(u >> 16);
}
__device__ __forceinline__ float bflo(unsigned u){ return __uint_as_float(u << 16); }
__device__ __forceinline__ float bfhi(unsigned u){ return __uint_as_float(u & 0xffff0000u); }
// HW packed convert: 1 instr for 2 values (gfx950 v_cvt_pk_bf16_f32; no builtin — inline asm)
__device__ __forceinline__ unsigned cvtpk(float a, float b){
    unsigned r; asm("v_cvt_pk_bf16_f32 %0, %1, %2" : "=v"(r) : "v"(a), "v"(b)); return r;
}
__device__ __forceinline__ void st4bf(void* p, float a, float b, float c, float d){
    uint2 v; v.x = cvtpk(a,b); v.y = cvtpk(c,d);
    *(uint2*)p = v;
}

// ---------------- K0 v3: coalesced prep — one thread per (o,c)/(q,c): 9 contiguous
// reads (was stride-9, 9x over-fetch), 9 lane-dense u16 stores. 53,248 thr = 208 blocks.
__global__ __launch_bounds__(256) void k_prep(fp dcn_w, fp pw, fp mw, fp pww,
                                              unsigned short* Wbf, unsigned short* Wpm,
                                              unsigned short* Wpwbf){
    int i = blockIdx.x*256 + threadIdx.x;
    if(i < 16384){                              // dcn: (o,c) -> 9 taps
        int o = i >> 7, c = i & 127;
        const float* s = dcn_w + o*1152 + c*9;
        #pragma unroll
        for(int n=0;n<9;n++) Wbf[(n<<14) + (o<<7) + c] = f2bf(s[n]);
    } else if(i < 20480){                       // pw/mw: (q,c) -> 9 taps, q<32
        int j = i - 16384;
        int q = j >> 7, c = j & 127;
        if(q < 18){
            const float* s = pw + q*1152 + c*9;
            #pragma unroll
            for(int n=0;n<9;n++) Wpm[(n<<12) + (q<<7) + c] = f2bf(s[n]);
        } else if(q < 27){
            const float* s = mw + (q-18)*1152 + c*9;
            #pragma unroll
            for(int n=0;n<9;n++) Wpm[(n<<12) + (q<<7) + c] = f2bf(s[n]);
        } else {
            #pragma unroll
            for(int n=0;n<9;n++) Wpm[(n<<12) + (q<<7) + c] = 0;
        }
    } else if(i < 53248){
        int j = i - 20480;                      // 32768: pointwise weights [o][c] bf16
        Wpwbf[j] = f2bf(pww[j]);
    }
}

// ---------------- K1 v3: fused upsample+concat+depthwise256 -> Bo (8,256,4096) BF16
__global__ __launch_bounds__(256) void k_updw256(fp x1, fp x2, fp w, fp bias, unsigned short* Bo){
    __shared__ float sA[66*68 + 4];
    int bid = blockIdx.x;
    int c = bid & 255, b = bid >> 8;
    int tid = threadIdx.x;
    for(int j = tid; j < 264; j += 256){
        int idx;
        if(j < 66)       idx = j;
        else if(j < 132) idx = 65*68 + (j-66);
        else if(j < 196) idx = (j-132+1)*68;
        else if(j < 260) idx = (j-196+1)*68 + 65;
        else             idx = 66*68 + (j-260);
        sA[idx] = 0.f;
    }
    if(c < 128){
        const float* src = x2 + ((size_t)(b*128+c)<<12);
        for(int j = tid; j < 1024; j += 256){
            int yy = j >> 4, x4 = (j & 15) << 2;
            float4 v = *(const float4*)&src[(yy<<6) + x4];
            float* d = &sA[(yy+1)*68 + x4 + 1];
            d[0]=v.x; d[1]=v.y; d[2]=v.z; d[3]=v.w;
        }
    } else {
        int cc = c - 128;
        fp src = x1 + ((b*128+cc)<<10);
        const float s = 31.0f/63.0f;
        for(int j = tid; j < 4096; j += 256){
            int yy = j >> 6, xx = j & 63;
            float fy = yy*s, fx = xx*s;
            int iy = (int)fy; if (iy > 30) iy = 30;
            int ix = (int)fx; if (ix > 30) ix = 30;
            float ty = fy - (float)iy, tx = fx - (float)ix;
            float v00 = src[iy*32+ix],     v01 = src[iy*32+ix+1];
            float v10 = src[(iy+1)*32+ix], v11 = src[(iy+1)*32+ix+1];
            sA[(yy+1)*68 + xx + 1] =
                (v00*(1.f-ty)+v10*ty)*(1.f-tx) + (v01*(1.f-ty)+v11*ty)*tx;
        }
    }
    __syncthreads();
    float w0=w[c*9+0], w1=w[c*9+1], w2=w[c*9+2];
    float w3=w[c*9+3], w4=w[c*9+4], w5=w[c*9+5];
    float w6=w[c*9+6], w7=w[c*9+7], w8=w[c*9+8];
    float bv = bias[c];
    unsigned short* dst = Bo + ((size_t)(b*256+c)<<12);
    for(int j = tid; j < 1024; j += 256){
        int y = j >> 4, x0 = (j & 15) << 2;
        float a0=bv, a1=bv, a2=bv, a3=bv;
        #pragma unroll
        for(int ky=0; ky<3; ky++){
            const float* rr = &sA[(y+ky)*68 + x0];
            float4 u0 = *(const float4*)&rr[0];
            float2 u1 = *(const float2*)&rr[4];
            float wA = (ky==0)?w0:((ky==1)?w3:w6);
            float wB = (ky==0)?w1:((ky==1)?w4:w7);
            float wC = (ky==0)?w2:((ky==1)?w5:w8);
            a0 += wA*u0.x + wB*u0.y + wC*u0.z;
            a1 += wA*u0.y + wB*u0.z + wC*u0.w;
            a2 += wA*u0.z + wB*u0.w + wC*u1.x;
            a3 += wA*u0.w + wB*u1.x + wC*u1.y;
        }
        st4bf(&dst[(y<<6)+x0], a0,a1,a2,a3);
    }
}

// ---------------- K3 v6: pointwise 256->128 + bias via bf16 MFMA; Bo bf16 in, Cbf bf16 out.
#define PW_STAGE_X(kc, bufp) do{ \
    _Pragma("unroll") \
    for(int k_=0;k_<4;k_++){ \
        int j_ = tid + (k_<<9); \
        int cc_ = j_ >> 4, p4_ = (j_ & 15) << 2; \
        int c_ = ((kc)<<7) + cc_; \
        uint2 v_ = *(const uint2*)&Bo[((size_t)((b<<8)+c_)<<12) + pix0 + p4_]; \
        (bufp)[(p4_+0)*136 + cc_] = (unsigned short)(v_.x & 0xffffu); \
        (bufp)[(p4_+1)*136 + cc_] = (unsigned short)(v_.x >> 16); \
        (bufp)[(p4_+2)*136 + cc_] = (unsigned short)(v_.y & 0xffffu); \
        (bufp)[(p4_+3)*136 + cc_] = (unsigned short)(v_.y >> 16); \
    } }while(0)

#define PW_STAGE_W(kc) do{ \
    _Pragma("unroll") \
    for(int k_=0;k_<4;k_++){ \
        int j_ = tid + (k_<<9); \
        int o_ = j_ >> 4, cg_ = j_ & 15; \
        *(int4*)&sW[o_*136 + (cg_<<3)] = \
            *(const int4*)&Wpwbf[o_*256 + ((kc)<<7) + (cg_<<3)]; \
    } }while(0)

#define PW_DOMFMA(srcp) do{ \
    _Pragma("unroll") \
    for(int ks_=0; ks_<4; ks_++){ \
        int k0_ = ks_ << 5; \
        short8 bfr0 = *(const short8*)&(srcp)[(phb + m16)*136 + k0_ + (quad<<3)]; \
        short8 bfr1 = *(const short8*)&(srcp)[(phb + 16 + m16)*136 + k0_ + (quad<<3)]; \
        _Pragma("unroll") \
        for(int ot_=0;ot_<2;ot_++){ \
            short8 afr = *(const short8*)&sW[(wo + (ot_<<4) + m16)*136 + k0_ + (quad<<3)]; \
            acc[ot_][0] = __builtin_amdgcn_mfma_f32_16x16x32_bf16(afr, bfr0, acc[ot_][0], 0,0,0); \
            acc[ot_][1] = __builtin_amdgcn_mfma_f32_16x16x32_bf16(afr, bfr1, acc[ot_][1], 0,0,0); \
        } } }while(0)

__global__ __launch_bounds__(512, 2) void k_pw(const unsigned short* Bo, const unsigned short* Wpwbf,
                                               fp bias, unsigned short* Cbf){
    __shared__ __align__(16) unsigned short sW[128*136];     // 34,816 B [o][cc]
    __shared__ __align__(16) unsigned short sX[2][64*136];   // 34,816 B dbuf [px][cc]
    int b = blockIdx.x & 7;
    int pix0 = (blockIdx.x >> 3) << 6;   // 64 tiles x 8 b
    int tid = threadIdx.x;               // 0..511
    int lane = tid & 63, wave = tid >> 6;
    int m16 = lane & 15, quad = lane >> 4;
    int wo  = (wave & 3) << 5;           // o-range: 4 groups of 32
    int phb = (wave >> 2) << 5;          // px-half: 0 / 32

    // ---- probe
    short8 ap = {0,0,0,0,0,0,0,0}, bpr = {0,0,0,0,0,0,0,0};
    if(quad == 0){
        ap[0]  = (short)f2bf((float)m16);
        bpr[0] = (short)f2bf((float)(m16+100));
    }
    f32x4 dp = {0.f,0.f,0.f,0.f};
    dp = __builtin_amdgcn_mfma_f32_16x16x32_bf16(ap, bpr, dp, 0,0,0);
    bool p1 = true;
    #pragma unroll
    for(int r=0;r<4;r++){
        float expP1 = (float)(quad*4+r) * (float)(m16+100);
        p1 = p1 && (fabsf(dp[r]-expP1) < 0.5f);
    }
    bool swapD = (__ballot(p1) != 0xFFFFFFFFFFFFFFFFull);

    f32x4 acc[2][2];                     // [ot][pt]
    #pragma unroll
    for(int i=0;i<2;i++){
        #pragma unroll
        for(int j=0;j<2;j++) acc[i][j] = (f32x4){0.f,0.f,0.f,0.f};
    }

    // ---- pipeline: 2 K-chunks
    PW_STAGE_X(0, (&sX[0][0]));
    PW_STAGE_W(0);
    __syncthreads();                      // sX[0], sW(0) ready
    PW_STAGE_X(1, (&sX[1][0]));           // overlaps MFMA(0)
    PW_DOMFMA((&sX[0][0]));
    __syncthreads();                      // MFMA(0) done (sW free), sX[1] writes done
    PW_STAGE_W(1);
    __syncthreads();                      // sW(1) ready
    PW_DOMFMA((&sX[1][0]));

    // ---- epilogue: bias + channel-last bf16 write
    if(!swapD){
        #pragma unroll
        for(int ot=0;ot<2;ot++){
            int o0 = wo + (ot<<4) + (quad<<2);
            float4 bv = *(const float4*)&bias[o0];
            #pragma unroll
            for(int pt=0;pt<2;pt++){
                int px = pix0 + phb + (pt<<4) + m16;
                st4bf(&Cbf[((size_t)((b<<12) + px))*128 + o0],
                      acc[ot][pt][0]+bv.x, acc[ot][pt][1]+bv.y,
                      acc[ot][pt][2]+bv.z, acc[ot][pt][3]+bv.w);
            }
        }
    } else {
        #pragma unroll
        for(int ot=0;ot<2;ot++){
            int o = wo + (ot<<4) + m16;
            float bv = bias[o];
            #pragma unroll
            for(int pt=0;pt<2;pt++){
                #pragma unroll
                for(int r=0;r<4;r++){
                    int px = pix0 + phb + (pt<<4) + (quad<<2) + r;
                    Cbf[((size_t)((b<<12) + px))*128 + o] = f2bf(acc[ot][pt][r] + bv);
                }
            }
        }
    }
}

// ---------------- K4 v4 (verified): offset+mask conv, one-shot window staging from bf16 Cbf.
__global__ __launch_bounds__(256, 2) void k_offmask(const unsigned short* Cbf, const unsigned short* Wpm,
                                                    fp pb, fp mb, float* OM){
    __shared__ __align__(16) unsigned short sWin[3*66*136];  // 53,856 B [r][col][c]
    __shared__ __align__(16) unsigned short sW[2][32*136];   // 17,408 B dbuf [q][c]
    int b = blockIdx.x & 7;
    int y = blockIdx.x >> 3;          // output row
    int pix0 = y << 6;
    int tid = threadIdx.x;
    int lane = tid & 63, wave = tid >> 6;
    int m16 = lane & 15, quad = lane >> 4;
    int wp = wave << 4;               // px-subtile
    const unsigned short* cbf = Cbf + ((size_t)b<<12)*128;

    // ---- probe: D[m][n]=m*(n+100)
    short8 ap = {0,0,0,0,0,0,0,0}, bpr = {0,0,0,0,0,0,0,0};
    if(quad == 0){
        ap[0]  = (short)f2bf((float)m16);
        bpr[0] = (short)f2bf((float)(m16+100));
    }
    f32x4 dp = {0.f,0.f,0.f,0.f};
    dp = __builtin_amdgcn_mfma_f32_16x16x32_bf16(ap, bpr, dp, 0,0,0);
    bool p1 = true;
    #pragma unroll
    for(int r=0;r<4;r++){
        float expP1 = (float)(quad*4+r) * (float)(m16+100);
        p1 = p1 && (fabsf(dp[r]-expP1) < 0.5f);
    }
    bool swapD = (__ballot(p1) != 0xFFFFFFFFFFFFFFFFull);

    f32x4 acc[2];
    acc[0] = (f32x4){0.f,0.f,0.f,0.f};
    acc[1] = (f32x4){0.f,0.f,0.f,0.f};

    // ---- prologue: issue W(0) loads, stage window (16B copies), write sW[0]
    {
        const int4* wsrc = (const int4*)Wpm;
        int4 wA_ = wsrc[tid], wB_ = wsrc[tid + 256];
        for(int i = tid; i < 3168; i += 256){        // 198 pos x 16 groups of 8 ch
            int pos = i >> 4, g = i & 15;
            int r = pos / 66, col = pos - r*66;
            int yy = y + r - 1, xx = col - 1;
            int4 v = make_int4(0,0,0,0);
            if(yy>=0 && yy<64 && xx>=0 && xx<64)
                v = *(const int4*)&cbf[(size_t)((yy<<6)+xx)*128 + (g<<3)];
            *(int4*)&sWin[pos*136 + (g<<3)] = v;
        }
        *(int4*)&sW[0][(tid>>4)*136 + ((tid&15)<<3)] = wA_;
        int j = tid + 256;
        *(int4*)&sW[0][(j>>4)*136 + ((j&15)<<3)] = wB_;
    }
    __syncthreads();

    for(int n=0;n<9;n++){
        int4 wA_, wB_;
        if(n<8){
            const int4* wsrc = (const int4*)(Wpm + ((n+1)<<12));
            wA_ = wsrc[tid]; wB_ = wsrc[tid + 256];   // issue early; MFMA covers latency
        }
        int ky = n/3, kx = n - ky*3;
        const unsigned short* base = &sWin[(ky*66 + wp + kx)*136];
        #pragma unroll
        for(int ks=0; ks<4; ks++){
            int k0 = ks << 5;
            short8 bfr = *(const short8*)&base[m16*136 + k0 + (quad<<3)];
            #pragma unroll
            for(int qt=0;qt<2;qt++){
                short8 afr = *(const short8*)&sW[n&1][((qt<<4) + m16)*136 + k0 + (quad<<3)];
                acc[qt] = __builtin_amdgcn_mfma_f32_16x16x32_bf16(afr, bfr, acc[qt], 0,0,0);
            }
        }
        if(n<8){
            *(int4*)&sW[(n+1)&1][(tid>>4)*136 + ((tid&15)<<3)] = wA_;
            int j = tid + 256;
            *(int4*)&sW[(n+1)&1][(j>>4)*136 + ((j&15)<<3)] = wB_;
        }
        __syncthreads();
    }
    if(!swapD){
        #pragma unroll
        for(int qt=0;qt<2;qt++){
            int px = pix0 + wp + m16;
            #pragma unroll
            for(int r=0;r<4;r++){
                int q = (qt<<4) + (quad<<2) + r;
                if(q < 27){
                    float v = acc[qt][r] + ((q<18) ? pb[q] : mb[q-18]);
                    if(q>=18) v = 1.f/(1.f+expf(-v));
                    OM[((b*27+q)<<12) + px] = v;
                }
            }
        }
    } else {
        #pragma unroll
        for(int qt=0;qt<2;qt++){
            int q = (qt<<4) + m16;
            if(q < 27){
                float bias = (q<18) ? pb[q] : mb[q-18];
                #pragma unroll
                for(int r=0;r<4;r++){
                    int px = pix0 + wp + (quad<<2) + r;
                    float v = acc[qt][r] + bias;
                    if(q>=18) v = 1.f/(1.f+expf(-v));
                    OM[((b*27+q)<<12) + px] = v;
                }
            }
        }
    }
}

// ---------------- K5 v13: deformable sampling from bf16 Cbf + MFMA; D bf16.
// Pack via v_cvt_pk_bf16_f32 (1 instr / 2 values) — gather VALU cut ~25%.
#define K5_META(t) do{ if(tid < 256){ \
    int px_ = tid >> 2, k_ = tid & 3; \
    int pix_ = pix0 + px_; \
    int yq_ = pix_ >> 6, xq_ = pix_ & 63; \
    int kyy_ = (t)/3, kxx_ = (t)-kyy_*3; \
    float oxv_ = omb[((t)<<12)+pix_]; \
    float oyv_ = omb[(((t)+9)<<12)+pix_]; \
    float mv_  = omb[(((t)+18)<<12)+pix_]; \
    float pxf_ = (float)(yq_ + kyy_) + oxv_; \
    float pyf_ = (float)(xq_ + kxx_) + oyv_; \
    float fx_ = floorf(pxf_), fy_ = floorf(pyf_); \
    float qx0_ = fminf(fmaxf(fx_,0.f),65.f),  qx1_ = fminf(fmaxf(fx_+1.f,0.f),65.f); \
    float qy0_ = fminf(fmaxf(fy_,0.f),65.f),  qy1_ = fminf(fmaxf(fy_+1.f,0.f),65.f); \
    float pxc_ = fminf(fmaxf(pxf_,0.f),65.f), pyc_ = fminf(fmaxf(pyf_,0.f),65.f); \
    float dx0_ = 1.f+(qx0_-pxc_), dx1_ = 1.f-(qx1_-pxc_); \
    float dy0_ = 1.f+(qy0_-pyc_), dy1_ = 1.f-(qy1_-pyc_); \
    int ax0_=(int)qx0_, ax1_=(int)qx1_, ay0_=(int)qy0_, ay1_=(int)qy1_; \
    bool vx0_ = (ax0_>=1)&&(ax0_<=64), vx1_ = (ax1_>=1)&&(ax1_<=64); \
    bool vy0_ = (ay0_>=1)&&(ay0_<=64), vy1_ = (ay1_>=1)&&(ay1_<=64); \
    int  axs_ = (k_&1) ? ax1_ : ax0_; \
    int  ays_ = (k_==1||k_==2) ? ay1_ : ay0_; \
    bool vxs_ = (k_&1) ? vx1_ : vx0_; \
    bool vys_ = (k_==1||k_==2) ? vy1_ : vy0_; \
    float dxs_ = (k_&1) ? dx1_ : dx0_; \
    float dys_ = (k_==1||k_==2) ? dy1_ : dy0_; \
    bool v_ = vxs_ && vys_; \
    int base_ = v_ ? (((axs_-1)<<6)+(ays_-1)) : 0; \
    float g_ = v_ ? dxs_*dys_*mv_ : 0.f; \
    sM[tid] = make_uint2((unsigned)base_, __float_as_uint(g_)); \
} }while(0)

#define K5_GATHER(bufp) do{ \
    _Pragma("unroll") \
    for(int j_=0;j_<4;j_++){ \
        int px_ = pxb + (j_<<4); \
        uint2 e0_ = sM[(px_<<2)+0]; \
        uint2 e1_ = sM[(px_<<2)+1]; \
        uint2 e2_ = sM[(px_<<2)+2]; \
        uint2 e3_ = sM[(px_<<2)+3]; \
        float g0_ = __uint_as_float(e0_.y), g1_ = __uint_as_float(e1_.y); \
        float g2_ = __uint_as_float(e2_.y), g3_ = __uint_as_float(e3_.y); \
        uint2 c0_ = *(const uint2*)&cb[((size_t)e0_.x<<7) + cg4]; \
        uint2 c1_ = *(const uint2*)&cb[((size_t)e1_.x<<7) + cg4]; \
        uint2 c2_ = *(const uint2*)&cb[((size_t)e2_.x<<7) + cg4]; \
        uint2 c3_ = *(const uint2*)&cb[((size_t)e3_.x<<7) + cg4]; \
        float vx_ = g0_*bflo(c0_.x) + g1_*bflo(c1_.x) + g2_*bflo(c2_.x) + g3_*bflo(c3_.x); \
        float vy_ = g0_*bfhi(c0_.x) + g1_*bfhi(c1_.x) + g2_*bfhi(c2_.x) + g3_*bfhi(c3_.x); \
        float vz_ = g0_*bflo(c0_.y) + g1_*bflo(c1_.y) + g2_*bflo(c2_.y) + g3_*bflo(c3_.y); \
        float vw_ = g0_*bfhi(c0_.y) + g1_*bfhi(c1_.y) + g2_*bfhi(c2_.y) + g3_*bfhi(c3_.y); \
        st4bf(&(bufp)[px_*136 + cg4], vx_, vy_, vz_, vw_); \
    } }while(0)

#define K5_STAGE_W(t) do{ \
    const int4* wsrc_ = (const int4*)(Wbf + ((t)<<14)); \
    _Pragma("unroll") \
    for(int k_=0;k_<4;k_++){ int j_ = tid + (k_<<9); \
        *(int4*)&sW[(j_>>4)*136 + ((j_&15)<<3)] = wsrc_[j_]; } }while(0)

#define K5_DOMFMA(srcp) do{ \
    _Pragma("unroll") \
    for(int ks_=0; ks_<4; ks_++){ \
        int k0_ = ks_ << 5; \
        short8 bfr0 = *(const short8*)&(srcp)[(phb + m16)*136 + k0_ + (quad<<3)]; \
        short8 bfr1 = *(const short8*)&(srcp)[(phb + 16 + m16)*136 + k0_ + (quad<<3)]; \
        _Pragma("unroll") \
        for(int ot_=0;ot_<2;ot_++){ \
            short8 afr = *(const short8*)&sW[(wo + (ot_<<4) + m16)*136 + k0_ + (quad<<3)]; \
            acc[ot_][0] = __builtin_amdgcn_mfma_f32_16x16x32_bf16(afr, bfr0, acc[ot_][0], 0,0,0); \
            acc[ot_][1] = __builtin_amdgcn_mfma_f32_16x16x32_bf16(afr, bfr1, acc[ot_][1], 0,0,0); \
        } } }while(0)

__global__ __launch_bounds__(512, 2) void k_deform(const unsigned short* Cbf, fp OM,
                                                   const unsigned short* Wbf,
                                                   unsigned short* D, float* stats){
    __shared__ __align__(16) unsigned short sW[128*136];     // 34,816 B [o][c]
    __shared__ __align__(16) unsigned short sX[2][64*136];   // 34,816 B dbuf [px][c]
    __shared__ __align__(8)  uint2 sM[256];                  //  2,048 B meta (base,weight)
    int b = blockIdx.x & 7;
    int pix0 = (blockIdx.x >> 3) << 6;   // 64 tiles (one row each) x 8 b
    int tid = threadIdx.x;               // 0..511
    int lane = tid & 63, wave = tid >> 6;
    int m16 = lane & 15, quad = lane >> 4;
    int wo  = (wave & 3) << 5;           // o-range: 4 groups of 32
    int phb = (wave >> 2) << 5;          // px-half: 0 / 32
    int cg4 = (tid & 31) << 2;           // channel group (4 ch)
    int pxb = tid >> 5;                  // base px 0..15 (handles px pxb, +16, +32, +48)
    const float* omb = OM + b*27*4096;
    const unsigned short* cb = Cbf + ((size_t)b<<12)*128;

    // ---- probe
    short8 ap = {0,0,0,0,0,0,0,0}, bpr = {0,0,0,0,0,0,0,0};
    if(quad == 0){
        ap[0]  = (short)f2bf((float)m16);
        bpr[0] = (short)f2bf((float)(m16+100));
    }
    f32x4 dp = {0.f,0.f,0.f,0.f};
    dp = __builtin_amdgcn_mfma_f32_16x16x32_bf16(ap, bpr, dp, 0,0,0);
    bool p1 = true;
    #pragma unroll
    for(int r=0;r<4;r++){
        float expP1 = (float)(quad*4+r) * (float)(m16+100);
        p1 = p1 && (fabsf(dp[r]-expP1) < 0.5f);
    }
    bool swapD = (__ballot(p1) != 0xFFFFFFFFFFFFFFFFull);

    f32x4 acc[2][2];                     // [ot][pt]
    #pragma unroll
    for(int i=0;i<2;i++){
        #pragma unroll
        for(int j=0;j<2;j++) acc[i][j] = (f32x4){0.f,0.f,0.f,0.f};
    }

    // ---- prologue
    K5_META(0);
    __syncthreads();                      // sM = meta(0)
    K5_GATHER((&sX[0][0]));               // gather(0) using meta(0)
    K5_STAGE_W(0);
    __syncthreads();                      // sX[0], sW(0) ready; sM reads done
    K5_META(1);
    __syncthreads();                      // sM = meta(1)

    for(int n=0;n<9;n++){
        if(n<8) K5_GATHER((&sX[(n+1)&1][0]));  // uses sM = meta(n+1); overlaps MFMA(n)
        K5_DOMFMA((&sX[n&1][0]));              // operands from LDS (sW, sX)
        __syncthreads();                       // sW/sM reads + sX writes done
        if(n<8){
            K5_STAGE_W(n+1);                   // sW <- W(n+1), transient regs
            if(n<7) K5_META(n+2);              // sM <- meta(n+2)
            __syncthreads();                   // sW, sM ready for next iter
        }
    }

    // epilogue: bf16 D writes + per-channel sum/sumsq reduction (stats from f32 acc)
    float* sdq = (float*)&sX[0][0];       // [0..127]=sum, [128..255]=sumsq
    if(tid < 256) sdq[tid] = 0.f;
    __syncthreads();
    if(!swapD){
        #pragma unroll
        for(int ot=0;ot<2;ot++){
            #pragma unroll
            for(int pt=0;pt<2;pt++){
                int px = pix0 + phb + (pt<<4) + m16;
                #pragma unroll
                for(int r=0;r<4;r++){
                    int o = wo + (ot<<4) + (quad<<2) + r;
                    D[((size_t)(b*128+o)<<12) + px] = f2bf(acc[ot][pt][r]);
                }
            }
        }
        #pragma unroll
        for(int ot=0;ot<2;ot++){
            #pragma unroll
            for(int r=0;r<4;r++){
                float s  = acc[ot][0][r] + acc[ot][1][r];
                float s2 = acc[ot][0][r]*acc[ot][0][r] + acc[ot][1][r]*acc[ot][1][r];
                #pragma unroll
                for(int msk=1; msk<16; msk<<=1){
                    s  += __shfl_xor(s, msk, 64);
                    s2 += __shfl_xor(s2, msk, 64);
                }
                if(m16 == 0){
                    int o = wo + (ot<<4) + (quad<<2) + r;
                    atomicAdd(&sdq[o], s);
                    atomicAdd(&sdq[128+o], s2);
                }
            }
        }
    } else {
        #pragma unroll
        for(int ot=0;ot<2;ot++){
            #pragma unroll
            for(int pt=0;pt<2;pt++){
                int o = wo + (ot<<4) + m16;
                #pragma unroll
                for(int r=0;r<4;r++){
                    int px = pix0 + phb + (pt<<4) + (quad<<2) + r;
                    D[((size_t)(b*128+o)<<12) + px] = f2bf(acc[ot][pt][r]);
                }
            }
        }
        #pragma unroll
        for(int ot=0;ot<2;ot++){
            float s = 0.f, s2 = 0.f;
            #pragma unroll
            for(int pt=0;pt<2;pt++){
                #pragma unroll
                for(int r=0;r<4;r++){
                    float v = acc[ot][pt][r];
                    s += v; s2 += v*v;
                }
            }
            #pragma unroll
            for(int msk=16; msk<64; msk<<=1){
                s  += __shfl_xor(s, msk, 64);
                s2 += __shfl_xor(s2, msk, 64);
            }
            if(quad == 0){
                int o = wo + (ot<<4) + m16;
                atomicAdd(&sdq[o], s);
                atomicAdd(&sdq[128+o], s2);
            }
        }
    }
    __syncthreads();
    if(tid < 128){
        atomicAdd(&stats[tid],     sdq[tid]);
        atomicAdd(&stats[128+tid], sdq[128+tid]);
    }
}

// ---------------- K7 v3: fused BN1+GELU + depthwise128 (bf16 D in, bf16 Hs out)
__global__ __launch_bounds__(256) void k_bngelu_dw128(const unsigned short* Dsrc, float* stats,
                                                      fp g1, fp b1, fp w, fp bias, unsigned short* Hs){
    __shared__ float sG[66*68 + 4];
    __shared__ float sd[256], sq[256];
    int bid = blockIdx.x;
    int c = bid & 127, b = bid >> 7;
    int tid = threadIdx.x;
    float mean1 = stats[c] * (1.f/32768.f);
    float var1  = stats[128+c] * (1.f/32768.f) - mean1*mean1;
    float rstd1 = rsqrtf(var1 + 1e-5f);
    float sc = rstd1 * g1[c];
    float sb = b1[c] - mean1*sc;
    for(int j = tid; j < 264; j += 256){
        int idx;
        if(j < 66)       idx = j;
        else if(j < 132) idx = 65*68 + (j-66);
        else if(j < 196) idx = (j-132+1)*68;
        else if(j < 260) idx = (j-196+1)*68 + 65;
        else             idx = 66*68 + (j-260);
        sG[idx] = 0.f;
    }
    const unsigned short* dplane = Dsrc + ((size_t)(b*128+c)<<12);
    for(int j = tid; j < 1024; j += 256){           // 64 rows x 16 groups of 4 px
        int yy = j >> 4, x4 = (j & 15) << 2;
        uint2 v = *(const uint2*)&dplane[(yy<<6) + x4];
        float g0 = bflo(v.x)*sc+sb, g1v = bfhi(v.x)*sc+sb;
        float g2 = bflo(v.y)*sc+sb, g3 = bfhi(v.y)*sc+sb;
        float* d = &sG[(yy+1)*68 + x4 + 1];
        d[0] = 0.5f*g0*(1.0f + erff(g0*0.70710678118654752f));
        d[1] = 0.5f*g1v*(1.0f + erff(g1v*0.70710678118654752f));
        d[2] = 0.5f*g2*(1.0f + erff(g2*0.70710678118654752f));
        d[3] = 0.5f*g3*(1.0f + erff(g3*0.70710678118654752f));
    }
    __syncthreads();
    float w0=w[c*9+0], w1=w[c*9+1], w2=w[c*9+2];
    float w3=w[c*9+3], w4=w[c*9+4], w5=w[c*9+5];
    float w6=w[c*9+6], w7=w[c*9+7], w8=w[c*9+8];
    float bv = bias[c];
    unsigned short* dst = Hs + ((size_t)(b*128+c)<<12);
    float s = 0.f, s2 = 0.f;
    for(int j = tid; j < 1024; j += 256){           // 64 rows x 16 groups of 4 px
        int y = j >> 4, x0 = (j & 15) << 2;
        float a0=bv, a1=bv, a2=bv, a3=bv;
        #pragma unroll
        for(int ky=0; ky<3; ky++){
            const float* rr = &sG[(y+ky)*68 + x0];
            float4 u0 = *(const float4*)&rr[0];
            float2 u1 = *(const float2*)&rr[4];
            float wA = (ky==0)?w0:((ky==1)?w3:w6);
            float wB = (ky==0)?w1:((ky==1)?w4:w7);
            float wC = (ky==0)?w2:((ky==1)?w5:w8);
            a0 += wA*u0.x + wB*u0.y + wC*u0.z;
            a1 += wA*u0.y + wB*u0.z + wC*u0.w;
            a2 += wA*u0.z + wB*u0.w + wC*u1.x;
            a3 += wA*u0.w + wB*u1.x + wC*u1.y;
        }
        st4bf(&dst[(y<<6)+x0], a0,a1,a2,a3);
        s += a0+a1+a2+a3;
        s2 += a0*a0 + a1*a1 + a2*a2 + a3*a3;
    }
    sd[tid]=s; sq[tid]=s2; __syncthreads();
    for(int off=128; off>0; off>>=1){
        if(tid<off){ sd[tid]+=sd[tid+off]; sq[tid]+=sq[tid+off]; }
        __syncthreads();
    }
    if(tid==0){
        atomicAdd(&stats[256+c], sd[0]);
        atomicAdd(&stats[384+c], sq[0]);
    }
}

// ---------------- BN2 + ReLU -> f32 out (bf16 Hs in)
__global__ __launch_bounds__(256) void k_bn_relu_out(const unsigned short* Hs, const float* stats,
                                                     fp g, fp bb, float* out){
    int idx = blockIdx.x*256+threadIdx.x;       // 1,048,576 groups of 4 px
    int c = (idx>>10)&127;
    float mean2 = stats[256+c] * (1.f/32768.f);
    float var2  = stats[384+c] * (1.f/32768.f) - mean2*mean2;
    float rs = rsqrtf(var2 + 1e-5f) * g[c];
    float sb = bb[c] - mean2*rs;
    uint2 v = ((const uint2*)Hs)[idx];
    float4 o;
    o.x = fmaxf(bflo(v.x)*rs+sb, 0.f);
    o.y = fmaxf(bfhi(v.x)*rs+sb, 0.f);
    o.z = fmaxf(bflo(v.y)*rs+sb, 0.f);
    o.w = fmaxf(bfhi(v.y)*rs+sb, 0.f);
    ((float4*)out)[idx] = o;
}

extern "C" void kernel_launch(void* const* d_in, const int* in_sizes, int n_in,
                              void* d_out, int out_size, void* d_ws, size_t ws_size,
                              hipStream_t stream){
    fp x1   = (fp)d_in[0];
    fp x2   = (fp)d_in[1];
    fp dw_w = (fp)d_in[2];  fp dw_b = (fp)d_in[3];
    fp pw_w = (fp)d_in[4];  fp pw_b = (fp)d_in[5];
    fp p_w  = (fp)d_in[6];  fp p_b  = (fp)d_in[7];
    fp m_w  = (fp)d_in[8];  fp m_b  = (fp)d_in[9];
    fp dcn_w= (fp)d_in[10];
    fp bn1g = (fp)d_in[11]; fp bn1b = (fp)d_in[12];
    fp dw2w = (fp)d_in[13]; fp dw2b = (fp)d_in[14];
    fp bn2g = (fp)d_in[15]; fp bn2b = (fp)d_in[16];

    float* ws  = (float*)d_ws;
    unsigned short* Bo  = (unsigned short*)ws;               // (8,256,4096) bf16 ; D overlays after k_pw
    unsigned short* Cbf = (unsigned short*)(ws + 8388608);   // (8,4096,128) bf16 ; Hs overlays after k_deform
    unsigned short* Hs  = (unsigned short*)(ws + 8388608);   // (8,128,4096) bf16
    float* OM  = ws + 12582912;         // (8,27,4096)
    unsigned short* Wbf = (unsigned short*)(ws + 13467648);
    unsigned short* Wpm = (unsigned short*)(ws + 13541376);
    float* stats = ws + 13559808;       // 512 f
    unsigned short* Wpwbf = (unsigned short*)(ws + 13560320);  // 32,768 bf16
    unsigned short* D   = Bo;           // Bo dead after k_pw
    float* out = (float*)d_out;

    hipMemsetAsync(stats, 0, 512*sizeof(float), stream);
    k_prep         <<<208,   256, 0, stream>>>(dcn_w, p_w, m_w, pw_w, Wbf, Wpm, Wpwbf);
    k_updw256      <<<2048,  256, 0, stream>>>(x1, x2, dw_w, dw_b, Bo);
    k_pw           <<<512,   512, 0, stream>>>(Bo, Wpwbf, pw_b, Cbf);
    k_offmask      <<<512,   256, 0, stream>>>(Cbf, Wpm, p_b, m_b, OM);
    k_deform       <<<512,   512, 0, stream>>>(Cbf, OM, Wbf, D, stats);
    k_bngelu_dw128 <<<1024,  256, 0, stream>>>(D, stats, bn1g, bn1b, dw2w, dw2b, Hs);
    k_bn_relu_out  <<<4096,  256, 0, stream>>>(Hs, stats, bn2g, bn2b, out);
}

// Round 17
// 194.796 us; speedup vs baseline: 1.3904x; 1.0069x over previous
//
#include <hip/hip_runtime.h>
#include <math.h>

// Problem constants: B=8, spatial 64x64 (HW=4096), C_mid=256, C=128, N=9 taps.
typedef const float* fp;
typedef __attribute__((ext_vector_type(8))) short short8;   // 8 bf16 = 4 VGPRs (MFMA A/B frag)
typedef __attribute__((ext_vector_type(4))) float f32x4;    // MFMA C/D frag

__device__ __forceinline__ unsigned short f2bf(float f){    // RTNE float->bf16 (scalar/cold paths)
    unsigned u = __float_as_uint(f);
    u += 0x7fff + ((u >> 16) & 1);
    return (unsigned short)(u >> 16);
}
__device__ __forceinline__ float bflo(unsigned u){ return __uint_as_float(u << 16); }
__device__ __forceinline__ float bfhi(unsigned u){ return __uint_as_float(u & 0xffff0000u); }
// HW packed convert: 1 instr for 2 values (gfx950 v_cvt_pk_bf16_f32; no builtin — inline asm)
__device__ __forceinline__ unsigned cvtpk(float a, float b){
    unsigned r; asm("v_cvt_pk_bf16_f32 %0, %1, %2" : "=v"(r) : "v"(a), "v"(b)); return r;
}
__device__ __forceinline__ void st4bf(void* p, float a, float b, float c, float d){
    uint2 v; v.x = cvtpk(a,b); v.y = cvtpk(c,d);
    *(uint2*)p = v;
}

// ---------------- K0 v3: coalesced prep
__global__ __launch_bounds__(256) void k_prep(fp dcn_w, fp pw, fp mw, fp pww,
                                              unsigned short* Wbf, unsigned short* Wpm,
                                              unsigned short* Wpwbf){
    int i = blockIdx.x*256 + threadIdx.x;
    if(i < 16384){                              // dcn: (o,c) -> 9 taps
        int o = i >> 7, c = i & 127;
        const float* s = dcn_w + o*1152 + c*9;
        #pragma unroll
        for(int n=0;n<9;n++) Wbf[(n<<14) + (o<<7) + c] = f2bf(s[n]);
    } else if(i < 20480){                       // pw/mw: (q,c) -> 9 taps, q<32
        int j = i - 16384;
        int q = j >> 7, c = j & 127;
        if(q < 18){
            const float* s = pw + q*1152 + c*9;
            #pragma unroll
            for(int n=0;n<9;n++) Wpm[(n<<12) + (q<<7) + c] = f2bf(s[n]);
        } else if(q < 27){
            const float* s = mw + (q-18)*1152 + c*9;
            #pragma unroll
            for(int n=0;n<9;n++) Wpm[(n<<12) + (q<<7) + c] = f2bf(s[n]);
        } else {
            #pragma unroll
            for(int n=0;n<9;n++) Wpm[(n<<12) + (q<<7) + c] = 0;
        }
    } else if(i < 53248){
        int j = i - 20480;                      // 32768: pointwise weights [o][c] bf16
        Wpwbf[j] = f2bf(pww[j]);
    }
}

// ---------------- K1 v3: fused upsample+concat+depthwise256 -> Bo (8,256,4096) BF16
__global__ __launch_bounds__(256) void k_updw256(fp x1, fp x2, fp w, fp bias, unsigned short* Bo){
    __shared__ float sA[66*68 + 4];
    int bid = blockIdx.x;
    int c = bid & 255, b = bid >> 8;
    int tid = threadIdx.x;
    for(int j = tid; j < 264; j += 256){
        int idx;
        if(j < 66)       idx = j;
        else if(j < 132) idx = 65*68 + (j-66);
        else if(j < 196) idx = (j-132+1)*68;
        else if(j < 260) idx = (j-196+1)*68 + 65;
        else             idx = 66*68 + (j-260);
        sA[idx] = 0.f;
    }
    if(c < 128){
        const float* src = x2 + ((size_t)(b*128+c)<<12);
        for(int j = tid; j < 1024; j += 256){
            int yy = j >> 4, x4 = (j & 15) << 2;
            float4 v = *(const float4*)&src[(yy<<6) + x4];
            float* d = &sA[(yy+1)*68 + x4 + 1];
            d[0]=v.x; d[1]=v.y; d[2]=v.z; d[3]=v.w;
        }
    } else {
        int cc = c - 128;
        fp src = x1 + ((b*128+cc)<<10);
        const float s = 31.0f/63.0f;
        for(int j = tid; j < 4096; j += 256){
            int yy = j >> 6, xx = j & 63;
            float fy = yy*s, fx = xx*s;
            int iy = (int)fy; if (iy > 30) iy = 30;
            int ix = (int)fx; if (ix > 30) ix = 30;
            float ty = fy - (float)iy, tx = fx - (float)ix;
            float v00 = src[iy*32+ix],     v01 = src[iy*32+ix+1];
            float v10 = src[(iy+1)*32+ix], v11 = src[(iy+1)*32+ix+1];
            sA[(yy+1)*68 + xx + 1] =
                (v00*(1.f-ty)+v10*ty)*(1.f-tx) + (v01*(1.f-ty)+v11*ty)*tx;
        }
    }
    __syncthreads();
    float w0=w[c*9+0], w1=w[c*9+1], w2=w[c*9+2];
    float w3=w[c*9+3], w4=w[c*9+4], w5=w[c*9+5];
    float w6=w[c*9+6], w7=w[c*9+7], w8=w[c*9+8];
    float bv = bias[c];
    unsigned short* dst = Bo + ((size_t)(b*256+c)<<12);
    for(int j = tid; j < 1024; j += 256){
        int y = j >> 4, x0 = (j & 15) << 2;
        float a0=bv, a1=bv, a2=bv, a3=bv;
        #pragma unroll
        for(int ky=0; ky<3; ky++){
            const float* rr = &sA[(y+ky)*68 + x0];
            float4 u0 = *(const float4*)&rr[0];
            float2 u1 = *(const float2*)&rr[4];
            float wA = (ky==0)?w0:((ky==1)?w3:w6);
            float wB = (ky==0)?w1:((ky==1)?w4:w7);
            float wC = (ky==0)?w2:((ky==1)?w5:w8);
            a0 += wA*u0.x + wB*u0.y + wC*u0.z;
            a1 += wA*u0.y + wB*u0.z + wC*u0.w;
            a2 += wA*u0.z + wB*u0.w + wC*u1.x;
            a3 += wA*u0.w + wB*u1.x + wC*u1.y;
        }
        st4bf(&dst[(y<<6)+x0], a0,a1,a2,a3);
    }
}

// ---------------- K3 v6: pointwise 256->128 + bias via bf16 MFMA; Bo bf16 in, Cbf bf16 out.
#define PW_STAGE_X(kc, bufp) do{ \
    _Pragma("unroll") \
    for(int k_=0;k_<4;k_++){ \
        int j_ = tid + (k_<<9); \
        int cc_ = j_ >> 4, p4_ = (j_ & 15) << 2; \
        int c_ = ((kc)<<7) + cc_; \
        uint2 v_ = *(const uint2*)&Bo[((size_t)((b<<8)+c_)<<12) + pix0 + p4_]; \
        (bufp)[(p4_+0)*136 + cc_] = (unsigned short)(v_.x & 0xffffu); \
        (bufp)[(p4_+1)*136 + cc_] = (unsigned short)(v_.x >> 16); \
        (bufp)[(p4_+2)*136 + cc_] = (unsigned short)(v_.y & 0xffffu); \
        (bufp)[(p4_+3)*136 + cc_] = (unsigned short)(v_.y >> 16); \
    } }while(0)

#define PW_STAGE_W(kc) do{ \
    _Pragma("unroll") \
    for(int k_=0;k_<4;k_++){ \
        int j_ = tid + (k_<<9); \
        int o_ = j_ >> 4, cg_ = j_ & 15; \
        *(int4*)&sW[o_*136 + (cg_<<3)] = \
            *(const int4*)&Wpwbf[o_*256 + ((kc)<<7) + (cg_<<3)]; \
    } }while(0)

#define PW_DOMFMA(srcp) do{ \
    _Pragma("unroll") \
    for(int ks_=0; ks_<4; ks_++){ \
        int k0_ = ks_ << 5; \
        short8 bfr0 = *(const short8*)&(srcp)[(phb + m16)*136 + k0_ + (quad<<3)]; \
        short8 bfr1 = *(const short8*)&(srcp)[(phb + 16 + m16)*136 + k0_ + (quad<<3)]; \
        _Pragma("unroll") \
        for(int ot_=0;ot_<2;ot_++){ \
            short8 afr = *(const short8*)&sW[(wo + (ot_<<4) + m16)*136 + k0_ + (quad<<3)]; \
            acc[ot_][0] = __builtin_amdgcn_mfma_f32_16x16x32_bf16(afr, bfr0, acc[ot_][0], 0,0,0); \
            acc[ot_][1] = __builtin_amdgcn_mfma_f32_16x16x32_bf16(afr, bfr1, acc[ot_][1], 0,0,0); \
        } } }while(0)

__global__ __launch_bounds__(512, 2) void k_pw(const unsigned short* Bo, const unsigned short* Wpwbf,
                                               fp bias, unsigned short* Cbf){
    __shared__ __align__(16) unsigned short sW[128*136];     // 34,816 B [o][cc]
    __shared__ __align__(16) unsigned short sX[2][64*136];   // 34,816 B dbuf [px][cc]
    int b = blockIdx.x & 7;
    int pix0 = (blockIdx.x >> 3) << 6;   // 64 tiles x 8 b
    int tid = threadIdx.x;               // 0..511
    int lane = tid & 63, wave = tid >> 6;
    int m16 = lane & 15, quad = lane >> 4;
    int wo  = (wave & 3) << 5;           // o-range: 4 groups of 32
    int phb = (wave >> 2) << 5;          // px-half: 0 / 32

    // ---- probe
    short8 ap = {0,0,0,0,0,0,0,0}, bpr = {0,0,0,0,0,0,0,0};
    if(quad == 0){
        ap[0]  = (short)f2bf((float)m16);
        bpr[0] = (short)f2bf((float)(m16+100));
    }
    f32x4 dp = {0.f,0.f,0.f,0.f};
    dp = __builtin_amdgcn_mfma_f32_16x16x32_bf16(ap, bpr, dp, 0,0,0);
    bool p1 = true;
    #pragma unroll
    for(int r=0;r<4;r++){
        float expP1 = (float)(quad*4+r) * (float)(m16+100);
        p1 = p1 && (fabsf(dp[r]-expP1) < 0.5f);
    }
    bool swapD = (__ballot(p1) != 0xFFFFFFFFFFFFFFFFull);

    f32x4 acc[2][2];                     // [ot][pt]
    #pragma unroll
    for(int i=0;i<2;i++){
        #pragma unroll
        for(int j=0;j<2;j++) acc[i][j] = (f32x4){0.f,0.f,0.f,0.f};
    }

    // ---- pipeline: 2 K-chunks
    PW_STAGE_X(0, (&sX[0][0]));
    PW_STAGE_W(0);
    __syncthreads();                      // sX[0], sW(0) ready
    PW_STAGE_X(1, (&sX[1][0]));           // overlaps MFMA(0)
    PW_DOMFMA((&sX[0][0]));
    __syncthreads();                      // MFMA(0) done (sW free), sX[1] writes done
    PW_STAGE_W(1);
    __syncthreads();                      // sW(1) ready
    PW_DOMFMA((&sX[1][0]));

    // ---- epilogue: bias + channel-last bf16 write
    if(!swapD){
        #pragma unroll
        for(int ot=0;ot<2;ot++){
            int o0 = wo + (ot<<4) + (quad<<2);
            float4 bv = *(const float4*)&bias[o0];
            #pragma unroll
            for(int pt=0;pt<2;pt++){
                int px = pix0 + phb + (pt<<4) + m16;
                st4bf(&Cbf[((size_t)((b<<12) + px))*128 + o0],
                      acc[ot][pt][0]+bv.x, acc[ot][pt][1]+bv.y,
                      acc[ot][pt][2]+bv.z, acc[ot][pt][3]+bv.w);
            }
        }
    } else {
        #pragma unroll
        for(int ot=0;ot<2;ot++){
            int o = wo + (ot<<4) + m16;
            float bv = bias[o];
            #pragma unroll
            for(int pt=0;pt<2;pt++){
                #pragma unroll
                for(int r=0;r<4;r++){
                    int px = pix0 + phb + (pt<<4) + (quad<<2) + r;
                    Cbf[((size_t)((b<<12) + px))*128 + o] = f2bf(acc[ot][pt][r] + bv);
                }
            }
        }
    }
}

// ---------------- K5 v14: FUSED offmask + deform. Grid 512 (one row x 8 b), 512 thr.
// Phase A (= verified k_offmask v4 retiled 8 wave-tiles): window + Wpm dbuf -> OM row
// kept in LDS (sOM, 6.9 KB) — OM never touches global. Phase B = verified deform v13
// reading meta offsets from sOM. LDS union 71,680 + sOM 6,912 = 78,592 B -> 2 blocks/CU.
#define K5_META(t) do{ if(tid < 256){ \
    int px_ = tid >> 2, k_ = tid & 3; \
    int yq_ = y, xq_ = px_; \
    int kyy_ = (t)/3, kxx_ = (t)-kyy_*3; \
    float oxv_ = sOM[((t)<<6)+px_]; \
    float oyv_ = sOM[(((t)+9)<<6)+px_]; \
    float mv_  = sOM[(((t)+18)<<6)+px_]; \
    float pxf_ = (float)(yq_ + kyy_) + oxv_; \
    float pyf_ = (float)(xq_ + kxx_) + oyv_; \
    float fx_ = floorf(pxf_), fy_ = floorf(pyf_); \
    float qx0_ = fminf(fmaxf(fx_,0.f),65.f),  qx1_ = fminf(fmaxf(fx_+1.f,0.f),65.f); \
    float qy0_ = fminf(fmaxf(fy_,0.f),65.f),  qy1_ = fminf(fmaxf(fy_+1.f,0.f),65.f); \
    float pxc_ = fminf(fmaxf(pxf_,0.f),65.f), pyc_ = fminf(fmaxf(pyf_,0.f),65.f); \
    float dx0_ = 1.f+(qx0_-pxc_), dx1_ = 1.f-(qx1_-pxc_); \
    float dy0_ = 1.f+(qy0_-pyc_), dy1_ = 1.f-(qy1_-pyc_); \
    int ax0_=(int)qx0_, ax1_=(int)qx1_, ay0_=(int)qy0_, ay1_=(int)qy1_; \
    bool vx0_ = (ax0_>=1)&&(ax0_<=64), vx1_ = (ax1_>=1)&&(ax1_<=64); \
    bool vy0_ = (ay0_>=1)&&(ay0_<=64), vy1_ = (ay1_>=1)&&(ay1_<=64); \
    int  axs_ = (k_&1) ? ax1_ : ax0_; \
    int  ays_ = (k_==1||k_==2) ? ay1_ : ay0_; \
    bool vxs_ = (k_&1) ? vx1_ : vx0_; \
    bool vys_ = (k_==1||k_==2) ? vy1_ : vy0_; \
    float dxs_ = (k_&1) ? dx1_ : dx0_; \
    float dys_ = (k_==1||k_==2) ? dy1_ : dy0_; \
    bool v_ = vxs_ && vys_; \
    int base_ = v_ ? (((axs_-1)<<6)+(ays_-1)) : 0; \
    float g_ = v_ ? dxs_*dys_*mv_ : 0.f; \
    sM[tid] = make_uint2((unsigned)base_, __float_as_uint(g_)); \
} }while(0)

#define K5_GATHER(bufp) do{ \
    _Pragma("unroll") \
    for(int j_=0;j_<4;j_++){ \
        int px_ = pxb + (j_<<4); \
        uint2 e0_ = sM[(px_<<2)+0]; \
        uint2 e1_ = sM[(px_<<2)+1]; \
        uint2 e2_ = sM[(px_<<2)+2]; \
        uint2 e3_ = sM[(px_<<2)+3]; \
        float g0_ = __uint_as_float(e0_.y), g1_ = __uint_as_float(e1_.y); \
        float g2_ = __uint_as_float(e2_.y), g3_ = __uint_as_float(e3_.y); \
        uint2 c0_ = *(const uint2*)&cb[((size_t)e0_.x<<7) + cg4]; \
        uint2 c1_ = *(const uint2*)&cb[((size_t)e1_.x<<7) + cg4]; \
        uint2 c2_ = *(const uint2*)&cb[((size_t)e2_.x<<7) + cg4]; \
        uint2 c3_ = *(const uint2*)&cb[((size_t)e3_.x<<7) + cg4]; \
        float vx_ = g0_*bflo(c0_.x) + g1_*bflo(c1_.x) + g2_*bflo(c2_.x) + g3_*bflo(c3_.x); \
        float vy_ = g0_*bfhi(c0_.x) + g1_*bfhi(c1_.x) + g2_*bfhi(c2_.x) + g3_*bfhi(c3_.x); \
        float vz_ = g0_*bflo(c0_.y) + g1_*bflo(c1_.y) + g2_*bflo(c2_.y) + g3_*bflo(c3_.y); \
        float vw_ = g0_*bfhi(c0_.y) + g1_*bfhi(c1_.y) + g2_*bfhi(c2_.y) + g3_*bfhi(c3_.y); \
        st4bf(&(bufp)[px_*136 + cg4], vx_, vy_, vz_, vw_); \
    } }while(0)

#define K5_STAGE_W(t) do{ \
    const int4* wsrc_ = (const int4*)(Wbf + ((t)<<14)); \
    _Pragma("unroll") \
    for(int k_=0;k_<4;k_++){ int j_ = tid + (k_<<9); \
        *(int4*)&sW[(j_>>4)*136 + ((j_&15)<<3)] = wsrc_[j_]; } }while(0)

#define K5_DOMFMA(srcp) do{ \
    _Pragma("unroll") \
    for(int ks_=0; ks_<4; ks_++){ \
        int k0_ = ks_ << 5; \
        short8 bfr0 = *(const short8*)&(srcp)[(phb + m16)*136 + k0_ + (quad<<3)]; \
        short8 bfr1 = *(const short8*)&(srcp)[(phb + 16 + m16)*136 + k0_ + (quad<<3)]; \
        _Pragma("unroll") \
        for(int ot_=0;ot_<2;ot_++){ \
            short8 afr = *(const short8*)&sW[(wo + (ot_<<4) + m16)*136 + k0_ + (quad<<3)]; \
            acc[ot_][0] = __builtin_amdgcn_mfma_f32_16x16x32_bf16(afr, bfr0, acc[ot_][0], 0,0,0); \
            acc[ot_][1] = __builtin_amdgcn_mfma_f32_16x16x32_bf16(afr, bfr1, acc[ot_][1], 0,0,0); \
        } } }while(0)

__global__ __launch_bounds__(512, 2) void k_deform(const unsigned short* Cbf,
                                                   const unsigned short* Wpm, fp pb, fp mb,
                                                   const unsigned short* Wbf,
                                                   unsigned short* D, float* stats){
    __shared__ __align__(16) unsigned short uLDS[35840];     // 71,680 B union (A: win+Wpm / B: sW+sX+sM)
    __shared__ __align__(16) float sOM[27*64];               //  6,912 B OM row (persists A->B)
    int b = blockIdx.x & 7;
    int y = blockIdx.x >> 3;             // output row
    int pix0 = y << 6;
    int tid = threadIdx.x;               // 0..511
    int lane = tid & 63, wave = tid >> 6;
    int m16 = lane & 15, quad = lane >> 4;
    int wo  = (wave & 3) << 5;           // phase B: o-range
    int phb = (wave >> 2) << 5;          // phase B: px-half
    int cg4 = (tid & 31) << 2;           // channel group (4 ch)
    int pxb = tid >> 5;                  // base px 0..15
    const unsigned short* cb = Cbf + ((size_t)b<<12)*128;

    // ---- probe (shared by both phases)
    short8 ap = {0,0,0,0,0,0,0,0}, bpr = {0,0,0,0,0,0,0,0};
    if(quad == 0){
        ap[0]  = (short)f2bf((float)m16);
        bpr[0] = (short)f2bf((float)(m16+100));
    }
    f32x4 dp = {0.f,0.f,0.f,0.f};
    dp = __builtin_amdgcn_mfma_f32_16x16x32_bf16(ap, bpr, dp, 0,0,0);
    bool p1 = true;
    #pragma unroll
    for(int r=0;r<4;r++){
        float expP1 = (float)(quad*4+r) * (float)(m16+100);
        p1 = p1 && (fabsf(dp[r]-expP1) < 0.5f);
    }
    bool swapD = (__ballot(p1) != 0xFFFFFFFFFFFFFFFFull);

    // ================= PHASE A: offset+mask conv -> sOM =================
    {
        unsigned short* sWin  = uLDS;            // 26,928 shorts (3x66x136)
        unsigned short* sWpm0 = uLDS + 26928;    //  4,096 shorts
        unsigned short* sWpm1 = uLDS + 31024;    //  4,096 shorts
        int qt = wave & 1, pt = wave >> 1;       // 2 q-tiles x 4 px-tiles
        // prologue: issue Wpm(0) (512 int4 = full tap), stage window, write sWpm0
        int4 w0_ = ((const int4*)Wpm)[tid];
        for(int i = tid; i < 3168; i += 512){    // 198 pos x 16 groups of 8 ch
            int pos = i >> 4, g = i & 15;
            int r = pos / 66, col = pos - r*66;
            int yy = y + r - 1, xx = col - 1;
            int4 v = make_int4(0,0,0,0);
            if(yy>=0 && yy<64 && xx>=0 && xx<64)
                v = *(const int4*)&cb[(size_t)((yy<<6)+xx)*128 + (g<<3)];
            *(int4*)&sWin[pos*136 + (g<<3)] = v;
        }
        *(int4*)&sWpm0[(tid>>4)*136 + ((tid&15)<<3)] = w0_;
        __syncthreads();

        f32x4 accA = {0.f,0.f,0.f,0.f};
        for(int n=0;n<9;n++){
            int4 wn_;
            if(n<8) wn_ = ((const int4*)(Wpm + ((n+1)<<12)))[tid];  // issue early
            int ky = n/3, kx = n - ky*3;
            const unsigned short* base = &sWin[(ky*66 + (pt<<4) + kx)*136];
            const unsigned short* swp = (n&1) ? sWpm1 : sWpm0;
            #pragma unroll
            for(int ks=0; ks<4; ks++){
                int k0 = ks << 5;
                short8 bfr = *(const short8*)&base[m16*136 + k0 + (quad<<3)];
                short8 afr = *(const short8*)&swp[((qt<<4) + m16)*136 + k0 + (quad<<3)];
                accA = __builtin_amdgcn_mfma_f32_16x16x32_bf16(afr, bfr, accA, 0,0,0);
            }
            if(n<8){
                unsigned short* swn = ((n+1)&1) ? sWpm1 : sWpm0;
                *(int4*)&swn[(tid>>4)*136 + ((tid&15)<<3)] = wn_;
            }
            __syncthreads();
        }
        if(!swapD){
            int pxl = (pt<<4) + m16;
            #pragma unroll
            for(int r=0;r<4;r++){
                int q = (qt<<4) + (quad<<2) + r;
                if(q < 27){
                    float v = accA[r] + ((q<18) ? pb[q] : mb[q-18]);
                    if(q>=18) v = 1.f/(1.f+expf(-v));
                    sOM[(q<<6) + pxl] = v;
                }
            }
        } else {
            int q = (qt<<4) + m16;
            if(q < 27){
                float bias2 = (q<18) ? pb[q] : mb[q-18];
                #pragma unroll
                for(int r=0;r<4;r++){
                    int pxl = (pt<<4) + (quad<<2) + r;
                    float v = accA[r] + bias2;
                    if(q>=18) v = 1.f/(1.f+expf(-v));
                    sOM[(q<<6) + pxl] = v;
                }
            }
        }
        __syncthreads();                  // sOM complete; uLDS free for phase B
    }

    // ================= PHASE B: deformable sampling + MFMA (verified v13) =================
    unsigned short* sW = uLDS;                   // 17,408 shorts [o][c]
    unsigned short* sXb = uLDS + 17408;          // 2 x 8,704 shorts dbuf [px][c]
    uint2* sM = (uint2*)(uLDS + 34816);          // 256 entries

    f32x4 acc[2][2];                     // [ot][pt]
    #pragma unroll
    for(int i=0;i<2;i++){
        #pragma unroll
        for(int j=0;j<2;j++) acc[i][j] = (f32x4){0.f,0.f,0.f,0.f};
    }

    // ---- prologue
    K5_META(0);
    __syncthreads();                      // sM = meta(0)
    K5_GATHER((sXb));                     // gather(0) using meta(0)
    K5_STAGE_W(0);
    __syncthreads();                      // sX[0], sW(0) ready; sM reads done
    K5_META(1);
    __syncthreads();                      // sM = meta(1)

    for(int n=0;n<9;n++){
        if(n<8) K5_GATHER((sXb + (((n+1)&1)*8704)));  // meta(n+1); overlaps MFMA(n)
        K5_DOMFMA((sXb + ((n&1)*8704)));              // operands from LDS (sW, sX)
        __syncthreads();                              // sW/sM reads + sX writes done
        if(n<8){
            K5_STAGE_W(n+1);                          // sW <- W(n+1), transient regs
            if(n<7) K5_META(n+2);                     // sM <- meta(n+2)
            __syncthreads();                          // sW, sM ready for next iter
        }
    }

    // epilogue: bf16 D writes + per-channel sum/sumsq reduction (stats from f32 acc)
    float* sdq = (float*)uLDS;            // [0..127]=sum, [128..255]=sumsq
    if(tid < 256) sdq[tid] = 0.f;
    __syncthreads();
    if(!swapD){
        #pragma unroll
        for(int ot=0;ot<2;ot++){
            #pragma unroll
            for(int pt=0;pt<2;pt++){
                int px = pix0 + phb + (pt<<4) + m16;
                #pragma unroll
                for(int r=0;r<4;r++){
                    int o = wo + (ot<<4) + (quad<<2) + r;
                    D[((size_t)(b*128+o)<<12) + px] = f2bf(acc[ot][pt][r]);
                }
            }
        }
        #pragma unroll
        for(int ot=0;ot<2;ot++){
            #pragma unroll
            for(int r=0;r<4;r++){
                float s  = acc[ot][0][r] + acc[ot][1][r];
                float s2 = acc[ot][0][r]*acc[ot][0][r] + acc[ot][1][r]*acc[ot][1][r];
                #pragma unroll
                for(int msk=1; msk<16; msk<<=1){
                    s  += __shfl_xor(s, msk, 64);
                    s2 += __shfl_xor(s2, msk, 64);
                }
                if(m16 == 0){
                    int o = wo + (ot<<4) + (quad<<2) + r;
                    atomicAdd(&sdq[o], s);
                    atomicAdd(&sdq[128+o], s2);
                }
            }
        }
    } else {
        #pragma unroll
        for(int ot=0;ot<2;ot++){
            #pragma unroll
            for(int pt=0;pt<2;pt++){
                int o = wo + (ot<<4) + m16;
                #pragma unroll
                for(int r=0;r<4;r++){
                    int px = pix0 + phb + (pt<<4) + (quad<<2) + r;
                    D[((size_t)(b*128+o)<<12) + px] = f2bf(acc[ot][pt][r]);
                }
            }
        }
        #pragma unroll
        for(int ot=0;ot<2;ot++){
            float s = 0.f, s2 = 0.f;
            #pragma unroll
            for(int pt=0;pt<2;pt++){
                #pragma unroll
                for(int r=0;r<4;r++){
                    float v = acc[ot][pt][r];
                    s += v; s2 += v*v;
                }
            }
            #pragma unroll
            for(int msk=16; msk<64; msk<<=1){
                s  += __shfl_xor(s, msk, 64);
                s2 += __shfl_xor(s2, msk, 64);
            }
            if(quad == 0){
                int o = wo + (ot<<4) + m16;
                atomicAdd(&sdq[o], s);
                atomicAdd(&sdq[128+o], s2);
            }
        }
    }
    __syncthreads();
    if(tid < 128){
        atomicAdd(&stats[tid],     sdq[tid]);
        atomicAdd(&stats[128+tid], sdq[128+tid]);
    }
}

// ---------------- K7 v3: fused BN1+GELU + depthwise128 (bf16 D in, bf16 Hs out)
__global__ __launch_bounds__(256) void k_bngelu_dw128(const unsigned short* Dsrc, float* stats,
                                                      fp g1, fp b1, fp w, fp bias, unsigned short* Hs){
    __shared__ float sG[66*68 + 4];
    __shared__ float sd[256], sq[256];
    int bid = blockIdx.x;
    int c = bid & 127, b = bid >> 7;
    int tid = threadIdx.x;
    float mean1 = stats[c] * (1.f/32768.f);
    float var1  = stats[128+c] * (1.f/32768.f) - mean1*mean1;
    float rstd1 = rsqrtf(var1 + 1e-5f);
    float sc = rstd1 * g1[c];
    float sb = b1[c] - mean1*sc;
    for(int j = tid; j < 264; j += 256){
        int idx;
        if(j < 66)       idx = j;
        else if(j < 132) idx = 65*68 + (j-66);
        else if(j < 196) idx = (j-132+1)*68;
        else if(j < 260) idx = (j-196+1)*68 + 65;
        else             idx = 66*68 + (j-260);
        sG[idx] = 0.f;
    }
    const unsigned short* dplane = Dsrc + ((size_t)(b*128+c)<<12);
    for(int j = tid; j < 1024; j += 256){
        int yy = j >> 4, x4 = (j & 15) << 2;
        uint2 v = *(const uint2*)&dplane[(yy<<6) + x4];
        float g0 = bflo(v.x)*sc+sb, g1v = bfhi(v.x)*sc+sb;
        float g2 = bflo(v.y)*sc+sb, g3 = bfhi(v.y)*sc+sb;
        float* d = &sG[(yy+1)*68 + x4 + 1];
        d[0] = 0.5f*g0*(1.0f + erff(g0*0.70710678118654752f));
        d[1] = 0.5f*g1v*(1.0f + erff(g1v*0.70710678118654752f));
        d[2] = 0.5f*g2*(1.0f + erff(g2*0.70710678118654752f));
        d[3] = 0.5f*g3*(1.0f + erff(g3*0.70710678118654752f));
    }
    __syncthreads();
    float w0=w[c*9+0], w1=w[c*9+1], w2=w[c*9+2];
    float w3=w[c*9+3], w4=w[c*9+4], w5=w[c*9+5];
    float w6=w[c*9+6], w7=w[c*9+7], w8=w[c*9+8];
    float bv = bias[c];
    unsigned short* dst = Hs + ((size_t)(b*128+c)<<12);
    float s = 0.f, s2 = 0.f;
    for(int j = tid; j < 1024; j += 256){
        int y = j >> 4, x0 = (j & 15) << 2;
        float a0=bv, a1=bv, a2=bv, a3=bv;
        #pragma unroll
        for(int ky=0; ky<3; ky++){
            const float* rr = &sG[(y+ky)*68 + x0];
            float4 u0 = *(const float4*)&rr[0];
            float2 u1 = *(const float2*)&rr[4];
            float wA = (ky==0)?w0:((ky==1)?w3:w6);
            float wB = (ky==0)?w1:((ky==1)?w4:w7);
            float wC = (ky==0)?w2:((ky==1)?w5:w8);
            a0 += wA*u0.x + wB*u0.y + wC*u0.z;
            a1 += wA*u0.y + wB*u0.z + wC*u0.w;
            a2 += wA*u0.z + wB*u0.w + wC*u1.x;
            a3 += wA*u0.w + wB*u1.x + wC*u1.y;
        }
        st4bf(&dst[(y<<6)+x0], a0,a1,a2,a3);
        s += a0+a1+a2+a3;
        s2 += a0*a0 + a1*a1 + a2*a2 + a3*a3;
    }
    sd[tid]=s; sq[tid]=s2; __syncthreads();
    for(int off=128; off>0; off>>=1){
        if(tid<off){ sd[tid]+=sd[tid+off]; sq[tid]+=sq[tid+off]; }
        __syncthreads();
    }
    if(tid==0){
        atomicAdd(&stats[256+c], sd[0]);
        atomicAdd(&stats[384+c], sq[0]);
    }
}

// ---------------- BN2 + ReLU -> f32 out (bf16 Hs in)
__global__ __launch_bounds__(256) void k_bn_relu_out(const unsigned short* Hs, const float* stats,
                                                     fp g, fp bb, float* out){
    int idx = blockIdx.x*256+threadIdx.x;       // 1,048,576 groups of 4 px
    int c = (idx>>10)&127;
    float mean2 = stats[256+c] * (1.f/32768.f);
    float var2  = stats[384+c] * (1.f/32768.f) - mean2*mean2;
    float rs = rsqrtf(var2 + 1e-5f) * g[c];
    float sb = bb[c] - mean2*rs;
    uint2 v = ((const uint2*)Hs)[idx];
    float4 o;
    o.x = fmaxf(bflo(v.x)*rs+sb, 0.f);
    o.y = fmaxf(bfhi(v.x)*rs+sb, 0.f);
    o.z = fmaxf(bflo(v.y)*rs+sb, 0.f);
    o.w = fmaxf(bfhi(v.y)*rs+sb, 0.f);
    ((float4*)out)[idx] = o;
}

extern "C" void kernel_launch(void* const* d_in, const int* in_sizes, int n_in,
                              void* d_out, int out_size, void* d_ws, size_t ws_size,
                              hipStream_t stream){
    fp x1   = (fp)d_in[0];
    fp x2   = (fp)d_in[1];
    fp dw_w = (fp)d_in[2];  fp dw_b = (fp)d_in[3];
    fp pw_w = (fp)d_in[4];  fp pw_b = (fp)d_in[5];
    fp p_w  = (fp)d_in[6];  fp p_b  = (fp)d_in[7];
    fp m_w  = (fp)d_in[8];  fp m_b  = (fp)d_in[9];
    fp dcn_w= (fp)d_in[10];
    fp bn1g = (fp)d_in[11]; fp bn1b = (fp)d_in[12];
    fp dw2w = (fp)d_in[13]; fp dw2b = (fp)d_in[14];
    fp bn2g = (fp)d_in[15]; fp bn2b = (fp)d_in[16];

    float* ws  = (float*)d_ws;
    unsigned short* Bo  = (unsigned short*)ws;               // (8,256,4096) bf16 ; D overlays after k_pw
    unsigned short* Cbf = (unsigned short*)(ws + 8388608);   // (8,4096,128) bf16 ; Hs overlays after k_deform
    unsigned short* Hs  = (unsigned short*)(ws + 8388608);   // (8,128,4096) bf16
    unsigned short* Wbf = (unsigned short*)(ws + 13467648);
    unsigned short* Wpm = (unsigned short*)(ws + 13541376);
    float* stats = ws + 13559808;       // 512 f
    unsigned short* Wpwbf = (unsigned short*)(ws + 13560320);  // 32,768 bf16
    unsigned short* D   = Bo;           // Bo dead after k_pw
    float* out = (float*)d_out;

    hipMemsetAsync(stats, 0, 512*sizeof(float), stream);
    k_prep         <<<208,   256, 0, stream>>>(dcn_w, p_w, m_w, pw_w, Wbf, Wpm, Wpwbf);
    k_updw256      <<<2048,  256, 0, stream>>>(x1, x2, dw_w, dw_b, Bo);
    k_pw           <<<512,   512, 0, stream>>>(Bo, Wpwbf, pw_b, Cbf);
    k_deform       <<<512,   512, 0, stream>>>(Cbf, Wpm, p_b, m_b, Wbf, D, stats);  // fused offmask+deform
    k_bngelu_dw128 <<<1024,  256, 0, stream>>>(D, stats, bn1g, bn1b, dw2w, dw2b, Hs);
    k_bn_relu_out  <<<4096,  256, 0, stream>>>(Hs, stats, bn2g, bn2b, out);
}

// Round 18
// 192.370 us; speedup vs baseline: 1.4080x; 1.0126x over previous
//
#include <hip/hip_runtime.h>
#include <math.h>

// Problem constants: B=8, spatial 64x64 (HW=4096), C_mid=256, C=128, N=9 taps.
typedef const float* fp;
typedef __attribute__((ext_vector_type(8))) short short8;   // 8 bf16 = 4 VGPRs (MFMA A/B frag)
typedef __attribute__((ext_vector_type(4))) float f32x4;    // MFMA C/D frag

__device__ __forceinline__ unsigned short f2bf(float f){    // RTNE float->bf16 (scalar/cold paths)
    unsigned u = __float_as_uint(f);
    u += 0x7fff + ((u >> 16) & 1);
    return (unsigned short)(u >> 16);
}
__device__ __forceinline__ float bflo(unsigned u){ return __uint_as_float(u << 16); }
__device__ __forceinline__ float bfhi(unsigned u){ return __uint_as_float(u & 0xffff0000u); }
// HW packed convert: 1 instr for 2 values (gfx950 v_cvt_pk_bf16_f32; no builtin — inline asm)
__device__ __forceinline__ unsigned cvtpk(float a, float b){
    unsigned r; asm("v_cvt_pk_bf16_f32 %0, %1, %2" : "=v"(r) : "v"(a), "v"(b)); return r;
}
__device__ __forceinline__ void st4bf(void* p, float a, float b, float c, float d){
    uint2 v; v.x = cvtpk(a,b); v.y = cvtpk(c,d);
    *(uint2*)p = v;
}

// ---------------- K0 v3: coalesced prep
__global__ __launch_bounds__(256) void k_prep(fp dcn_w, fp pw, fp mw, fp pww,
                                              unsigned short* Wbf, unsigned short* Wpm,
                                              unsigned short* Wpwbf){
    int i = blockIdx.x*256 + threadIdx.x;
    if(i < 16384){                              // dcn: (o,c) -> 9 taps
        int o = i >> 7, c = i & 127;
        const float* s = dcn_w + o*1152 + c*9;
        #pragma unroll
        for(int n=0;n<9;n++) Wbf[(n<<14) + (o<<7) + c] = f2bf(s[n]);
    } else if(i < 20480){                       // pw/mw: (q,c) -> 9 taps, q<32
        int j = i - 16384;
        int q = j >> 7, c = j & 127;
        if(q < 18){
            const float* s = pw + q*1152 + c*9;
            #pragma unroll
            for(int n=0;n<9;n++) Wpm[(n<<12) + (q<<7) + c] = f2bf(s[n]);
        } else if(q < 27){
            const float* s = mw + (q-18)*1152 + c*9;
            #pragma unroll
            for(int n=0;n<9;n++) Wpm[(n<<12) + (q<<7) + c] = f2bf(s[n]);
        } else {
            #pragma unroll
            for(int n=0;n<9;n++) Wpm[(n<<12) + (q<<7) + c] = 0;
        }
    } else if(i < 53248){
        int j = i - 20480;                      // 32768: pointwise weights [o][c] bf16
        Wpwbf[j] = f2bf(pww[j]);
    }
}

// ---------------- K1 v3: fused upsample+concat+depthwise256 -> Bo (8,256,4096) BF16
__global__ __launch_bounds__(256) void k_updw256(fp x1, fp x2, fp w, fp bias, unsigned short* Bo){
    __shared__ float sA[66*68 + 4];
    int bid = blockIdx.x;
    int c = bid & 255, b = bid >> 8;
    int tid = threadIdx.x;
    for(int j = tid; j < 264; j += 256){
        int idx;
        if(j < 66)       idx = j;
        else if(j < 132) idx = 65*68 + (j-66);
        else if(j < 196) idx = (j-132+1)*68;
        else if(j < 260) idx = (j-196+1)*68 + 65;
        else             idx = 66*68 + (j-260);
        sA[idx] = 0.f;
    }
    if(c < 128){
        const float* src = x2 + ((size_t)(b*128+c)<<12);
        for(int j = tid; j < 1024; j += 256){
            int yy = j >> 4, x4 = (j & 15) << 2;
            float4 v = *(const float4*)&src[(yy<<6) + x4];
            float* d = &sA[(yy+1)*68 + x4 + 1];
            d[0]=v.x; d[1]=v.y; d[2]=v.z; d[3]=v.w;
        }
    } else {
        int cc = c - 128;
        fp src = x1 + ((b*128+cc)<<10);
        const float s = 31.0f/63.0f;
        for(int j = tid; j < 4096; j += 256){
            int yy = j >> 6, xx = j & 63;
            float fy = yy*s, fx = xx*s;
            int iy = (int)fy; if (iy > 30) iy = 30;
            int ix = (int)fx; if (ix > 30) ix = 30;
            float ty = fy - (float)iy, tx = fx - (float)ix;
            float v00 = src[iy*32+ix],     v01 = src[iy*32+ix+1];
            float v10 = src[(iy+1)*32+ix], v11 = src[(iy+1)*32+ix+1];
            sA[(yy+1)*68 + xx + 1] =
                (v00*(1.f-ty)+v10*ty)*(1.f-tx) + (v01*(1.f-ty)+v11*ty)*tx;
        }
    }
    __syncthreads();
    float w0=w[c*9+0], w1=w[c*9+1], w2=w[c*9+2];
    float w3=w[c*9+3], w4=w[c*9+4], w5=w[c*9+5];
    float w6=w[c*9+6], w7=w[c*9+7], w8=w[c*9+8];
    float bv = bias[c];
    unsigned short* dst = Bo + ((size_t)(b*256+c)<<12);
    for(int j = tid; j < 1024; j += 256){
        int y = j >> 4, x0 = (j & 15) << 2;
        float a0=bv, a1=bv, a2=bv, a3=bv;
        #pragma unroll
        for(int ky=0; ky<3; ky++){
            const float* rr = &sA[(y+ky)*68 + x0];
            float4 u0 = *(const float4*)&rr[0];
            float2 u1 = *(const float2*)&rr[4];
            float wA = (ky==0)?w0:((ky==1)?w3:w6);
            float wB = (ky==0)?w1:((ky==1)?w4:w7);
            float wC = (ky==0)?w2:((ky==1)?w5:w8);
            a0 += wA*u0.x + wB*u0.y + wC*u0.z;
            a1 += wA*u0.y + wB*u0.z + wC*u0.w;
            a2 += wA*u0.z + wB*u0.w + wC*u1.x;
            a3 += wA*u0.w + wB*u1.x + wC*u1.y;
        }
        st4bf(&dst[(y<<6)+x0], a0,a1,a2,a3);
    }
}

// ---------------- K3 v6: pointwise 256->128 + bias via bf16 MFMA; Bo bf16 in, Cbf bf16 out.
#define PW_STAGE_X(kc, bufp) do{ \
    _Pragma("unroll") \
    for(int k_=0;k_<4;k_++){ \
        int j_ = tid + (k_<<9); \
        int cc_ = j_ >> 4, p4_ = (j_ & 15) << 2; \
        int c_ = ((kc)<<7) + cc_; \
        uint2 v_ = *(const uint2*)&Bo[((size_t)((b<<8)+c_)<<12) + pix0 + p4_]; \
        (bufp)[(p4_+0)*136 + cc_] = (unsigned short)(v_.x & 0xffffu); \
        (bufp)[(p4_+1)*136 + cc_] = (unsigned short)(v_.x >> 16); \
        (bufp)[(p4_+2)*136 + cc_] = (unsigned short)(v_.y & 0xffffu); \
        (bufp)[(p4_+3)*136 + cc_] = (unsigned short)(v_.y >> 16); \
    } }while(0)

#define PW_STAGE_W(kc) do{ \
    _Pragma("unroll") \
    for(int k_=0;k_<4;k_++){ \
        int j_ = tid + (k_<<9); \
        int o_ = j_ >> 4, cg_ = j_ & 15; \
        *(int4*)&sW[o_*136 + (cg_<<3)] = \
            *(const int4*)&Wpwbf[o_*256 + ((kc)<<7) + (cg_<<3)]; \
    } }while(0)

#define PW_DOMFMA(srcp) do{ \
    _Pragma("unroll") \
    for(int ks_=0; ks_<4; ks_++){ \
        int k0_ = ks_ << 5; \
        short8 bfr0 = *(const short8*)&(srcp)[(phb + m16)*136 + k0_ + (quad<<3)]; \
        short8 bfr1 = *(const short8*)&(srcp)[(phb + 16 + m16)*136 + k0_ + (quad<<3)]; \
        _Pragma("unroll") \
        for(int ot_=0;ot_<2;ot_++){ \
            short8 afr = *(const short8*)&sW[(wo + (ot_<<4) + m16)*136 + k0_ + (quad<<3)]; \
            acc[ot_][0] = __builtin_amdgcn_mfma_f32_16x16x32_bf16(afr, bfr0, acc[ot_][0], 0,0,0); \
            acc[ot_][1] = __builtin_amdgcn_mfma_f32_16x16x32_bf16(afr, bfr1, acc[ot_][1], 0,0,0); \
        } } }while(0)

__global__ __launch_bounds__(512, 2) void k_pw(const unsigned short* Bo, const unsigned short* Wpwbf,
                                               fp bias, unsigned short* Cbf){
    __shared__ __align__(16) unsigned short sW[128*136];     // 34,816 B [o][cc]
    __shared__ __align__(16) unsigned short sX[2][64*136];   // 34,816 B dbuf [px][cc]
    int b = blockIdx.x & 7;
    int pix0 = (blockIdx.x >> 3) << 6;   // 64 tiles x 8 b
    int tid = threadIdx.x;               // 0..511
    int lane = tid & 63, wave = tid >> 6;
    int m16 = lane & 15, quad = lane >> 4;
    int wo  = (wave & 3) << 5;           // o-range: 4 groups of 32
    int phb = (wave >> 2) << 5;          // px-half: 0 / 32

    // ---- probe
    short8 ap = {0,0,0,0,0,0,0,0}, bpr = {0,0,0,0,0,0,0,0};
    if(quad == 0){
        ap[0]  = (short)f2bf((float)m16);
        bpr[0] = (short)f2bf((float)(m16+100));
    }
    f32x4 dp = {0.f,0.f,0.f,0.f};
    dp = __builtin_amdgcn_mfma_f32_16x16x32_bf16(ap, bpr, dp, 0,0,0);
    bool p1 = true;
    #pragma unroll
    for(int r=0;r<4;r++){
        float expP1 = (float)(quad*4+r) * (float)(m16+100);
        p1 = p1 && (fabsf(dp[r]-expP1) < 0.5f);
    }
    bool swapD = (__ballot(p1) != 0xFFFFFFFFFFFFFFFFull);

    f32x4 acc[2][2];                     // [ot][pt]
    #pragma unroll
    for(int i=0;i<2;i++){
        #pragma unroll
        for(int j=0;j<2;j++) acc[i][j] = (f32x4){0.f,0.f,0.f,0.f};
    }

    // ---- pipeline: 2 K-chunks
    PW_STAGE_X(0, (&sX[0][0]));
    PW_STAGE_W(0);
    __syncthreads();                      // sX[0], sW(0) ready
    PW_STAGE_X(1, (&sX[1][0]));           // overlaps MFMA(0)
    PW_DOMFMA((&sX[0][0]));
    __syncthreads();                      // MFMA(0) done (sW free), sX[1] writes done
    PW_STAGE_W(1);
    __syncthreads();                      // sW(1) ready
    PW_DOMFMA((&sX[1][0]));

    // ---- epilogue: bias + channel-last bf16 write
    if(!swapD){
        #pragma unroll
        for(int ot=0;ot<2;ot++){
            int o0 = wo + (ot<<4) + (quad<<2);
            float4 bv = *(const float4*)&bias[o0];
            #pragma unroll
            for(int pt=0;pt<2;pt++){
                int px = pix0 + phb + (pt<<4) + m16;
                st4bf(&Cbf[((size_t)((b<<12) + px))*128 + o0],
                      acc[ot][pt][0]+bv.x, acc[ot][pt][1]+bv.y,
                      acc[ot][pt][2]+bv.z, acc[ot][pt][3]+bv.w);
            }
        }
    } else {
        #pragma unroll
        for(int ot=0;ot<2;ot++){
            int o = wo + (ot<<4) + m16;
            float bv = bias[o];
            #pragma unroll
            for(int pt=0;pt<2;pt++){
                #pragma unroll
                for(int r=0;r<4;r++){
                    int px = pix0 + phb + (pt<<4) + (quad<<2) + r;
                    Cbf[((size_t)((b<<12) + px))*128 + o] = f2bf(acc[ot][pt][r] + bv);
                }
            }
        }
    }
}

// ---------------- K5 v15: FUSED offmask + deform (r17 + LDS-overlap FIX).
// r17 bug: sWpm1 at uLDS+31024 overlapped sWpm0 [26928,31280) by 256 shorts ->
// staging even taps clobbered sWpm1 rows 0-1 concurrently with MFMA reads
// (absmax 0.0625 -> 0.15625, 0.3% under threshold). Fix: sWpm1 at uLDS+31280.
// Phase A footprint = 26928+4352+4352 = 35,632 shorts <= 35,840.
#define K5_META(t) do{ if(tid < 256){ \
    int px_ = tid >> 2, k_ = tid & 3; \
    int yq_ = y, xq_ = px_; \
    int kyy_ = (t)/3, kxx_ = (t)-kyy_*3; \
    float oxv_ = sOM[((t)<<6)+px_]; \
    float oyv_ = sOM[(((t)+9)<<6)+px_]; \
    float mv_  = sOM[(((t)+18)<<6)+px_]; \
    float pxf_ = (float)(yq_ + kyy_) + oxv_; \
    float pyf_ = (float)(xq_ + kxx_) + oyv_; \
    float fx_ = floorf(pxf_), fy_ = floorf(pyf_); \
    float qx0_ = fminf(fmaxf(fx_,0.f),65.f),  qx1_ = fminf(fmaxf(fx_+1.f,0.f),65.f); \
    float qy0_ = fminf(fmaxf(fy_,0.f),65.f),  qy1_ = fminf(fmaxf(fy_+1.f,0.f),65.f); \
    float pxc_ = fminf(fmaxf(pxf_,0.f),65.f), pyc_ = fminf(fmaxf(pyf_,0.f),65.f); \
    float dx0_ = 1.f+(qx0_-pxc_), dx1_ = 1.f-(qx1_-pxc_); \
    float dy0_ = 1.f+(qy0_-pyc_), dy1_ = 1.f-(qy1_-pyc_); \
    int ax0_=(int)qx0_, ax1_=(int)qx1_, ay0_=(int)qy0_, ay1_=(int)qy1_; \
    bool vx0_ = (ax0_>=1)&&(ax0_<=64), vx1_ = (ax1_>=1)&&(ax1_<=64); \
    bool vy0_ = (ay0_>=1)&&(ay0_<=64), vy1_ = (ay1_>=1)&&(ay1_<=64); \
    int  axs_ = (k_&1) ? ax1_ : ax0_; \
    int  ays_ = (k_==1||k_==2) ? ay1_ : ay0_; \
    bool vxs_ = (k_&1) ? vx1_ : vx0_; \
    bool vys_ = (k_==1||k_==2) ? vy1_ : vy0_; \
    float dxs_ = (k_&1) ? dx1_ : dx0_; \
    float dys_ = (k_==1||k_==2) ? dy1_ : dy0_; \
    bool v_ = vxs_ && vys_; \
    int base_ = v_ ? (((axs_-1)<<6)+(ays_-1)) : 0; \
    float g_ = v_ ? dxs_*dys_*mv_ : 0.f; \
    sM[tid] = make_uint2((unsigned)base_, __float_as_uint(g_)); \
} }while(0)

#define K5_GATHER(bufp) do{ \
    _Pragma("unroll") \
    for(int j_=0;j_<4;j_++){ \
        int px_ = pxb + (j_<<4); \
        uint2 e0_ = sM[(px_<<2)+0]; \
        uint2 e1_ = sM[(px_<<2)+1]; \
        uint2 e2_ = sM[(px_<<2)+2]; \
        uint2 e3_ = sM[(px_<<2)+3]; \
        float g0_ = __uint_as_float(e0_.y), g1_ = __uint_as_float(e1_.y); \
        float g2_ = __uint_as_float(e2_.y), g3_ = __uint_as_float(e3_.y); \
        uint2 c0_ = *(const uint2*)&cb[((size_t)e0_.x<<7) + cg4]; \
        uint2 c1_ = *(const uint2*)&cb[((size_t)e1_.x<<7) + cg4]; \
        uint2 c2_ = *(const uint2*)&cb[((size_t)e2_.x<<7) + cg4]; \
        uint2 c3_ = *(const uint2*)&cb[((size_t)e3_.x<<7) + cg4]; \
        float vx_ = g0_*bflo(c0_.x) + g1_*bflo(c1_.x) + g2_*bflo(c2_.x) + g3_*bflo(c3_.x); \
        float vy_ = g0_*bfhi(c0_.x) + g1_*bfhi(c1_.x) + g2_*bfhi(c2_.x) + g3_*bfhi(c3_.x); \
        float vz_ = g0_*bflo(c0_.y) + g1_*bflo(c1_.y) + g2_*bflo(c2_.y) + g3_*bflo(c3_.y); \
        float vw_ = g0_*bfhi(c0_.y) + g1_*bfhi(c1_.y) + g2_*bfhi(c2_.y) + g3_*bfhi(c3_.y); \
        st4bf(&(bufp)[px_*136 + cg4], vx_, vy_, vz_, vw_); \
    } }while(0)

#define K5_STAGE_W(t) do{ \
    const int4* wsrc_ = (const int4*)(Wbf + ((t)<<14)); \
    _Pragma("unroll") \
    for(int k_=0;k_<4;k_++){ int j_ = tid + (k_<<9); \
        *(int4*)&sW[(j_>>4)*136 + ((j_&15)<<3)] = wsrc_[j_]; } }while(0)

#define K5_DOMFMA(srcp) do{ \
    _Pragma("unroll") \
    for(int ks_=0; ks_<4; ks_++){ \
        int k0_ = ks_ << 5; \
        short8 bfr0 = *(const short8*)&(srcp)[(phb + m16)*136 + k0_ + (quad<<3)]; \
        short8 bfr1 = *(const short8*)&(srcp)[(phb + 16 + m16)*136 + k0_ + (quad<<3)]; \
        _Pragma("unroll") \
        for(int ot_=0;ot_<2;ot_++){ \
            short8 afr = *(const short8*)&sW[(wo + (ot_<<4) + m16)*136 + k0_ + (quad<<3)]; \
            acc[ot_][0] = __builtin_amdgcn_mfma_f32_16x16x32_bf16(afr, bfr0, acc[ot_][0], 0,0,0); \
            acc[ot_][1] = __builtin_amdgcn_mfma_f32_16x16x32_bf16(afr, bfr1, acc[ot_][1], 0,0,0); \
        } } }while(0)

__global__ __launch_bounds__(512, 2) void k_deform(const unsigned short* Cbf,
                                                   const unsigned short* Wpm, fp pb, fp mb,
                                                   const unsigned short* Wbf,
                                                   unsigned short* D, float* stats){
    __shared__ __align__(16) unsigned short uLDS[35840];     // 71,680 B union (A: win+Wpm / B: sW+sX+sM)
    __shared__ __align__(16) float sOM[27*64];               //  6,912 B OM row (persists A->B)
    int b = blockIdx.x & 7;
    int y = blockIdx.x >> 3;             // output row
    int pix0 = y << 6;
    int tid = threadIdx.x;               // 0..511
    int lane = tid & 63, wave = tid >> 6;
    int m16 = lane & 15, quad = lane >> 4;
    int wo  = (wave & 3) << 5;           // phase B: o-range
    int phb = (wave >> 2) << 5;          // phase B: px-half
    int cg4 = (tid & 31) << 2;           // channel group (4 ch)
    int pxb = tid >> 5;                  // base px 0..15
    const unsigned short* cb = Cbf + ((size_t)b<<12)*128;

    // ---- probe (shared by both phases)
    short8 ap = {0,0,0,0,0,0,0,0}, bpr = {0,0,0,0,0,0,0,0};
    if(quad == 0){
        ap[0]  = (short)f2bf((float)m16);
        bpr[0] = (short)f2bf((float)(m16+100));
    }
    f32x4 dp = {0.f,0.f,0.f,0.f};
    dp = __builtin_amdgcn_mfma_f32_16x16x32_bf16(ap, bpr, dp, 0,0,0);
    bool p1 = true;
    #pragma unroll
    for(int r=0;r<4;r++){
        float expP1 = (float)(quad*4+r) * (float)(m16+100);
        p1 = p1 && (fabsf(dp[r]-expP1) < 0.5f);
    }
    bool swapD = (__ballot(p1) != 0xFFFFFFFFFFFFFFFFull);

    // ================= PHASE A: offset+mask conv -> sOM =================
    {
        unsigned short* sWin  = uLDS;            // 26,928 shorts (3x66x136): [0, 26928)
        unsigned short* sWpm0 = uLDS + 26928;    //  4,352 shorts: [26928, 31280)
        unsigned short* sWpm1 = uLDS + 31280;    //  4,352 shorts: [31280, 35632)  (FIX: was 31024)
        int qt = wave & 1, pt = wave >> 1;       // 2 q-tiles x 4 px-tiles
        // prologue: issue Wpm(0) (512 int4 = full tap), stage window, write sWpm0
        int4 w0_ = ((const int4*)Wpm)[tid];
        for(int i = tid; i < 3168; i += 512){    // 198 pos x 16 groups of 8 ch
            int pos = i >> 4, g = i & 15;
            int r = pos / 66, col = pos - r*66;
            int yy = y + r - 1, xx = col - 1;
            int4 v = make_int4(0,0,0,0);
            if(yy>=0 && yy<64 && xx>=0 && xx<64)
                v = *(const int4*)&cb[(size_t)((yy<<6)+xx)*128 + (g<<3)];
            *(int4*)&sWin[pos*136 + (g<<3)] = v;
        }
        *(int4*)&sWpm0[(tid>>4)*136 + ((tid&15)<<3)] = w0_;
        __syncthreads();

        f32x4 accA = {0.f,0.f,0.f,0.f};
        for(int n=0;n<9;n++){
            int4 wn_;
            if(n<8) wn_ = ((const int4*)(Wpm + ((n+1)<<12)))[tid];  // issue early
            int ky = n/3, kx = n - ky*3;
            const unsigned short* base = &sWin[(ky*66 + (pt<<4) + kx)*136];
            const unsigned short* swp = (n&1) ? sWpm1 : sWpm0;
            #pragma unroll
            for(int ks=0; ks<4; ks++){
                int k0 = ks << 5;
                short8 bfr = *(const short8*)&base[m16*136 + k0 + (quad<<3)];
                short8 afr = *(const short8*)&swp[((qt<<4) + m16)*136 + k0 + (quad<<3)];
                accA = __builtin_amdgcn_mfma_f32_16x16x32_bf16(afr, bfr, accA, 0,0,0);
            }
            if(n<8){
                unsigned short* swn = ((n+1)&1) ? sWpm1 : sWpm0;
                *(int4*)&swn[(tid>>4)*136 + ((tid&15)<<3)] = wn_;
            }
            __syncthreads();
        }
        if(!swapD){
            int pxl = (pt<<4) + m16;
            #pragma unroll
            for(int r=0;r<4;r++){
                int q = (qt<<4) + (quad<<2) + r;
                if(q < 27){
                    float v = accA[r] + ((q<18) ? pb[q] : mb[q-18]);
                    if(q>=18) v = 1.f/(1.f+expf(-v));
                    sOM[(q<<6) + pxl] = v;
                }
            }
        } else {
            int q = (qt<<4) + m16;
            if(q < 27){
                float bias2 = (q<18) ? pb[q] : mb[q-18];
                #pragma unroll
                for(int r=0;r<4;r++){
                    int pxl = (pt<<4) + (quad<<2) + r;
                    float v = accA[r] + bias2;
                    if(q>=18) v = 1.f/(1.f+expf(-v));
                    sOM[(q<<6) + pxl] = v;
                }
            }
        }
        __syncthreads();                  // sOM complete; uLDS free for phase B
    }

    // ================= PHASE B: deformable sampling + MFMA (verified v13) =================
    unsigned short* sW = uLDS;                   // 17,408 shorts [o][c]
    unsigned short* sXb = uLDS + 17408;          // 2 x 8,704 shorts dbuf [px][c]
    uint2* sM = (uint2*)(uLDS + 34816);          // 256 entries

    f32x4 acc[2][2];                     // [ot][pt]
    #pragma unroll
    for(int i=0;i<2;i++){
        #pragma unroll
        for(int j=0;j<2;j++) acc[i][j] = (f32x4){0.f,0.f,0.f,0.f};
    }

    // ---- prologue
    K5_META(0);
    __syncthreads();                      // sM = meta(0)
    K5_GATHER((sXb));                     // gather(0) using meta(0)
    K5_STAGE_W(0);
    __syncthreads();                      // sX[0], sW(0) ready; sM reads done
    K5_META(1);
    __syncthreads();                      // sM = meta(1)

    for(int n=0;n<9;n++){
        if(n<8) K5_GATHER((sXb + (((n+1)&1)*8704)));  // meta(n+1); overlaps MFMA(n)
        K5_DOMFMA((sXb + ((n&1)*8704)));              // operands from LDS (sW, sX)
        __syncthreads();                              // sW/sM reads + sX writes done
        if(n<8){
            K5_STAGE_W(n+1);                          // sW <- W(n+1), transient regs
            if(n<7) K5_META(n+2);                     // sM <- meta(n+2)
            __syncthreads();                          // sW, sM ready for next iter
        }
    }

    // epilogue: bf16 D writes + per-channel sum/sumsq reduction (stats from f32 acc)
    float* sdq = (float*)uLDS;            // [0..127]=sum, [128..255]=sumsq
    if(tid < 256) sdq[tid] = 0.f;
    __syncthreads();
    if(!swapD){
        #pragma unroll
        for(int ot=0;ot<2;ot++){
            #pragma unroll
            for(int pt=0;pt<2;pt++){
                int px = pix0 + phb + (pt<<4) + m16;
                #pragma unroll
                for(int r=0;r<4;r++){
                    int o = wo + (ot<<4) + (quad<<2) + r;
                    D[((size_t)(b*128+o)<<12) + px] = f2bf(acc[ot][pt][r]);
                }
            }
        }
        #pragma unroll
        for(int ot=0;ot<2;ot++){
            #pragma unroll
            for(int r=0;r<4;r++){
                float s  = acc[ot][0][r] + acc[ot][1][r];
                float s2 = acc[ot][0][r]*acc[ot][0][r] + acc[ot][1][r]*acc[ot][1][r];
                #pragma unroll
                for(int msk=1; msk<16; msk<<=1){
                    s  += __shfl_xor(s, msk, 64);
                    s2 += __shfl_xor(s2, msk, 64);
                }
                if(m16 == 0){
                    int o = wo + (ot<<4) + (quad<<2) + r;
                    atomicAdd(&sdq[o], s);
                    atomicAdd(&sdq[128+o], s2);
                }
            }
        }
    } else {
        #pragma unroll
        for(int ot=0;ot<2;ot++){
            #pragma unroll
            for(int pt=0;pt<2;pt++){
                int o = wo + (ot<<4) + m16;
                #pragma unroll
                for(int r=0;r<4;r++){
                    int px = pix0 + phb + (pt<<4) + (quad<<2) + r;
                    D[((size_t)(b*128+o)<<12) + px] = f2bf(acc[ot][pt][r]);
                }
            }
        }
        #pragma unroll
        for(int ot=0;ot<2;ot++){
            float s = 0.f, s2 = 0.f;
            #pragma unroll
            for(int pt=0;pt<2;pt++){
                #pragma unroll
                for(int r=0;r<4;r++){
                    float v = acc[ot][pt][r];
                    s += v; s2 += v*v;
                }
            }
            #pragma unroll
            for(int msk=16; msk<64; msk<<=1){
                s  += __shfl_xor(s, msk, 64);
                s2 += __shfl_xor(s2, msk, 64);
            }
            if(quad == 0){
                int o = wo + (ot<<4) + m16;
                atomicAdd(&sdq[o], s);
                atomicAdd(&sdq[128+o], s2);
            }
        }
    }
    __syncthreads();
    if(tid < 128){
        atomicAdd(&stats[tid],     sdq[tid]);
        atomicAdd(&stats[128+tid], sdq[128+tid]);
    }
}

// ---------------- K7 v3: fused BN1+GELU + depthwise128 (bf16 D in, bf16 Hs out)
__global__ __launch_bounds__(256) void k_bngelu_dw128(const unsigned short* Dsrc, float* stats,
                                                      fp g1, fp b1, fp w, fp bias, unsigned short* Hs){
    __shared__ float sG[66*68 + 4];
    __shared__ float sd[256], sq[256];
    int bid = blockIdx.x;
    int c = bid & 127, b = bid >> 7;
    int tid = threadIdx.x;
    float mean1 = stats[c] * (1.f/32768.f);
    float var1  = stats[128+c] * (1.f/32768.f) - mean1*mean1;
    float rstd1 = rsqrtf(var1 + 1e-5f);
    float sc = rstd1 * g1[c];
    float sb = b1[c] - mean1*sc;
    for(int j = tid; j < 264; j += 256){
        int idx;
        if(j < 66)       idx = j;
        else if(j < 132) idx = 65*68 + (j-66);
        else if(j < 196) idx = (j-132+1)*68;
        else if(j < 260) idx = (j-196+1)*68 + 65;
        else             idx = 66*68 + (j-260);
        sG[idx] = 0.f;
    }
    const unsigned short* dplane = Dsrc + ((size_t)(b*128+c)<<12);
    for(int j = tid; j < 1024; j += 256){
        int yy = j >> 4, x4 = (j & 15) << 2;
        uint2 v = *(const uint2*)&dplane[(yy<<6) + x4];
        float g0 = bflo(v.x)*sc+sb, g1v = bfhi(v.x)*sc+sb;
        float g2 = bflo(v.y)*sc+sb, g3 = bfhi(v.y)*sc+sb;
        float* d = &sG[(yy+1)*68 + x4 + 1];
        d[0] = 0.5f*g0*(1.0f + erff(g0*0.70710678118654752f));
        d[1] = 0.5f*g1v*(1.0f + erff(g1v*0.70710678118654752f));
        d[2] = 0.5f*g2*(1.0f + erff(g2*0.70710678118654752f));
        d[3] = 0.5f*g3*(1.0f + erff(g3*0.70710678118654752f));
    }
    __syncthreads();
    float w0=w[c*9+0], w1=w[c*9+1], w2=w[c*9+2];
    float w3=w[c*9+3], w4=w[c*9+4], w5=w[c*9+5];
    float w6=w[c*9+6], w7=w[c*9+7], w8=w[c*9+8];
    float bv = bias[c];
    unsigned short* dst = Hs + ((size_t)(b*128+c)<<12);
    float s = 0.f, s2 = 0.f;
    for(int j = tid; j < 1024; j += 256){
        int y = j >> 4, x0 = (j & 15) << 2;
        float a0=bv, a1=bv, a2=bv, a3=bv;
        #pragma unroll
        for(int ky=0; ky<3; ky++){
            const float* rr = &sG[(y+ky)*68 + x0];
            float4 u0 = *(const float4*)&rr[0];
            float2 u1 = *(const float2*)&rr[4];
            float wA = (ky==0)?w0:((ky==1)?w3:w6);
            float wB = (ky==0)?w1:((ky==1)?w4:w7);
            float wC = (ky==0)?w2:((ky==1)?w5:w8);
            a0 += wA*u0.x + wB*u0.y + wC*u0.z;
            a1 += wA*u0.y + wB*u0.z + wC*u0.w;
            a2 += wA*u0.z + wB*u0.w + wC*u1.x;
            a3 += wA*u0.w + wB*u1.x + wC*u1.y;
        }
        st4bf(&dst[(y<<6)+x0], a0,a1,a2,a3);
        s += a0+a1+a2+a3;
        s2 += a0*a0 + a1*a1 + a2*a2 + a3*a3;
    }
    sd[tid]=s; sq[tid]=s2; __syncthreads();
    for(int off=128; off>0; off>>=1){
        if(tid<off){ sd[tid]+=sd[tid+off]; sq[tid]+=sq[tid+off]; }
        __syncthreads();
    }
    if(tid==0){
        atomicAdd(&stats[256+c], sd[0]);
        atomicAdd(&stats[384+c], sq[0]);
    }
}

// ---------------- BN2 + ReLU -> f32 out (bf16 Hs in)
__global__ __launch_bounds__(256) void k_bn_relu_out(const unsigned short* Hs, const float* stats,
                                                     fp g, fp bb, float* out){
    int idx = blockIdx.x*256+threadIdx.x;       // 1,048,576 groups of 4 px
    int c = (idx>>10)&127;
    float mean2 = stats[256+c] * (1.f/32768.f);
    float var2  = stats[384+c] * (1.f/32768.f) - mean2*mean2;
    float rs = rsqrtf(var2 + 1e-5f) * g[c];
    float sb = bb[c] - mean2*rs;
    uint2 v = ((const uint2*)Hs)[idx];
    float4 o;
    o.x = fmaxf(bflo(v.x)*rs+sb, 0.f);
    o.y = fmaxf(bfhi(v.x)*rs+sb, 0.f);
    o.z = fmaxf(bflo(v.y)*rs+sb, 0.f);
    o.w = fmaxf(bfhi(v.y)*rs+sb, 0.f);
    ((float4*)out)[idx] = o;
}

extern "C" void kernel_launch(void* const* d_in, const int* in_sizes, int n_in,
                              void* d_out, int out_size, void* d_ws, size_t ws_size,
                              hipStream_t stream){
    fp x1   = (fp)d_in[0];
    fp x2   = (fp)d_in[1];
    fp dw_w = (fp)d_in[2];  fp dw_b = (fp)d_in[3];
    fp pw_w = (fp)d_in[4];  fp pw_b = (fp)d_in[5];
    fp p_w  = (fp)d_in[6];  fp p_b  = (fp)d_in[7];
    fp m_w  = (fp)d_in[8];  fp m_b  = (fp)d_in[9];
    fp dcn_w= (fp)d_in[10];
    fp bn1g = (fp)d_in[11]; fp bn1b = (fp)d_in[12];
    fp dw2w = (fp)d_in[13]; fp dw2b = (fp)d_in[14];
    fp bn2g = (fp)d_in[15]; fp bn2b = (fp)d_in[16];

    float* ws  = (float*)d_ws;
    unsigned short* Bo  = (unsigned short*)ws;               // (8,256,4096) bf16 ; D overlays after k_pw
    unsigned short* Cbf = (unsigned short*)(ws + 8388608);   // (8,4096,128) bf16 ; Hs overlays after k_deform
    unsigned short* Hs  = (unsigned short*)(ws + 8388608);   // (8,128,4096) bf16
    unsigned short* Wbf = (unsigned short*)(ws + 13467648);
    unsigned short* Wpm = (unsigned short*)(ws + 13541376);
    float* stats = ws + 13559808;       // 512 f
    unsigned short* Wpwbf = (unsigned short*)(ws + 13560320);  // 32,768 bf16
    unsigned short* D   = Bo;           // Bo dead after k_pw
    float* out = (float*)d_out;

    hipMemsetAsync(stats, 0, 512*sizeof(float), stream);
    k_prep         <<<208,   256, 0, stream>>>(dcn_w, p_w, m_w, pw_w, Wbf, Wpm, Wpwbf);
    k_updw256      <<<2048,  256, 0, stream>>>(x1, x2, dw_w, dw_b, Bo);
    k_pw           <<<512,   512, 0, stream>>>(Bo, Wpwbf, pw_b, Cbf);
    k_deform       <<<512,   512, 0, stream>>>(Cbf, Wpm, p_b, m_b, Wbf, D, stats);  // fused offmask+deform
    k_bngelu_dw128 <<<1024,  256, 0, stream>>>(D, stats, bn1g, bn1b, dw2w, dw2b, Hs);
    k_bn_relu_out  <<<4096,  256, 0, stream>>>(Hs, stats, bn2g, bn2b, out);
}

// Round 19
// 190.565 us; speedup vs baseline: 1.4213x; 1.0095x over previous
//
#include <hip/hip_runtime.h>
#include <math.h>

// Problem constants: B=8, spatial 64x64 (HW=4096), C_mid=256, C=128, N=9 taps.
typedef const float* fp;
typedef __attribute__((ext_vector_type(8))) short short8;   // 8 bf16 = 4 VGPRs (MFMA A/B frag)
typedef __attribute__((ext_vector_type(4))) float f32x4;    // MFMA C/D frag

__device__ __forceinline__ unsigned short f2bf(float f){    // RTNE float->bf16 (scalar/cold paths)
    unsigned u = __float_as_uint(f);
    u += 0x7fff + ((u >> 16) & 1);
    return (unsigned short)(u >> 16);
}
__device__ __forceinline__ float bflo(unsigned u){ return __uint_as_float(u << 16); }
__device__ __forceinline__ float bfhi(unsigned u){ return __uint_as_float(u & 0xffff0000u); }
// HW packed convert: 1 instr for 2 values (gfx950 v_cvt_pk_bf16_f32; no builtin — inline asm)
__device__ __forceinline__ unsigned cvtpk(float a, float b){
    unsigned r; asm("v_cvt_pk_bf16_f32 %0, %1, %2" : "=v"(r) : "v"(a), "v"(b)); return r;
}
__device__ __forceinline__ void st4bf(void* p, float a, float b, float c, float d){
    uint2 v; v.x = cvtpk(a,b); v.y = cvtpk(c,d);
    *(uint2*)p = v;
}

// ---------------- K1 v4: fused [k_prep fold-in] + upsample+concat+depthwise256 -> Bo bf16.
// x1 path: stage whole 32x32 plane (4 KB) in LDS via 256 coalesced float4 loads
// (was 16,384 scalar global loads/block); bilinear reads LDS. First 208 blocks
// also run the weight-prep body (outputs consumed by k_pw/k_deform, next launches).
__global__ __launch_bounds__(256) void k_updw256(fp x1, fp x2, fp w, fp bias, unsigned short* Bo,
                                                 fp dcn_w, fp pw, fp mw, fp pww,
                                                 unsigned short* Wbf, unsigned short* Wpm,
                                                 unsigned short* Wpwbf){
    __shared__ float sA[66*68 + 4];
    __shared__ float sX1[1024];
    int bid = blockIdx.x;
    int c = bid & 255, b = bid >> 8;
    int tid = threadIdx.x;
    // ---- folded k_prep (coalesced; first 208 blocks only)
    if(bid < 208){
        int i = bid*256 + tid;
        if(i < 16384){                              // dcn: (o,ci) -> 9 taps
            int o = i >> 7, ci = i & 127;
            const float* s = dcn_w + o*1152 + ci*9;
            #pragma unroll
            for(int n=0;n<9;n++) Wbf[(n<<14) + (o<<7) + ci] = f2bf(s[n]);
        } else if(i < 20480){                       // pw/mw: (q,ci) -> 9 taps, q<32
            int j = i - 16384;
            int q = j >> 7, ci = j & 127;
            if(q < 18){
                const float* s = pw + q*1152 + ci*9;
                #pragma unroll
                for(int n=0;n<9;n++) Wpm[(n<<12) + (q<<7) + ci] = f2bf(s[n]);
            } else if(q < 27){
                const float* s = mw + (q-18)*1152 + ci*9;
                #pragma unroll
                for(int n=0;n<9;n++) Wpm[(n<<12) + (q<<7) + ci] = f2bf(s[n]);
            } else {
                #pragma unroll
                for(int n=0;n<9;n++) Wpm[(n<<12) + (q<<7) + ci] = 0;
            }
        } else if(i < 53248){
            int j = i - 20480;                      // 32768: pointwise weights [o][c] bf16
            Wpwbf[j] = f2bf(pww[j]);
        }
    }
    // ---- halo zero
    for(int j = tid; j < 264; j += 256){
        int idx;
        if(j < 66)       idx = j;
        else if(j < 132) idx = 65*68 + (j-66);
        else if(j < 196) idx = (j-132+1)*68;
        else if(j < 260) idx = (j-196+1)*68 + 65;
        else             idx = 66*68 + (j-260);
        sA[idx] = 0.f;
    }
    if(c < 128){
        const float* src = x2 + ((size_t)(b*128+c)<<12);
        for(int j = tid; j < 1024; j += 256){
            int yy = j >> 4, x4 = (j & 15) << 2;
            float4 v = *(const float4*)&src[(yy<<6) + x4];
            float* d = &sA[(yy+1)*68 + x4 + 1];
            d[0]=v.x; d[1]=v.y; d[2]=v.z; d[3]=v.w;
        }
    } else {
        int cc = c - 128;
        fp src = x1 + ((b*128+cc)<<10);
        ((float4*)sX1)[tid] = ((const float4*)src)[tid];   // whole 32x32 plane, coalesced
        __syncthreads();                                   // block-uniform path (c uniform/block)
        const float s = 31.0f/63.0f;
        for(int j = tid; j < 4096; j += 256){
            int yy = j >> 6, xx = j & 63;
            float fy = yy*s, fx = xx*s;
            int iy = (int)fy; if (iy > 30) iy = 30;
            int ix = (int)fx; if (ix > 30) ix = 30;
            float ty = fy - (float)iy, tx = fx - (float)ix;
            float v00 = sX1[iy*32+ix],     v01 = sX1[iy*32+ix+1];
            float v10 = sX1[(iy+1)*32+ix], v11 = sX1[(iy+1)*32+ix+1];
            sA[(yy+1)*68 + xx + 1] =
                (v00*(1.f-ty)+v10*ty)*(1.f-tx) + (v01*(1.f-ty)+v11*ty)*tx;
        }
    }
    __syncthreads();
    float w0=w[c*9+0], w1=w[c*9+1], w2=w[c*9+2];
    float w3=w[c*9+3], w4=w[c*9+4], w5=w[c*9+5];
    float w6=w[c*9+6], w7=w[c*9+7], w8=w[c*9+8];
    float bv = bias[c];
    unsigned short* dst = Bo + ((size_t)(b*256+c)<<12);
    for(int j = tid; j < 1024; j += 256){
        int y = j >> 4, x0 = (j & 15) << 2;
        float a0=bv, a1=bv, a2=bv, a3=bv;
        #pragma unroll
        for(int ky=0; ky<3; ky++){
            const float* rr = &sA[(y+ky)*68 + x0];
            float4 u0 = *(const float4*)&rr[0];
            float2 u1 = *(const float2*)&rr[4];
            float wA = (ky==0)?w0:((ky==1)?w3:w6);
            float wB = (ky==0)?w1:((ky==1)?w4:w7);
            float wC = (ky==0)?w2:((ky==1)?w5:w8);
            a0 += wA*u0.x + wB*u0.y + wC*u0.z;
            a1 += wA*u0.y + wB*u0.z + wC*u0.w;
            a2 += wA*u0.z + wB*u0.w + wC*u1.x;
            a3 += wA*u0.w + wB*u1.x + wC*u1.y;
        }
        st4bf(&dst[(y<<6)+x0], a0,a1,a2,a3);
    }
}

// ---------------- K3 v6: pointwise 256->128 + bias via bf16 MFMA; Bo bf16 in, Cbf bf16 out.
#define PW_STAGE_X(kc, bufp) do{ \
    _Pragma("unroll") \
    for(int k_=0;k_<4;k_++){ \
        int j_ = tid + (k_<<9); \
        int cc_ = j_ >> 4, p4_ = (j_ & 15) << 2; \
        int c_ = ((kc)<<7) + cc_; \
        uint2 v_ = *(const uint2*)&Bo[((size_t)((b<<8)+c_)<<12) + pix0 + p4_]; \
        (bufp)[(p4_+0)*136 + cc_] = (unsigned short)(v_.x & 0xffffu); \
        (bufp)[(p4_+1)*136 + cc_] = (unsigned short)(v_.x >> 16); \
        (bufp)[(p4_+2)*136 + cc_] = (unsigned short)(v_.y & 0xffffu); \
        (bufp)[(p4_+3)*136 + cc_] = (unsigned short)(v_.y >> 16); \
    } }while(0)

#define PW_STAGE_W(kc) do{ \
    _Pragma("unroll") \
    for(int k_=0;k_<4;k_++){ \
        int j_ = tid + (k_<<9); \
        int o_ = j_ >> 4, cg_ = j_ & 15; \
        *(int4*)&sW[o_*136 + (cg_<<3)] = \
            *(const int4*)&Wpwbf[o_*256 + ((kc)<<7) + (cg_<<3)]; \
    } }while(0)

#define PW_DOMFMA(srcp) do{ \
    _Pragma("unroll") \
    for(int ks_=0; ks_<4; ks_++){ \
        int k0_ = ks_ << 5; \
        short8 bfr0 = *(const short8*)&(srcp)[(phb + m16)*136 + k0_ + (quad<<3)]; \
        short8 bfr1 = *(const short8*)&(srcp)[(phb + 16 + m16)*136 + k0_ + (quad<<3)]; \
        _Pragma("unroll") \
        for(int ot_=0;ot_<2;ot_++){ \
            short8 afr = *(const short8*)&sW[(wo + (ot_<<4) + m16)*136 + k0_ + (quad<<3)]; \
            acc[ot_][0] = __builtin_amdgcn_mfma_f32_16x16x32_bf16(afr, bfr0, acc[ot_][0], 0,0,0); \
            acc[ot_][1] = __builtin_amdgcn_mfma_f32_16x16x32_bf16(afr, bfr1, acc[ot_][1], 0,0,0); \
        } } }while(0)

__global__ __launch_bounds__(512, 2) void k_pw(const unsigned short* Bo, const unsigned short* Wpwbf,
                                               fp bias, unsigned short* Cbf){
    __shared__ __align__(16) unsigned short sW[128*136];     // 34,816 B [o][cc]
    __shared__ __align__(16) unsigned short sX[2][64*136];   // 34,816 B dbuf [px][cc]
    int b = blockIdx.x & 7;
    int pix0 = (blockIdx.x >> 3) << 6;   // 64 tiles x 8 b
    int tid = threadIdx.x;               // 0..511
    int lane = tid & 63, wave = tid >> 6;
    int m16 = lane & 15, quad = lane >> 4;
    int wo  = (wave & 3) << 5;           // o-range: 4 groups of 32
    int phb = (wave >> 2) << 5;          // px-half: 0 / 32

    // ---- probe
    short8 ap = {0,0,0,0,0,0,0,0}, bpr = {0,0,0,0,0,0,0,0};
    if(quad == 0){
        ap[0]  = (short)f2bf((float)m16);
        bpr[0] = (short)f2bf((float)(m16+100));
    }
    f32x4 dp = {0.f,0.f,0.f,0.f};
    dp = __builtin_amdgcn_mfma_f32_16x16x32_bf16(ap, bpr, dp, 0,0,0);
    bool p1 = true;
    #pragma unroll
    for(int r=0;r<4;r++){
        float expP1 = (float)(quad*4+r) * (float)(m16+100);
        p1 = p1 && (fabsf(dp[r]-expP1) < 0.5f);
    }
    bool swapD = (__ballot(p1) != 0xFFFFFFFFFFFFFFFFull);

    f32x4 acc[2][2];                     // [ot][pt]
    #pragma unroll
    for(int i=0;i<2;i++){
        #pragma unroll
        for(int j=0;j<2;j++) acc[i][j] = (f32x4){0.f,0.f,0.f,0.f};
    }

    // ---- pipeline: 2 K-chunks
    PW_STAGE_X(0, (&sX[0][0]));
    PW_STAGE_W(0);
    __syncthreads();                      // sX[0], sW(0) ready
    PW_STAGE_X(1, (&sX[1][0]));           // overlaps MFMA(0)
    PW_DOMFMA((&sX[0][0]));
    __syncthreads();                      // MFMA(0) done (sW free), sX[1] writes done
    PW_STAGE_W(1);
    __syncthreads();                      // sW(1) ready
    PW_DOMFMA((&sX[1][0]));

    // ---- epilogue: bias + channel-last bf16 write
    if(!swapD){
        #pragma unroll
        for(int ot=0;ot<2;ot++){
            int o0 = wo + (ot<<4) + (quad<<2);
            float4 bv = *(const float4*)&bias[o0];
            #pragma unroll
            for(int pt=0;pt<2;pt++){
                int px = pix0 + phb + (pt<<4) + m16;
                st4bf(&Cbf[((size_t)((b<<12) + px))*128 + o0],
                      acc[ot][pt][0]+bv.x, acc[ot][pt][1]+bv.y,
                      acc[ot][pt][2]+bv.z, acc[ot][pt][3]+bv.w);
            }
        }
    } else {
        #pragma unroll
        for(int ot=0;ot<2;ot++){
            int o = wo + (ot<<4) + m16;
            float bv = bias[o];
            #pragma unroll
            for(int pt=0;pt<2;pt++){
                #pragma unroll
                for(int r=0;r<4;r++){
                    int px = pix0 + phb + (pt<<4) + (quad<<2) + r;
                    Cbf[((size_t)((b<<12) + px))*128 + o] = f2bf(acc[ot][pt][r] + bv);
                }
            }
        }
    }
}

// ---------------- K5 v15: FUSED offmask + deform (verified r18; sWpm1 at +31280).
#define K5_META(t) do{ if(tid < 256){ \
    int px_ = tid >> 2, k_ = tid & 3; \
    int yq_ = y, xq_ = px_; \
    int kyy_ = (t)/3, kxx_ = (t)-kyy_*3; \
    float oxv_ = sOM[((t)<<6)+px_]; \
    float oyv_ = sOM[(((t)+9)<<6)+px_]; \
    float mv_  = sOM[(((t)+18)<<6)+px_]; \
    float pxf_ = (float)(yq_ + kyy_) + oxv_; \
    float pyf_ = (float)(xq_ + kxx_) + oyv_; \
    float fx_ = floorf(pxf_), fy_ = floorf(pyf_); \
    float qx0_ = fminf(fmaxf(fx_,0.f),65.f),  qx1_ = fminf(fmaxf(fx_+1.f,0.f),65.f); \
    float qy0_ = fminf(fmaxf(fy_,0.f),65.f),  qy1_ = fminf(fmaxf(fy_+1.f,0.f),65.f); \
    float pxc_ = fminf(fmaxf(pxf_,0.f),65.f), pyc_ = fminf(fmaxf(pyf_,0.f),65.f); \
    float dx0_ = 1.f+(qx0_-pxc_), dx1_ = 1.f-(qx1_-pxc_); \
    float dy0_ = 1.f+(qy0_-pyc_), dy1_ = 1.f-(qy1_-pyc_); \
    int ax0_=(int)qx0_, ax1_=(int)qx1_, ay0_=(int)qy0_, ay1_=(int)qy1_; \
    bool vx0_ = (ax0_>=1)&&(ax0_<=64), vx1_ = (ax1_>=1)&&(ax1_<=64); \
    bool vy0_ = (ay0_>=1)&&(ay0_<=64), vy1_ = (ay1_>=1)&&(ay1_<=64); \
    int  axs_ = (k_&1) ? ax1_ : ax0_; \
    int  ays_ = (k_==1||k_==2) ? ay1_ : ay0_; \
    bool vxs_ = (k_&1) ? vx1_ : vx0_; \
    bool vys_ = (k_==1||k_==2) ? vy1_ : vy0_; \
    float dxs_ = (k_&1) ? dx1_ : dx0_; \
    float dys_ = (k_==1||k_==2) ? dy1_ : dy0_; \
    bool v_ = vxs_ && vys_; \
    int base_ = v_ ? (((axs_-1)<<6)+(ays_-1)) : 0; \
    float g_ = v_ ? dxs_*dys_*mv_ : 0.f; \
    sM[tid] = make_uint2((unsigned)base_, __float_as_uint(g_)); \
} }while(0)

#define K5_GATHER(bufp) do{ \
    _Pragma("unroll") \
    for(int j_=0;j_<4;j_++){ \
        int px_ = pxb + (j_<<4); \
        uint2 e0_ = sM[(px_<<2)+0]; \
        uint2 e1_ = sM[(px_<<2)+1]; \
        uint2 e2_ = sM[(px_<<2)+2]; \
        uint2 e3_ = sM[(px_<<2)+3]; \
        float g0_ = __uint_as_float(e0_.y), g1_ = __uint_as_float(e1_.y); \
        float g2_ = __uint_as_float(e2_.y), g3_ = __uint_as_float(e3_.y); \
        uint2 c0_ = *(const uint2*)&cb[((size_t)e0_.x<<7) + cg4]; \
        uint2 c1_ = *(const uint2*)&cb[((size_t)e1_.x<<7) + cg4]; \
        uint2 c2_ = *(const uint2*)&cb[((size_t)e2_.x<<7) + cg4]; \
        uint2 c3_ = *(const uint2*)&cb[((size_t)e3_.x<<7) + cg4]; \
        float vx_ = g0_*bflo(c0_.x) + g1_*bflo(c1_.x) + g2_*bflo(c2_.x) + g3_*bflo(c3_.x); \
        float vy_ = g0_*bfhi(c0_.x) + g1_*bfhi(c1_.x) + g2_*bfhi(c2_.x) + g3_*bfhi(c3_.x); \
        float vz_ = g0_*bflo(c0_.y) + g1_*bflo(c1_.y) + g2_*bflo(c2_.y) + g3_*bflo(c3_.y); \
        float vw_ = g0_*bfhi(c0_.y) + g1_*bfhi(c1_.y) + g2_*bfhi(c2_.y) + g3_*bfhi(c3_.y); \
        st4bf(&(bufp)[px_*136 + cg4], vx_, vy_, vz_, vw_); \
    } }while(0)

#define K5_STAGE_W(t) do{ \
    const int4* wsrc_ = (const int4*)(Wbf + ((t)<<14)); \
    _Pragma("unroll") \
    for(int k_=0;k_<4;k_++){ int j_ = tid + (k_<<9); \
        *(int4*)&sW[(j_>>4)*136 + ((j_&15)<<3)] = wsrc_[j_]; } }while(0)

#define K5_DOMFMA(srcp) do{ \
    _Pragma("unroll") \
    for(int ks_=0; ks_<4; ks_++){ \
        int k0_ = ks_ << 5; \
        short8 bfr0 = *(const short8*)&(srcp)[(phb + m16)*136 + k0_ + (quad<<3)]; \
        short8 bfr1 = *(const short8*)&(srcp)[(phb + 16 + m16)*136 + k0_ + (quad<<3)]; \
        _Pragma("unroll") \
        for(int ot_=0;ot_<2;ot_++){ \
            short8 afr = *(const short8*)&sW[(wo + (ot_<<4) + m16)*136 + k0_ + (quad<<3)]; \
            acc[ot_][0] = __builtin_amdgcn_mfma_f32_16x16x32_bf16(afr, bfr0, acc[ot_][0], 0,0,0); \
            acc[ot_][1] = __builtin_amdgcn_mfma_f32_16x16x32_bf16(afr, bfr1, acc[ot_][1], 0,0,0); \
        } } }while(0)

__global__ __launch_bounds__(512, 2) void k_deform(const unsigned short* Cbf,
                                                   const unsigned short* Wpm, fp pb, fp mb,
                                                   const unsigned short* Wbf,
                                                   unsigned short* D, float* stats){
    __shared__ __align__(16) unsigned short uLDS[35840];     // 71,680 B union (A: win+Wpm / B: sW+sX+sM)
    __shared__ __align__(16) float sOM[27*64];               //  6,912 B OM row (persists A->B)
    int b = blockIdx.x & 7;
    int y = blockIdx.x >> 3;             // output row
    int pix0 = y << 6;
    int tid = threadIdx.x;               // 0..511
    int lane = tid & 63, wave = tid >> 6;
    int m16 = lane & 15, quad = lane >> 4;
    int wo  = (wave & 3) << 5;           // phase B: o-range
    int phb = (wave >> 2) << 5;          // phase B: px-half
    int cg4 = (tid & 31) << 2;           // channel group (4 ch)
    int pxb = tid >> 5;                  // base px 0..15
    const unsigned short* cb = Cbf + ((size_t)b<<12)*128;

    // ---- probe (shared by both phases)
    short8 ap = {0,0,0,0,0,0,0,0}, bpr = {0,0,0,0,0,0,0,0};
    if(quad == 0){
        ap[0]  = (short)f2bf((float)m16);
        bpr[0] = (short)f2bf((float)(m16+100));
    }
    f32x4 dp = {0.f,0.f,0.f,0.f};
    dp = __builtin_amdgcn_mfma_f32_16x16x32_bf16(ap, bpr, dp, 0,0,0);
    bool p1 = true;
    #pragma unroll
    for(int r=0;r<4;r++){
        float expP1 = (float)(quad*4+r) * (float)(m16+100);
        p1 = p1 && (fabsf(dp[r]-expP1) < 0.5f);
    }
    bool swapD = (__ballot(p1) != 0xFFFFFFFFFFFFFFFFull);

    // ================= PHASE A: offset+mask conv -> sOM =================
    {
        unsigned short* sWin  = uLDS;            // 26,928 shorts (3x66x136): [0, 26928)
        unsigned short* sWpm0 = uLDS + 26928;    //  4,352 shorts: [26928, 31280)
        unsigned short* sWpm1 = uLDS + 31280;    //  4,352 shorts: [31280, 35632)
        int qt = wave & 1, pt = wave >> 1;       // 2 q-tiles x 4 px-tiles
        // prologue: issue Wpm(0) (512 int4 = full tap), stage window, write sWpm0
        int4 w0_ = ((const int4*)Wpm)[tid];
        for(int i = tid; i < 3168; i += 512){    // 198 pos x 16 groups of 8 ch
            int pos = i >> 4, g = i & 15;
            int r = pos / 66, col = pos - r*66;
            int yy = y + r - 1, xx = col - 1;
            int4 v = make_int4(0,0,0,0);
            if(yy>=0 && yy<64 && xx>=0 && xx<64)
                v = *(const int4*)&cb[(size_t)((yy<<6)+xx)*128 + (g<<3)];
            *(int4*)&sWin[pos*136 + (g<<3)] = v;
        }
        *(int4*)&sWpm0[(tid>>4)*136 + ((tid&15)<<3)] = w0_;
        __syncthreads();

        f32x4 accA = {0.f,0.f,0.f,0.f};
        for(int n=0;n<9;n++){
            int4 wn_;
            if(n<8) wn_ = ((const int4*)(Wpm + ((n+1)<<12)))[tid];  // issue early
            int ky = n/3, kx = n - ky*3;
            const unsigned short* base = &sWin[(ky*66 + (pt<<4) + kx)*136];
            const unsigned short* swp = (n&1) ? sWpm1 : sWpm0;
            #pragma unroll
            for(int ks=0; ks<4; ks++){
                int k0 = ks << 5;
                short8 bfr = *(const short8*)&base[m16*136 + k0 + (quad<<3)];
                short8 afr = *(const short8*)&swp[((qt<<4) + m16)*136 + k0 + (quad<<3)];
                accA = __builtin_amdgcn_mfma_f32_16x16x32_bf16(afr, bfr, accA, 0,0,0);
            }
            if(n<8){
                unsigned short* swn = ((n+1)&1) ? sWpm1 : sWpm0;
                *(int4*)&swn[(tid>>4)*136 + ((tid&15)<<3)] = wn_;
            }
            __syncthreads();
        }
        if(!swapD){
            int pxl = (pt<<4) + m16;
            #pragma unroll
            for(int r=0;r<4;r++){
                int q = (qt<<4) + (quad<<2) + r;
                if(q < 27){
                    float v = accA[r] + ((q<18) ? pb[q] : mb[q-18]);
                    if(q>=18) v = 1.f/(1.f+expf(-v));
                    sOM[(q<<6) + pxl] = v;
                }
            }
        } else {
            int q = (qt<<4) + m16;
            if(q < 27){
                float bias2 = (q<18) ? pb[q] : mb[q-18];
                #pragma unroll
                for(int r=0;r<4;r++){
                    int pxl = (pt<<4) + (quad<<2) + r;
                    float v = accA[r] + bias2;
                    if(q>=18) v = 1.f/(1.f+expf(-v));
                    sOM[(q<<6) + pxl] = v;
                }
            }
        }
        __syncthreads();                  // sOM complete; uLDS free for phase B
    }

    // ================= PHASE B: deformable sampling + MFMA (verified v13) =================
    unsigned short* sW = uLDS;                   // 17,408 shorts [o][c]
    unsigned short* sXb = uLDS + 17408;          // 2 x 8,704 shorts dbuf [px][c]
    uint2* sM = (uint2*)(uLDS + 34816);          // 256 entries

    f32x4 acc[2][2];                     // [ot][pt]
    #pragma unroll
    for(int i=0;i<2;i++){
        #pragma unroll
        for(int j=0;j<2;j++) acc[i][j] = (f32x4){0.f,0.f,0.f,0.f};
    }

    // ---- prologue
    K5_META(0);
    __syncthreads();                      // sM = meta(0)
    K5_GATHER((sXb));                     // gather(0) using meta(0)
    K5_STAGE_W(0);
    __syncthreads();                      // sX[0], sW(0) ready; sM reads done
    K5_META(1);
    __syncthreads();                      // sM = meta(1)

    for(int n=0;n<9;n++){
        if(n<8) K5_GATHER((sXb + (((n+1)&1)*8704)));  // meta(n+1); overlaps MFMA(n)
        K5_DOMFMA((sXb + ((n&1)*8704)));              // operands from LDS (sW, sX)
        __syncthreads();                              // sW/sM reads + sX writes done
        if(n<8){
            K5_STAGE_W(n+1);                          // sW <- W(n+1), transient regs
            if(n<7) K5_META(n+2);                     // sM <- meta(n+2)
            __syncthreads();                          // sW, sM ready for next iter
        }
    }

    // epilogue: bf16 D writes + per-channel sum/sumsq reduction (stats from f32 acc)
    float* sdq = (float*)uLDS;            // [0..127]=sum, [128..255]=sumsq
    if(tid < 256) sdq[tid] = 0.f;
    __syncthreads();
    if(!swapD){
        #pragma unroll
        for(int ot=0;ot<2;ot++){
            #pragma unroll
            for(int pt=0;pt<2;pt++){
                int px = pix0 + phb + (pt<<4) + m16;
                #pragma unroll
                for(int r=0;r<4;r++){
                    int o = wo + (ot<<4) + (quad<<2) + r;
                    D[((size_t)(b*128+o)<<12) + px] = f2bf(acc[ot][pt][r]);
                }
            }
        }
        #pragma unroll
        for(int ot=0;ot<2;ot++){
            #pragma unroll
            for(int r=0;r<4;r++){
                float s  = acc[ot][0][r] + acc[ot][1][r];
                float s2 = acc[ot][0][r]*acc[ot][0][r] + acc[ot][1][r]*acc[ot][1][r];
                #pragma unroll
                for(int msk=1; msk<16; msk<<=1){
                    s  += __shfl_xor(s, msk, 64);
                    s2 += __shfl_xor(s2, msk, 64);
                }
                if(m16 == 0){
                    int o = wo + (ot<<4) + (quad<<2) + r;
                    atomicAdd(&sdq[o], s);
                    atomicAdd(&sdq[128+o], s2);
                }
            }
        }
    } else {
        #pragma unroll
        for(int ot=0;ot<2;ot++){
            #pragma unroll
            for(int pt=0;pt<2;pt++){
                int o = wo + (ot<<4) + m16;
                #pragma unroll
                for(int r=0;r<4;r++){
                    int px = pix0 + phb + (pt<<4) + (quad<<2) + r;
                    D[((size_t)(b*128+o)<<12) + px] = f2bf(acc[ot][pt][r]);
                }
            }
        }
        #pragma unroll
        for(int ot=0;ot<2;ot++){
            float s = 0.f, s2 = 0.f;
            #pragma unroll
            for(int pt=0;pt<2;pt++){
                #pragma unroll
                for(int r=0;r<4;r++){
                    float v = acc[ot][pt][r];
                    s += v; s2 += v*v;
                }
            }
            #pragma unroll
            for(int msk=16; msk<64; msk<<=1){
                s  += __shfl_xor(s, msk, 64);
                s2 += __shfl_xor(s2, msk, 64);
            }
            if(quad == 0){
                int o = wo + (ot<<4) + m16;
                atomicAdd(&sdq[o], s);
                atomicAdd(&sdq[128+o], s2);
            }
        }
    }
    __syncthreads();
    if(tid < 128){
        atomicAdd(&stats[tid],     sdq[tid]);
        atomicAdd(&stats[128+tid], sdq[128+tid]);
    }
}

// ---------------- K7 v3: fused BN1+GELU + depthwise128 (bf16 D in, bf16 Hs out)
__global__ __launch_bounds__(256) void k_bngelu_dw128(const unsigned short* Dsrc, float* stats,
                                                      fp g1, fp b1, fp w, fp bias, unsigned short* Hs){
    __shared__ float sG[66*68 + 4];
    __shared__ float sd[256], sq[256];
    int bid = blockIdx.x;
    int c = bid & 127, b = bid >> 7;
    int tid = threadIdx.x;
    float mean1 = stats[c] * (1.f/32768.f);
    float var1  = stats[128+c] * (1.f/32768.f) - mean1*mean1;
    float rstd1 = rsqrtf(var1 + 1e-5f);
    float sc = rstd1 * g1[c];
    float sb = b1[c] - mean1*sc;
    for(int j = tid; j < 264; j += 256){
        int idx;
        if(j < 66)       idx = j;
        else if(j < 132) idx = 65*68 + (j-66);
        else if(j < 196) idx = (j-132+1)*68;
        else if(j < 260) idx = (j-196+1)*68 + 65;
        else             idx = 66*68 + (j-260);
        sG[idx] = 0.f;
    }
    const unsigned short* dplane = Dsrc + ((size_t)(b*128+c)<<12);
    for(int j = tid; j < 1024; j += 256){
        int yy = j >> 4, x4 = (j & 15) << 2;
        uint2 v = *(const uint2*)&dplane[(yy<<6) + x4];
        float g0 = bflo(v.x)*sc+sb, g1v = bfhi(v.x)*sc+sb;
        float g2 = bflo(v.y)*sc+sb, g3 = bfhi(v.y)*sc+sb;
        float* d = &sG[(yy+1)*68 + x4 + 1];
        d[0] = 0.5f*g0*(1.0f + erff(g0*0.70710678118654752f));
        d[1] = 0.5f*g1v*(1.0f + erff(g1v*0.70710678118654752f));
        d[2] = 0.5f*g2*(1.0f + erff(g2*0.70710678118654752f));
        d[3] = 0.5f*g3*(1.0f + erff(g3*0.70710678118654752f));
    }
    __syncthreads();
    float w0=w[c*9+0], w1=w[c*9+1], w2=w[c*9+2];
    float w3=w[c*9+3], w4=w[c*9+4], w5=w[c*9+5];
    float w6=w[c*9+6], w7=w[c*9+7], w8=w[c*9+8];
    float bv = bias[c];
    unsigned short* dst = Hs + ((size_t)(b*128+c)<<12);
    float s = 0.f, s2 = 0.f;
    for(int j = tid; j < 1024; j += 256){
        int y = j >> 4, x0 = (j & 15) << 2;
        float a0=bv, a1=bv, a2=bv, a3=bv;
        #pragma unroll
        for(int ky=0; ky<3; ky++){
            const float* rr = &sG[(y+ky)*68 + x0];
            float4 u0 = *(const float4*)&rr[0];
            float2 u1 = *(const float2*)&rr[4];
            float wA = (ky==0)?w0:((ky==1)?w3:w6);
            float wB = (ky==0)?w1:((ky==1)?w4:w7);
            float wC = (ky==0)?w2:((ky==1)?w5:w8);
            a0 += wA*u0.x + wB*u0.y + wC*u0.z;
            a1 += wA*u0.y + wB*u0.z + wC*u0.w;
            a2 += wA*u0.z + wB*u0.w + wC*u1.x;
            a3 += wA*u0.w + wB*u1.x + wC*u1.y;
        }
        st4bf(&dst[(y<<6)+x0], a0,a1,a2,a3);
        s += a0+a1+a2+a3;
        s2 += a0*a0 + a1*a1 + a2*a2 + a3*a3;
    }
    sd[tid]=s; sq[tid]=s2; __syncthreads();
    for(int off=128; off>0; off>>=1){
        if(tid<off){ sd[tid]+=sd[tid+off]; sq[tid]+=sq[tid+off]; }
        __syncthreads();
    }
    if(tid==0){
        atomicAdd(&stats[256+c], sd[0]);
        atomicAdd(&stats[384+c], sq[0]);
    }
}

// ---------------- BN2 + ReLU -> f32 out (bf16 Hs in)
__global__ __launch_bounds__(256) void k_bn_relu_out(const unsigned short* Hs, const float* stats,
                                                     fp g, fp bb, float* out){
    int idx = blockIdx.x*256+threadIdx.x;       // 1,048,576 groups of 4 px
    int c = (idx>>10)&127;
    float mean2 = stats[256+c] * (1.f/32768.f);
    float var2  = stats[384+c] * (1.f/32768.f) - mean2*mean2;
    float rs = rsqrtf(var2 + 1e-5f) * g[c];
    float sb = bb[c] - mean2*rs;
    uint2 v = ((const uint2*)Hs)[idx];
    float4 o;
    o.x = fmaxf(bflo(v.x)*rs+sb, 0.f);
    o.y = fmaxf(bfhi(v.x)*rs+sb, 0.f);
    o.z = fmaxf(bflo(v.y)*rs+sb, 0.f);
    o.w = fmaxf(bfhi(v.y)*rs+sb, 0.f);
    ((float4*)out)[idx] = o;
}

extern "C" void kernel_launch(void* const* d_in, const int* in_sizes, int n_in,
                              void* d_out, int out_size, void* d_ws, size_t ws_size,
                              hipStream_t stream){
    fp x1   = (fp)d_in[0];
    fp x2   = (fp)d_in[1];
    fp dw_w = (fp)d_in[2];  fp dw_b = (fp)d_in[3];
    fp pw_w = (fp)d_in[4];  fp pw_b = (fp)d_in[5];
    fp p_w  = (fp)d_in[6];  fp p_b  = (fp)d_in[7];
    fp m_w  = (fp)d_in[8];  fp m_b  = (fp)d_in[9];
    fp dcn_w= (fp)d_in[10];
    fp bn1g = (fp)d_in[11]; fp bn1b = (fp)d_in[12];
    fp dw2w = (fp)d_in[13]; fp dw2b = (fp)d_in[14];
    fp bn2g = (fp)d_in[15]; fp bn2b = (fp)d_in[16];

    float* ws  = (float*)d_ws;
    unsigned short* Bo  = (unsigned short*)ws;               // (8,256,4096) bf16 ; D overlays after k_pw
    unsigned short* Cbf = (unsigned short*)(ws + 8388608);   // (8,4096,128) bf16 ; Hs overlays after k_deform
    unsigned short* Hs  = (unsigned short*)(ws + 8388608);   // (8,128,4096) bf16
    unsigned short* Wbf = (unsigned short*)(ws + 13467648);
    unsigned short* Wpm = (unsigned short*)(ws + 13541376);
    float* stats = ws + 13559808;       // 512 f
    unsigned short* Wpwbf = (unsigned short*)(ws + 13560320);  // 32,768 bf16
    unsigned short* D   = Bo;           // Bo dead after k_pw
    float* out = (float*)d_out;

    hipMemsetAsync(stats, 0, 512*sizeof(float), stream);
    k_updw256      <<<2048,  256, 0, stream>>>(x1, x2, dw_w, dw_b, Bo,
                                               dcn_w, p_w, m_w, pw_w, Wbf, Wpm, Wpwbf);  // prep folded in
    k_pw           <<<512,   512, 0, stream>>>(Bo, Wpwbf, pw_b, Cbf);
    k_deform       <<<512,   512, 0, stream>>>(Cbf, Wpm, p_b, m_b, Wbf, D, stats);  // fused offmask+deform
    k_bngelu_dw128 <<<1024,  256, 0, stream>>>(D, stats, bn1g, bn1b, dw2w, dw2b, Hs);
    k_bn_relu_out  <<<4096,  256, 0, stream>>>(Hs, stats, bn2g, bn2b, out);
}